// Round 6
// baseline (3665.075 us; speedup 1.0000x reference)
//
#include <hip/hip_runtime.h>
#include <hip/hip_bf16.h>

typedef __hip_bfloat16 bf16;

constexpr int kB = 2, kT = 2048, kC = 1024, kNH = 16, kHS = 64;
constexpr int kL = 32, kST = 16, kWIN = 256;
constexpr int kNB = (kT - kL) / kST + 1;   // 127
constexpr int kM = kB * kT;                // 4096

__device__ __forceinline__ float b2f(bf16 v) { return __bfloat162float(v); }
__device__ __forceinline__ bf16  f2b(float v) { return __float2bfloat16(v); }
__device__ __forceinline__ float gelu_f(float v) { return 0.5f * v * (1.0f + erff(v * 0.70710678118654752f)); }

__device__ __forceinline__ float ldf(const float* p, size_t i) { return p[i]; }
__device__ __forceinline__ float ldf(const bf16*  p, size_t i) { return b2f(p[i]); }
__device__ __forceinline__ void  stf(float* p, size_t i, float v) { p[i] = v; }
__device__ __forceinline__ void  stf(bf16*  p, size_t i, float v) { p[i] = f2b(v); }

// Y(M,N) = EPI(X(M,K) @ W(N,K)^T + bias). EPI: 0=none, 1=gelu, 3=sigmoid.
template<int EPI, typename TX, typename TY>
__global__ __launch_bounds__(256) void gemm_bias(
    const TX* __restrict__ X, const float* __restrict__ W,
    const float* __restrict__ bias, TY* __restrict__ Y,
    int M, int N, int K)
{
  __shared__ float Xs[64][17];
  __shared__ float Ws[64][17];
  const int bn = blockIdx.x * 64;
  const int bm = blockIdx.y * 64;
  const int tid = threadIdx.x;
  const int tx = tid & 15, ty = tid >> 4;
  const int lk = tid & 15, lr = tid >> 4;
  float acc[4][4] = {};
  for (int k0 = 0; k0 < K; k0 += 16) {
#pragma unroll
    for (int r = 0; r < 4; ++r) {
      Xs[lr + 16 * r][lk] = ldf(X, (size_t)(bm + lr + 16 * r) * K + k0 + lk);
      Ws[lr + 16 * r][lk] = W[(size_t)(bn + lr + 16 * r) * K + k0 + lk];
    }
    __syncthreads();
#pragma unroll
    for (int kk = 0; kk < 16; ++kk) {
      float a[4], bb[4];
#pragma unroll
      for (int i = 0; i < 4; ++i) a[i] = Xs[ty * 4 + i][kk];
#pragma unroll
      for (int j = 0; j < 4; ++j) bb[j] = Ws[tx * 4 + j][kk];
#pragma unroll
      for (int i = 0; i < 4; ++i)
#pragma unroll
        for (int j = 0; j < 4; ++j)
          acc[i][j] = fmaf(a[i], bb[j], acc[i][j]);
    }
    __syncthreads();
  }
#pragma unroll
  for (int i = 0; i < 4; ++i) {
    const int m = bm + ty * 4 + i;
#pragma unroll
    for (int j = 0; j < 4; ++j) {
      const int n = bn + tx * 4 + j;
      float v = acc[i][j] + bias[n];
      if (EPI == 1) v = gelu_f(v);
      if (EPI == 3) v = 1.f / (1.f + expf(-v));
      stf(Y, (size_t)m * N + n, v);
    }
  }
}

// Compression MLP: block per (b,h,blk); thread d handles channel d.
// kvbuf layout (B,T,2C) bf16; s=0 -> k half, s=1 -> v half.
__global__ __launch_bounds__(64) void comp_mlp(
    const bf16* __restrict__ kvbuf, int s,
    const float* __restrict__ fc1W, const float* __restrict__ fc1b,
    const float* __restrict__ fc2W, const float* __restrict__ fc2b,
    const float* __restrict__ rpW,  const float* __restrict__ rpb,
    const float* __restrict__ wpe,  bf16* __restrict__ outp)
{
  __shared__ float s_fc1W[128 * 32];
  __shared__ float s_fc1b[128];
  __shared__ float s_fc2W[128];
  const int id = blockIdx.x;
  const int blk = id % kNB;
  const int h = (id / kNB) % kNH;
  const int b = id / (kNB * kNH);
  const int d = threadIdx.x;
  for (int i = d; i < 128 * 32; i += 64) s_fc1W[i] = fc1W[i];
  for (int i = d; i < 128; i += 64) { s_fc1b[i] = fc1b[i]; s_fc2W[i] = fc2W[i]; }
  __syncthreads();

  float xu[kL], xpe[kL];
  const int t0 = blk * kST;
  const bf16* base = kvbuf + ((size_t)(b * kT + t0) * (2 * kC)) + (size_t)s * kC + h * kHS + d;
#pragma unroll
  for (int l = 0; l < kL; ++l) {
    float u = b2f(base[(size_t)l * (2 * kC)]);
    xu[l] = u;
    xpe[l] = u + wpe[l * kHS + d];
  }
  float out = fc2b[0];
  for (int j = 0; j < 128; ++j) {
    float a = s_fc1b[j];
#pragma unroll
    for (int l = 0; l < kL; ++l) a = fmaf(xpe[l], s_fc1W[j * kL + l], a);
    out = fmaf(gelu_f(a), s_fc2W[j], out);
  }
  float res = rpb[0];
#pragma unroll
  for (int l = 0; l < kL; ++l) res = fmaf(xu[l], rpW[l], res);
  float r = out + res;
  r = fminf(3.0f, fmaxf(-3.0f, r));
  outp[((size_t)(b * kNH + h) * kNB + blk) * kHS + d] = f2b(r);
}

// Local sliding-window attention for batch b: one wave per (h, i).
// Writes ybuf[i*C + h*HS + lane] (fp32, batch-local rows).
__global__ __launch_bounds__(64) void local_attn(
    const bf16* __restrict__ qkv, float* __restrict__ ybuf, int b)
{
  const int id = blockIdx.x;
  const int i = id % kT;
  const int h = id / kT;
  const int lane = threadIdx.x;
  __shared__ float qs[kHS];
  __shared__ float sc[kWIN];
  const size_t rs = 3 * kC;
  const bf16* qrow = qkv + ((size_t)(b * kT + i)) * rs + h * kHS;
  qs[lane] = b2f(qrow[lane]);
  __syncthreads();
  int jstart = i - (kWIN - 1); if (jstart < 0) jstart = 0;
  const int nk = i - jstart + 1;
  const bf16* kbase = qkv + ((size_t)b * kT) * rs + kC + h * kHS;
  for (int kk = lane; kk < nk; kk += 64) {
    const bf16* krow = kbase + (size_t)(jstart + kk) * rs;
    float dot = 0.f;
    for (int c = 0; c < kHS; ++c) dot = fmaf(b2f(krow[c]), qs[c], dot);
    sc[kk] = dot * 0.125f;
  }
  __syncthreads();
  float m = -1e30f;
  for (int kk = lane; kk < nk; kk += 64) m = fmaxf(m, sc[kk]);
#pragma unroll
  for (int off = 32; off >= 1; off >>= 1) m = fmaxf(m, __shfl_xor(m, off));
  float ssum = 0.f;
  for (int kk = lane; kk < nk; kk += 64) { float e = expf(sc[kk] - m); sc[kk] = e; ssum += e; }
#pragma unroll
  for (int off = 32; off >= 1; off >>= 1) ssum += __shfl_xor(ssum, off);
  __syncthreads();
  const bf16* vbase = qkv + ((size_t)b * kT) * rs + 2 * kC + h * kHS + lane;
  float acc = 0.f;
  for (int kk = 0; kk < nk; ++kk)
    acc = fmaf(sc[kk], b2f(vbase[(size_t)(jstart + kk) * rs]), acc);
  ybuf[(size_t)i * kC + h * kHS + lane] = acc / ssum;
}

// Compressed-block attention fused with gate mix, batch b.
// Reads gate (fp32, global rows) and yl from ybuf; writes mix in-place (1:1).
__global__ __launch_bounds__(64) void comp_attn_mix(
    const bf16* __restrict__ qkv, const bf16* __restrict__ kcomp,
    const bf16* __restrict__ vcomp, const float* __restrict__ gate,
    float* __restrict__ ybuf, int b)
{
  const int id = blockIdx.x;
  const int i = id % kT;
  const int h = id / kT;
  const int lane = threadIdx.x;
  const int c = h * kHS + lane;
  int nallow = (i + 15) >> 4;              // #blocks n with n*ST < i
  if (nallow > kNB) nallow = kNB;
  float yc = 0.f;                          // i==0: softmax all -inf -> nan_to_num -> 0
  if (nallow > 0) {                        // uniform per block (depends only on i)
    __shared__ float qs[kHS];
    __shared__ float sc[128];
    const bf16* qrow = qkv + ((size_t)(b * kT + i)) * (3 * kC) + h * kHS;
    qs[lane] = b2f(qrow[lane]);
    __syncthreads();
    const bf16* kb = kcomp + ((size_t)(b * kNH + h)) * kNB * kHS;
    for (int n = lane; n < nallow; n += 64) {
      const bf16* kr = kb + (size_t)n * kHS;
      float dot = 0.f;
      for (int cc = 0; cc < kHS; ++cc) dot = fmaf(b2f(kr[cc]), qs[cc], dot);
      sc[n] = dot * 0.125f;
    }
    __syncthreads();
    float m = -1e30f;
    for (int n = lane; n < nallow; n += 64) m = fmaxf(m, sc[n]);
#pragma unroll
    for (int off = 32; off >= 1; off >>= 1) m = fmaxf(m, __shfl_xor(m, off));
    float ssum = 0.f;
    for (int n = lane; n < nallow; n += 64) { float e = expf(sc[n] - m); sc[n] = e; ssum += e; }
#pragma unroll
    for (int off = 32; off >= 1; off >>= 1) ssum += __shfl_xor(ssum, off);
    __syncthreads();
    const bf16* vb = vcomp + ((size_t)(b * kNH + h)) * kNB * kHS + lane;
    float acc = 0.f;
    for (int n = 0; n < nallow; ++n)
      acc = fmaf(sc[n], b2f(vb[(size_t)n * kHS]), acc);
    yc = acc / ssum;
  }
  float g  = gate[((size_t)(b * kT + i)) * kC + c];
  float yl = ybuf[(size_t)i * kC + c];
  ybuf[(size_t)i * kC + c] = g * yl + (1.f - g) * yc;
}

extern "C" void kernel_launch(void* const* d_in, const int* in_sizes, int n_in,
                              void* d_out, int out_size, void* d_ws, size_t ws_size,
                              hipStream_t stream)
{
  (void)in_sizes; (void)n_in; (void)out_size; (void)ws_size;
  const float* x      = (const float*)d_in[0];
  const float* Wqkv   = (const float*)d_in[1];
  const float* bqkv   = (const float*)d_in[2];
  const float* Wcomp  = (const float*)d_in[3];
  const float* bcomp  = (const float*)d_in[4];
  const float* Wproj  = (const float*)d_in[5];
  const float* bproj  = (const float*)d_in[6];
  const float* k_fc1W = (const float*)d_in[7];
  const float* k_fc1b = (const float*)d_in[8];
  const float* k_fc2W = (const float*)d_in[9];
  const float* k_fc2b = (const float*)d_in[10];
  const float* k_rpW  = (const float*)d_in[11];
  const float* k_rpb  = (const float*)d_in[12];
  const float* k_wpe  = (const float*)d_in[13];
  const float* v_fc1W = (const float*)d_in[14];
  const float* v_fc1b = (const float*)d_in[15];
  const float* v_fc2W = (const float*)d_in[16];
  const float* v_fc2b = (const float*)d_in[17];
  const float* v_rpW  = (const float*)d_in[18];
  const float* v_rpb  = (const float*)d_in[19];
  const float* v_wpe  = (const float*)d_in[20];
  const float* Wg1    = (const float*)d_in[21];
  const float* bg1    = (const float*)d_in[22];
  const float* Wg2    = (const float*)d_in[23];
  const float* bg2    = (const float*)d_in[24];

  // ---- Workspace (peak 51,372,032 B ~ 49 MiB) ----
  // big   [0, 25165824) bf16: g1-half (16.8M) -> kvb (16.8M) -> qkvb (25.2M), time-disjoint
  // kcomp [25165824, 25686016) bf16
  // vcomp [25686016, 26206208) bf16
  // gate  [26206208, 42983424) fp32 (B,T,C)
  // ybuf  [42983424, 51372032) fp32 (T,C), per-batch ylocal -> ymix in-place
  char* wsb = (char*)d_ws;
  bf16*  big   = (bf16*)(wsb + 0);
  bf16*  kcomp = (bf16*)(wsb + 25165824);
  bf16*  vcomp = (bf16*)(wsb + 25686016);
  float* gate  = (float*)(wsb + 26206208);
  float* ybuf  = (float*)(wsb + 42983424);
  float* out   = (float*)d_out;

  // 1) gate -> ws, two row-halves through one 16.8MB g1 buffer
  for (int hh = 0; hh < 2; ++hh) {
    gemm_bias<1, float, bf16 ><<<dim3(4096 / 64, 2048 / 64), 256, 0, stream>>>(
        x + (size_t)hh * 2048 * kC, Wg1, bg1, big, 2048, 4096, 1024);
    gemm_bias<3, bf16, float><<<dim3(1024 / 64, 2048 / 64), 256, 0, stream>>>(
        big, Wg2, bg2, gate + (size_t)hh * 2048 * kC, 2048, 1024, 4096);
  }
  // 2) kv -> big; compression MLPs
  gemm_bias<0, float, bf16><<<dim3(2048 / 64, 4096 / 64), 256, 0, stream>>>(
      x, Wcomp, bcomp, big, 4096, 2048, 1024);
  comp_mlp<<<kB * kNH * kNB, 64, 0, stream>>>(big, 0, k_fc1W, k_fc1b, k_fc2W, k_fc2b, k_rpW, k_rpb, k_wpe, kcomp);
  comp_mlp<<<kB * kNH * kNB, 64, 0, stream>>>(big, 1, v_fc1W, v_fc1b, v_fc2W, v_fc2b, v_rpW, v_rpb, v_wpe, vcomp);
  // 3) qkv -> big (clobbers kv buffer, dead)
  gemm_bias<0, float, bf16><<<dim3(3072 / 64, 4096 / 64), 256, 0, stream>>>(
      x, Wqkv, bqkv, big, 4096, 3072, 1024);
  // 4) per batch: local attn -> ybuf; comp attn + gate mix in-place; projection -> d_out (fp32).
  for (int b = 0; b < kB; ++b) {
    local_attn<<<kNH * kT, 64, 0, stream>>>(big, ybuf, b);
    comp_attn_mix<<<kNH * kT, 64, 0, stream>>>(big, kcomp, vcomp, gate, ybuf, b);
    gemm_bias<0, float, float><<<dim3(1024 / 64, 2048 / 64), 256, 0, stream>>>(
        ybuf, Wproj, bproj, out + (size_t)b * 2048 * kC, 2048, 1024, 1024);
  }
}

// Round 7
// 1355.919 us; speedup vs baseline: 2.7030x; 2.7030x over previous
//
#include <hip/hip_runtime.h>
#include <hip/hip_bf16.h>

typedef __hip_bfloat16 bf16;

constexpr int kB = 2, kT = 2048, kC = 1024, kNH = 16, kHS = 64;
constexpr int kL = 32, kST = 16, kWIN = 256;
constexpr int kNB = (kT - kL) / kST + 1;   // 127
constexpr int kM = kB * kT;                // 4096

typedef __attribute__((ext_vector_type(8))) short short8;   // bf16 MFMA A/B frag (4 VGPRs)
typedef __attribute__((ext_vector_type(4))) short short4v;
typedef __attribute__((ext_vector_type(4))) float f32x4;

__device__ __forceinline__ float b2f(bf16 v) { return __bfloat162float(v); }
__device__ __forceinline__ bf16  f2b(float v) { return __float2bfloat16(v); }
__device__ __forceinline__ float gelu_f(float v) { return 0.5f * v * (1.0f + erff(v * 0.70710678118654752f)); }
__device__ __forceinline__ short fbits(float v) {
  return (short)__builtin_bit_cast(unsigned short, f2b(v));
}

// ---------------- MFMA GEMM ----------------
// Y(M,N) = EPI(X(M,K) @ W(N,K)^T + bias). 128x128 tile, BK=32, 4 waves (2x2).
// X staged fp32->bf16 (or bf16 passthrough) into swizzled LDS; W is fp32.
// Swizzle: 16B-chunk q of row r -> q ^ ((r>>1)&3)  (2-way LDS access = free).

template<typename TX>
__device__ __forceinline__ void stage_tile(const TX* __restrict__ src, int ldk,
                                           short* lds, int tid) {
#pragma unroll
  for (int rep = 0; rep < 4; ++rep) {
    const int c = rep * 256 + tid;      // 4-elem chunk id, 0..1023
    const int r = c >> 3, p = c & 7;    // row (0..127), 4-elem chunk in row
    const int si = r * 32 + ((p * 4) ^ (((r >> 1) & 3) << 3));
    const TX* s = src + (size_t)r * ldk + p * 4;
    short4v w;
    if constexpr (sizeof(TX) == 2) {
      w = *reinterpret_cast<const short4v*>(s);
    } else {
      const float* f = (const float*)s;
      float4 v = *reinterpret_cast<const float4*>(f);
      w.x = fbits(v.x); w.y = fbits(v.y); w.z = fbits(v.z); w.w = fbits(v.w);
    }
    *reinterpret_cast<short4v*>(&lds[si]) = w;
  }
}

template<int EPI, typename TX, typename TY>
__global__ __launch_bounds__(256) void gemm_mfma(
    const TX* __restrict__ X, const float* __restrict__ W,
    const float* __restrict__ bias, TY* __restrict__ Y,
    int M, int N, int K)
{
  __shared__ __align__(16) short As[128 * 32];
  __shared__ __align__(16) short Bs[128 * 32];
  const int tid = threadIdx.x;
  const int lane = tid & 63;
  const int wid = tid >> 6;
  const int wr = wid >> 1, wc = wid & 1;     // wave -> 64x64 sub-tile
  const int fr = lane & 15, q = lane >> 4;   // frag row/col + k-chunk
  const int bm = blockIdx.y * 128;
  const int bn = blockIdx.x * 128;

  f32x4 acc[4][4];
#pragma unroll
  for (int i = 0; i < 4; ++i)
#pragma unroll
    for (int j = 0; j < 4; ++j) acc[i][j] = (f32x4){0.f, 0.f, 0.f, 0.f};

  const TX* Xb = X + (size_t)bm * K;
  const float* Wb = W + (size_t)bn * K;

  for (int k0 = 0; k0 < K; k0 += 32) {
    __syncthreads();                      // protect LDS from previous reads
    stage_tile(Xb + k0, K, As, tid);
    stage_tile(Wb + k0, K, Bs, tid);
    __syncthreads();
    short8 af[4], bfr[4];
#pragma unroll
    for (int i = 0; i < 4; ++i) {
      const int ar = wr * 64 + i * 16 + fr;
      af[i] = *reinterpret_cast<const short8*>(&As[ar * 32 + ((q ^ ((ar >> 1) & 3)) << 3)]);
    }
#pragma unroll
    for (int j = 0; j < 4; ++j) {
      const int br = wc * 64 + j * 16 + fr;
      bfr[j] = *reinterpret_cast<const short8*>(&Bs[br * 32 + ((q ^ ((br >> 1) & 3)) << 3)]);
    }
#pragma unroll
    for (int i = 0; i < 4; ++i)
#pragma unroll
      for (int j = 0; j < 4; ++j)
        acc[i][j] = __builtin_amdgcn_mfma_f32_16x16x32_bf16(af[i], bfr[j], acc[i][j], 0, 0, 0);
  }

#pragma unroll
  for (int j = 0; j < 4; ++j) {
    const int gcol = bn + wc * 64 + j * 16 + fr;
    const float bv = bias[gcol];
#pragma unroll
    for (int i = 0; i < 4; ++i) {
      const int grow0 = bm + wr * 64 + i * 16 + q * 4;
#pragma unroll
      for (int r = 0; r < 4; ++r) {
        float v = acc[i][j][r] + bv;
        if (EPI == 1) v = gelu_f(v);
        if (EPI == 3) v = 1.f / (1.f + expf(-v));
        if constexpr (sizeof(TY) == 2) Y[(size_t)(grow0 + r) * N + gcol] = f2b(v);
        else                           ((float*)Y)[(size_t)(grow0 + r) * N + gcol] = v;
      }
    }
  }
}

// ---------------- Compression MLP (unchanged) ----------------
__global__ __launch_bounds__(64) void comp_mlp(
    const bf16* __restrict__ kvbuf, int s,
    const float* __restrict__ fc1W, const float* __restrict__ fc1b,
    const float* __restrict__ fc2W, const float* __restrict__ fc2b,
    const float* __restrict__ rpW,  const float* __restrict__ rpb,
    const float* __restrict__ wpe,  bf16* __restrict__ outp)
{
  __shared__ float s_fc1W[128 * 32];
  __shared__ float s_fc1b[128];
  __shared__ float s_fc2W[128];
  const int id = blockIdx.x;
  const int blk = id % kNB;
  const int h = (id / kNB) % kNH;
  const int b = id / (kNB * kNH);
  const int d = threadIdx.x;
  for (int i = d; i < 128 * 32; i += 64) s_fc1W[i] = fc1W[i];
  for (int i = d; i < 128; i += 64) { s_fc1b[i] = fc1b[i]; s_fc2W[i] = fc2W[i]; }
  __syncthreads();

  float xu[kL], xpe[kL];
  const int t0 = blk * kST;
  const bf16* base = kvbuf + ((size_t)(b * kT + t0) * (2 * kC)) + (size_t)s * kC + h * kHS + d;
#pragma unroll
  for (int l = 0; l < kL; ++l) {
    float u = b2f(base[(size_t)l * (2 * kC)]);
    xu[l] = u;
    xpe[l] = u + wpe[l * kHS + d];
  }
  float out = fc2b[0];
  for (int j = 0; j < 128; ++j) {
    float a = s_fc1b[j];
#pragma unroll
    for (int l = 0; l < kL; ++l) a = fmaf(xpe[l], s_fc1W[j * kL + l], a);
    out = fmaf(gelu_f(a), s_fc2W[j], out);
  }
  float res = rpb[0];
#pragma unroll
  for (int l = 0; l < kL; ++l) res = fmaf(xu[l], rpW[l], res);
  float r = out + res;
  r = fminf(3.0f, fmaxf(-3.0f, r));
  outp[((size_t)(b * kNH + h) * kNB + blk) * kHS + d] = f2b(r);
}

// ---------------- Local sliding-window attention (unchanged) ----------------
__global__ __launch_bounds__(64) void local_attn(
    const bf16* __restrict__ qkv, float* __restrict__ ybuf, int b)
{
  const int id = blockIdx.x;
  const int i = id % kT;
  const int h = id / kT;
  const int lane = threadIdx.x;
  __shared__ float qs[kHS];
  __shared__ float sc[kWIN];
  const size_t rs = 3 * kC;
  const bf16* qrow = qkv + ((size_t)(b * kT + i)) * rs + h * kHS;
  qs[lane] = b2f(qrow[lane]);
  __syncthreads();
  int jstart = i - (kWIN - 1); if (jstart < 0) jstart = 0;
  const int nk = i - jstart + 1;
  const bf16* kbase = qkv + ((size_t)b * kT) * rs + kC + h * kHS;
  for (int kk = lane; kk < nk; kk += 64) {
    const bf16* krow = kbase + (size_t)(jstart + kk) * rs;
    float dot = 0.f;
    for (int c = 0; c < kHS; ++c) dot = fmaf(b2f(krow[c]), qs[c], dot);
    sc[kk] = dot * 0.125f;
  }
  __syncthreads();
  float m = -1e30f;
  for (int kk = lane; kk < nk; kk += 64) m = fmaxf(m, sc[kk]);
#pragma unroll
  for (int off = 32; off >= 1; off >>= 1) m = fmaxf(m, __shfl_xor(m, off));
  float ssum = 0.f;
  for (int kk = lane; kk < nk; kk += 64) { float e = expf(sc[kk] - m); sc[kk] = e; ssum += e; }
#pragma unroll
  for (int off = 32; off >= 1; off >>= 1) ssum += __shfl_xor(ssum, off);
  __syncthreads();
  const bf16* vbase = qkv + ((size_t)b * kT) * rs + 2 * kC + h * kHS + lane;
  float acc = 0.f;
  for (int kk = 0; kk < nk; ++kk)
    acc = fmaf(sc[kk], b2f(vbase[(size_t)(jstart + kk) * rs]), acc);
  ybuf[(size_t)i * kC + h * kHS + lane] = acc / ssum;
}

// ---------------- Compressed attention + gate mix (gate now bf16) ----------------
__global__ __launch_bounds__(64) void comp_attn_mix(
    const bf16* __restrict__ qkv, const bf16* __restrict__ kcomp,
    const bf16* __restrict__ vcomp, const bf16* __restrict__ gate,
    float* __restrict__ ybuf, int b)
{
  const int id = blockIdx.x;
  const int i = id % kT;
  const int h = id / kT;
  const int lane = threadIdx.x;
  const int c = h * kHS + lane;
  int nallow = (i + 15) >> 4;              // #blocks n with n*ST < i
  if (nallow > kNB) nallow = kNB;
  float yc = 0.f;                          // i==0: softmax all -inf -> nan_to_num -> 0
  if (nallow > 0) {                        // uniform per block
    __shared__ float qs[kHS];
    __shared__ float sc[128];
    const bf16* qrow = qkv + ((size_t)(b * kT + i)) * (3 * kC) + h * kHS;
    qs[lane] = b2f(qrow[lane]);
    __syncthreads();
    const bf16* kb = kcomp + ((size_t)(b * kNH + h)) * kNB * kHS;
    for (int n = lane; n < nallow; n += 64) {
      const bf16* kr = kb + (size_t)n * kHS;
      float dot = 0.f;
      for (int cc = 0; cc < kHS; ++cc) dot = fmaf(b2f(kr[cc]), qs[cc], dot);
      sc[n] = dot * 0.125f;
    }
    __syncthreads();
    float m = -1e30f;
    for (int n = lane; n < nallow; n += 64) m = fmaxf(m, sc[n]);
#pragma unroll
    for (int off = 32; off >= 1; off >>= 1) m = fmaxf(m, __shfl_xor(m, off));
    float ssum = 0.f;
    for (int n = lane; n < nallow; n += 64) { float e = expf(sc[n] - m); sc[n] = e; ssum += e; }
#pragma unroll
    for (int off = 32; off >= 1; off >>= 1) ssum += __shfl_xor(ssum, off);
    __syncthreads();
    const bf16* vb = vcomp + ((size_t)(b * kNH + h)) * kNB * kHS + lane;
    float acc = 0.f;
    for (int n = 0; n < nallow; ++n)
      acc = fmaf(sc[n], b2f(vb[(size_t)n * kHS]), acc);
    yc = acc / ssum;
  }
  float g  = b2f(gate[((size_t)(b * kT + i)) * kC + c]);
  float yl = ybuf[(size_t)i * kC + c];
  ybuf[(size_t)i * kC + c] = g * yl + (1.f - g) * yc;
}

extern "C" void kernel_launch(void* const* d_in, const int* in_sizes, int n_in,
                              void* d_out, int out_size, void* d_ws, size_t ws_size,
                              hipStream_t stream)
{
  (void)in_sizes; (void)n_in; (void)out_size; (void)ws_size;
  const float* x      = (const float*)d_in[0];
  const float* Wqkv   = (const float*)d_in[1];
  const float* bqkv   = (const float*)d_in[2];
  const float* Wcomp  = (const float*)d_in[3];
  const float* bcomp  = (const float*)d_in[4];
  const float* Wproj  = (const float*)d_in[5];
  const float* bproj  = (const float*)d_in[6];
  const float* k_fc1W = (const float*)d_in[7];
  const float* k_fc1b = (const float*)d_in[8];
  const float* k_fc2W = (const float*)d_in[9];
  const float* k_fc2b = (const float*)d_in[10];
  const float* k_rpW  = (const float*)d_in[11];
  const float* k_rpb  = (const float*)d_in[12];
  const float* k_wpe  = (const float*)d_in[13];
  const float* v_fc1W = (const float*)d_in[14];
  const float* v_fc1b = (const float*)d_in[15];
  const float* v_fc2W = (const float*)d_in[16];
  const float* v_fc2b = (const float*)d_in[17];
  const float* v_rpW  = (const float*)d_in[18];
  const float* v_rpb  = (const float*)d_in[19];
  const float* v_wpe  = (const float*)d_in[20];
  const float* Wg1    = (const float*)d_in[21];
  const float* bg1    = (const float*)d_in[22];
  const float* Wg2    = (const float*)d_in[23];
  const float* bg2    = (const float*)d_in[24];

  // ---- Workspace (peak 51,372,032 B, same as round-6 proven) ----
  // big   [0, 33554432) bf16: g1 full (33.5M) -> kvb (16.8M) -> qkvb (25.2M), time-disjoint
  // kcomp [33554432, 34074624) bf16
  // vcomp [34074624, 34594816) bf16
  // gate  [34594816, 42983424) bf16 (B,T,C)
  // ybuf  [42983424, 51372032) fp32 (T,C), per-batch ylocal -> ymix in-place
  char* wsb = (char*)d_ws;
  bf16*  big   = (bf16*)(wsb + 0);
  bf16*  kcomp = (bf16*)(wsb + 33554432);
  bf16*  vcomp = (bf16*)(wsb + 34074624);
  bf16*  gate  = (bf16*)(wsb + 34594816);
  float* ybuf  = (float*)(wsb + 42983424);
  float* out   = (float*)d_out;

  // 1) g1 = gelu(x@Wg1) -> big (full M)
  gemm_mfma<1, float, bf16><<<dim3(4096 / 128, 4096 / 128), 256, 0, stream>>>(
      x, Wg1, bg1, big, 4096, 4096, 1024);
  // 2) gate = sigmoid(g1@Wg2) -> gate (bf16)
  gemm_mfma<3, bf16, bf16><<<dim3(1024 / 128, 4096 / 128), 256, 0, stream>>>(
      big, Wg2, bg2, gate, 4096, 1024, 4096);
  // 3) kv -> big (g1 dead); compression MLPs
  gemm_mfma<0, float, bf16><<<dim3(2048 / 128, 4096 / 128), 256, 0, stream>>>(
      x, Wcomp, bcomp, big, 4096, 2048, 1024);
  comp_mlp<<<kB * kNH * kNB, 64, 0, stream>>>(big, 0, k_fc1W, k_fc1b, k_fc2W, k_fc2b, k_rpW, k_rpb, k_wpe, kcomp);
  comp_mlp<<<kB * kNH * kNB, 64, 0, stream>>>(big, 1, v_fc1W, v_fc1b, v_fc2W, v_fc2b, v_rpW, v_rpb, v_wpe, vcomp);
  // 4) qkv -> big (kv dead)
  gemm_mfma<0, float, bf16><<<dim3(3072 / 128, 4096 / 128), 256, 0, stream>>>(
      x, Wqkv, bqkv, big, 4096, 3072, 1024);
  // 5) per batch: local attn -> ybuf; comp attn + gate mix in-place; projection -> d_out (fp32)
  for (int b = 0; b < kB; ++b) {
    local_attn<<<kNH * kT, 64, 0, stream>>>(big, ybuf, b);
    comp_attn_mix<<<kNH * kT, 64, 0, stream>>>(big, kcomp, vcomp, gate, ybuf, b);
    gemm_mfma<0, float, float><<<dim3(1024 / 128, 2048 / 128), 256, 0, stream>>>(
        ybuf, Wproj, bproj, out + (size_t)b * 2048 * kC, 2048, 1024, 1024);
  }
}

// Round 8
// 692.476 us; speedup vs baseline: 5.2927x; 1.9581x over previous
//
#include <hip/hip_runtime.h>
#include <hip/hip_bf16.h>

typedef __hip_bfloat16 bf16;

constexpr int kB = 2, kT = 2048, kC = 1024, kNH = 16, kHS = 64;
constexpr int kL = 32, kST = 16, kWIN = 256;
constexpr int kNB = (kT - kL) / kST + 1;   // 127
constexpr int kM = kB * kT;                // 4096

typedef __attribute__((ext_vector_type(8))) short short8;   // bf16 MFMA A/B frag (4 VGPRs)
typedef __attribute__((ext_vector_type(4))) short short4v;
typedef __attribute__((ext_vector_type(4))) float f32x4;

__device__ __forceinline__ float b2f(bf16 v) { return __bfloat162float(v); }
__device__ __forceinline__ bf16  f2b(float v) { return __float2bfloat16(v); }
__device__ __forceinline__ float gelu_f(float v) { return 0.5f * v * (1.0f + erff(v * 0.70710678118654752f)); }
__device__ __forceinline__ short fbits(float v) {
  return (short)__builtin_bit_cast(unsigned short, f2b(v));
}

// ---------------- MFMA GEMM (unchanged from round 7) ----------------
template<typename TX>
__device__ __forceinline__ void stage_tile(const TX* __restrict__ src, int ldk,
                                           short* lds, int tid) {
#pragma unroll
  for (int rep = 0; rep < 4; ++rep) {
    const int c = rep * 256 + tid;      // 4-elem chunk id, 0..1023
    const int r = c >> 3, p = c & 7;    // row (0..127), 4-elem chunk in row
    const int si = r * 32 + ((p * 4) ^ (((r >> 1) & 3) << 3));
    const TX* s = src + (size_t)r * ldk + p * 4;
    short4v w;
    if constexpr (sizeof(TX) == 2) {
      w = *reinterpret_cast<const short4v*>(s);
    } else {
      const float* f = (const float*)s;
      float4 v = *reinterpret_cast<const float4*>(f);
      w.x = fbits(v.x); w.y = fbits(v.y); w.z = fbits(v.z); w.w = fbits(v.w);
    }
    *reinterpret_cast<short4v*>(&lds[si]) = w;
  }
}

template<int EPI, typename TX, typename TY>
__global__ __launch_bounds__(256) void gemm_mfma(
    const TX* __restrict__ X, const float* __restrict__ W,
    const float* __restrict__ bias, TY* __restrict__ Y,
    int M, int N, int K)
{
  __shared__ __align__(16) short As[128 * 32];
  __shared__ __align__(16) short Bs[128 * 32];
  const int tid = threadIdx.x;
  const int lane = tid & 63;
  const int wid = tid >> 6;
  const int wr = wid >> 1, wc = wid & 1;
  const int fr = lane & 15, q = lane >> 4;
  const int bm = blockIdx.y * 128;
  const int bn = blockIdx.x * 128;

  f32x4 acc[4][4];
#pragma unroll
  for (int i = 0; i < 4; ++i)
#pragma unroll
    for (int j = 0; j < 4; ++j) acc[i][j] = (f32x4){0.f, 0.f, 0.f, 0.f};

  const TX* Xb = X + (size_t)bm * K;
  const float* Wb = W + (size_t)bn * K;

  for (int k0 = 0; k0 < K; k0 += 32) {
    __syncthreads();
    stage_tile(Xb + k0, K, As, tid);
    stage_tile(Wb + k0, K, Bs, tid);
    __syncthreads();
    short8 af[4], bfr[4];
#pragma unroll
    for (int i = 0; i < 4; ++i) {
      const int ar = wr * 64 + i * 16 + fr;
      af[i] = *reinterpret_cast<const short8*>(&As[ar * 32 + ((q ^ ((ar >> 1) & 3)) << 3)]);
    }
#pragma unroll
    for (int j = 0; j < 4; ++j) {
      const int br = wc * 64 + j * 16 + fr;
      bfr[j] = *reinterpret_cast<const short8*>(&Bs[br * 32 + ((q ^ ((br >> 1) & 3)) << 3)]);
    }
#pragma unroll
    for (int i = 0; i < 4; ++i)
#pragma unroll
      for (int j = 0; j < 4; ++j)
        acc[i][j] = __builtin_amdgcn_mfma_f32_16x16x32_bf16(af[i], bfr[j], acc[i][j], 0, 0, 0);
  }

#pragma unroll
  for (int j = 0; j < 4; ++j) {
    const int gcol = bn + wc * 64 + j * 16 + fr;
    const float bv = bias[gcol];
#pragma unroll
    for (int i = 0; i < 4; ++i) {
      const int grow0 = bm + wr * 64 + i * 16 + q * 4;
#pragma unroll
      for (int r = 0; r < 4; ++r) {
        float v = acc[i][j][r] + bv;
        if (EPI == 1) v = gelu_f(v);
        if (EPI == 3) v = 1.f / (1.f + expf(-v));
        if constexpr (sizeof(TY) == 2) Y[(size_t)(grow0 + r) * N + gcol] = f2b(v);
        else                           ((float*)Y)[(size_t)(grow0 + r) * N + gcol] = v;
      }
    }
  }
}

// ---------------- Compression MLP (unchanged) ----------------
__global__ __launch_bounds__(64) void comp_mlp(
    const bf16* __restrict__ kvbuf, int s,
    const float* __restrict__ fc1W, const float* __restrict__ fc1b,
    const float* __restrict__ fc2W, const float* __restrict__ fc2b,
    const float* __restrict__ rpW,  const float* __restrict__ rpb,
    const float* __restrict__ wpe,  bf16* __restrict__ outp)
{
  __shared__ float s_fc1W[128 * 32];
  __shared__ float s_fc1b[128];
  __shared__ float s_fc2W[128];
  const int id = blockIdx.x;
  const int blk = id % kNB;
  const int h = (id / kNB) % kNH;
  const int b = id / (kNB * kNH);
  const int d = threadIdx.x;
  for (int i = d; i < 128 * 32; i += 64) s_fc1W[i] = fc1W[i];
  for (int i = d; i < 128; i += 64) { s_fc1b[i] = fc1b[i]; s_fc2W[i] = fc2W[i]; }
  __syncthreads();

  float xu[kL], xpe[kL];
  const int t0 = blk * kST;
  const bf16* base = kvbuf + ((size_t)(b * kT + t0) * (2 * kC)) + (size_t)s * kC + h * kHS + d;
#pragma unroll
  for (int l = 0; l < kL; ++l) {
    float u = b2f(base[(size_t)l * (2 * kC)]);
    xu[l] = u;
    xpe[l] = u + wpe[l * kHS + d];
  }
  float out = fc2b[0];
  for (int j = 0; j < 128; ++j) {
    float a = s_fc1b[j];
#pragma unroll
    for (int l = 0; l < kL; ++l) a = fmaf(xpe[l], s_fc1W[j * kL + l], a);
    out = fmaf(gelu_f(a), s_fc2W[j], out);
  }
  float res = rpb[0];
#pragma unroll
  for (int l = 0; l < kL; ++l) res = fmaf(xu[l], rpW[l], res);
  float r = out + res;
  r = fminf(3.0f, fmaxf(-3.0f, r));
  outp[((size_t)(b * kNH + h) * kNB + blk) * kHS + d] = f2b(r);
}

// ---------------- Local sliding-window attention: MFMA flash ----------------
// One block per (h, 64-query tile) for batch b. 4 waves; wave w owns 16 queries.
// Key window [t0-255, t0+63] processed as <=5 tiles of 64 keys.
__global__ __launch_bounds__(256) void local_attn_mfma(
    const bf16* __restrict__ qkv, float* __restrict__ ybuf, int b)
{
  __shared__ __align__(16) short Qs[64 * 64];
  __shared__ __align__(16) short Ks[64 * 64];
  __shared__ __align__(16) short VTs[64 * 64];  // V transposed: [d][k]
  __shared__ __align__(16) short Ps[64 * 64];   // wave w rows w*16..w*16+15
  const int tid = threadIdx.x;
  const int lane = tid & 63;
  const int w = tid >> 6;
  const int fr = lane & 15;
  const int g  = lane >> 4;
  const int h  = blockIdx.y;
  const int t0 = blockIdx.x * 64;
  const size_t rs = 3 * kC;
  const bf16* qbase = qkv + ((size_t)b * kT) * rs + h * kHS;
  const bf16* kbase = qbase + kC;
  const bf16* vbase = qbase + 2 * kC;

  // stage Q tile (64 rows x 64 d), swizzled: elem col ^= (row&7)<<3
  for (int c = tid; c < 512; c += 256) {
    const int r = c >> 3, p = c & 7;
    short8 v = *reinterpret_cast<const short8*>(qbase + (size_t)(t0 + r) * rs + p * 8);
    *reinterpret_cast<short8*>(&Qs[r * 64 + ((p ^ (r & 7)) << 3)]) = v;
  }
  __syncthreads();
  short8 qf[2];
  {
    const int r = w * 16 + fr;
#pragma unroll
    for (int dc = 0; dc < 2; ++dc) {
      const int d0 = dc * 32 + g * 8;
      qf[dc] = *reinterpret_cast<const short8*>(&Qs[r * 64 + (d0 ^ ((r & 7) << 3))]);
    }
  }

  f32x4 acc[4];                       // O: row q = g*4+reg, col d = dt*16+fr
  float m[4], l[4];
#pragma unroll
  for (int r = 0; r < 4; ++r) { m[r] = -1e30f; l[r] = 0.f; }
#pragma unroll
  for (int dt = 0; dt < 4; ++dt) acc[dt] = (f32x4){0.f, 0.f, 0.f, 0.f};

  const int jb0 = (t0 >= 256) ? (t0 - 256) : 0;
  for (int jb = jb0; jb <= t0; jb += 64) {
    const bool masked = (jb == t0 - 256) || (jb == t0);
    __syncthreads();
    // stage K tile (swizzled row-major)
    for (int c = tid; c < 512; c += 256) {
      const int r = c >> 3, p = c & 7;
      short8 v = *reinterpret_cast<const short8*>(kbase + (size_t)(jb + r) * rs + p * 8);
      *reinterpret_cast<short8*>(&Ks[r * 64 + ((p ^ (r & 7)) << 3)]) = v;
    }
    // stage V tile transposed (VTs[d][k], swizzled)
    for (int c = tid; c < 512; c += 256) {
      const int r = c >> 3, p = c & 7;           // key r, d-chunk p
      short8 v = *reinterpret_cast<const short8*>(vbase + (size_t)(jb + r) * rs + p * 8);
#pragma unroll
      for (int e = 0; e < 8; ++e) {
        const int d = p * 8 + e;
        VTs[d * 64 + (r ^ ((d & 7) << 3))] = v[e];
      }
    }
    __syncthreads();

    // QK^T: S[q=g*4+reg][k=ks*16+fr]
    f32x4 S[4];
#pragma unroll
    for (int ks = 0; ks < 4; ++ks) S[ks] = (f32x4){0.f, 0.f, 0.f, 0.f};
#pragma unroll
    for (int ks = 0; ks < 4; ++ks) {
      const int kr = ks * 16 + fr;
#pragma unroll
      for (int dc = 0; dc < 2; ++dc) {
        const int d0 = dc * 32 + g * 8;
        short8 kf = *reinterpret_cast<const short8*>(&Ks[kr * 64 + (d0 ^ ((kr & 7) << 3))]);
        S[ks] = __builtin_amdgcn_mfma_f32_16x16x32_bf16(qf[dc], kf, S[ks], 0, 0, 0);
      }
    }

    // scale + mask + row-max
    const int qrow0 = t0 + w * 16 + g * 4;
    float rowmax[4];
#pragma unroll
    for (int r = 0; r < 4; ++r) rowmax[r] = -1e30f;
#pragma unroll
    for (int ks = 0; ks < 4; ++ks) {
      const int j = jb + ks * 16 + fr;
#pragma unroll
      for (int r = 0; r < 4; ++r) {
        float s = S[ks][r] * 0.125f;
        if (masked) {
          const int i = qrow0 + r;
          if (!((j <= i) && (j > i - 256))) s = -1e30f;
        }
        S[ks][r] = s;
        rowmax[r] = fmaxf(rowmax[r], s);
      }
    }
#pragma unroll
    for (int off = 1; off <= 8; off <<= 1)
#pragma unroll
      for (int r = 0; r < 4; ++r)
        rowmax[r] = fmaxf(rowmax[r], __shfl_xor(rowmax[r], off));

    float resc[4], psum[4];
#pragma unroll
    for (int r = 0; r < 4; ++r) {
      const float mn = fmaxf(m[r], rowmax[r]);
      resc[r] = __expf(m[r] - mn);   // both -1e30 -> exp(0)=1, acc/l are 0 anyway
      m[r] = mn;
      psum[r] = 0.f;
    }
#pragma unroll
    for (int ks = 0; ks < 4; ++ks) {
      const int j = jb + ks * 16 + fr;
#pragma unroll
      for (int r = 0; r < 4; ++r) {
        float p = __expf(S[ks][r] - m[r]);
        if (masked) {
          const int i = qrow0 + r;
          if (!((j <= i) && (j > i - 256))) p = 0.f;   // covers all-masked-row (m stuck at -1e30)
        }
        S[ks][r] = p;
        psum[r] += p;
      }
    }
#pragma unroll
    for (int off = 1; off <= 8; off <<= 1)
#pragma unroll
      for (int r = 0; r < 4; ++r) psum[r] += __shfl_xor(psum[r], off);
#pragma unroll
    for (int r = 0; r < 4; ++r) l[r] = l[r] * resc[r] + psum[r];
#pragma unroll
    for (int dt = 0; dt < 4; ++dt)
#pragma unroll
      for (int r = 0; r < 4; ++r) acc[dt][r] *= resc[r];

    // write P (bf16) to wave-private LDS rows
#pragma unroll
    for (int ks = 0; ks < 4; ++ks)
#pragma unroll
      for (int r = 0; r < 4; ++r) {
        const int prow = w * 16 + g * 4 + r;
        const int pcol = ks * 16 + fr;
        Ps[prow * 64 + (pcol ^ ((prow & 7) << 3))] = fbits(S[ks][r]);
      }

    // PV: A = P (16q x 32k), B = V (32k x 16d) via VTs
#pragma unroll
    for (int kc = 0; kc < 2; ++kc) {
      const int prow = w * 16 + fr;
      const int k0 = kc * 32 + g * 8;
      short8 pf = *reinterpret_cast<const short8*>(&Ps[prow * 64 + (k0 ^ ((prow & 7) << 3))]);
#pragma unroll
      for (int dt = 0; dt < 4; ++dt) {
        const int dr = dt * 16 + fr;
        short8 vf = *reinterpret_cast<const short8*>(&VTs[dr * 64 + (k0 ^ ((dr & 7) << 3))]);
        acc[dt] = __builtin_amdgcn_mfma_f32_16x16x32_bf16(pf, vf, acc[dt], 0, 0, 0);
      }
    }
  }

  // epilogue: O = acc / l
#pragma unroll
  for (int dt = 0; dt < 4; ++dt)
#pragma unroll
    for (int r = 0; r < 4; ++r) {
      const int i = t0 + w * 16 + g * 4 + r;
      const int d = dt * 16 + fr;
      ybuf[(size_t)i * kC + h * kHS + d] = acc[dt][r] / l[r];
    }
}

// ---------------- Compressed attention + gate mix (unchanged) ----------------
__global__ __launch_bounds__(64) void comp_attn_mix(
    const bf16* __restrict__ qkv, const bf16* __restrict__ kcomp,
    const bf16* __restrict__ vcomp, const bf16* __restrict__ gate,
    float* __restrict__ ybuf, int b)
{
  const int id = blockIdx.x;
  const int i = id % kT;
  const int h = id / kT;
  const int lane = threadIdx.x;
  const int c = h * kHS + lane;
  int nallow = (i + 15) >> 4;
  if (nallow > kNB) nallow = kNB;
  float yc = 0.f;
  if (nallow > 0) {
    __shared__ float qs[kHS];
    __shared__ float sc[128];
    const bf16* qrow = qkv + ((size_t)(b * kT + i)) * (3 * kC) + h * kHS;
    qs[lane] = b2f(qrow[lane]);
    __syncthreads();
    const bf16* kb = kcomp + ((size_t)(b * kNH + h)) * kNB * kHS;
    for (int n = lane; n < nallow; n += 64) {
      const bf16* kr = kb + (size_t)n * kHS;
      float dot = 0.f;
      for (int cc = 0; cc < kHS; ++cc) dot = fmaf(b2f(kr[cc]), qs[cc], dot);
      sc[n] = dot * 0.125f;
    }
    __syncthreads();
    float mm = -1e30f;
    for (int n = lane; n < nallow; n += 64) mm = fmaxf(mm, sc[n]);
#pragma unroll
    for (int off = 32; off >= 1; off >>= 1) mm = fmaxf(mm, __shfl_xor(mm, off));
    float ssum = 0.f;
    for (int n = lane; n < nallow; n += 64) { float e = expf(sc[n] - mm); sc[n] = e; ssum += e; }
#pragma unroll
    for (int off = 32; off >= 1; off >>= 1) ssum += __shfl_xor(ssum, off);
    __syncthreads();
    const bf16* vb = vcomp + ((size_t)(b * kNH + h)) * kNB * kHS + lane;
    float accv = 0.f;
    for (int n = 0; n < nallow; ++n)
      accv = fmaf(sc[n], b2f(vb[(size_t)n * kHS]), accv);
    yc = accv / ssum;
  }
  float gg  = b2f(gate[((size_t)(b * kT + i)) * kC + c]);
  float yl = ybuf[(size_t)i * kC + c];
  ybuf[(size_t)i * kC + c] = gg * yl + (1.f - gg) * yc;
}

extern "C" void kernel_launch(void* const* d_in, const int* in_sizes, int n_in,
                              void* d_out, int out_size, void* d_ws, size_t ws_size,
                              hipStream_t stream)
{
  (void)in_sizes; (void)n_in; (void)out_size; (void)ws_size;
  const float* x      = (const float*)d_in[0];
  const float* Wqkv   = (const float*)d_in[1];
  const float* bqkv   = (const float*)d_in[2];
  const float* Wcomp  = (const float*)d_in[3];
  const float* bcomp  = (const float*)d_in[4];
  const float* Wproj  = (const float*)d_in[5];
  const float* bproj  = (const float*)d_in[6];
  const float* k_fc1W = (const float*)d_in[7];
  const float* k_fc1b = (const float*)d_in[8];
  const float* k_fc2W = (const float*)d_in[9];
  const float* k_fc2b = (const float*)d_in[10];
  const float* k_rpW  = (const float*)d_in[11];
  const float* k_rpb  = (const float*)d_in[12];
  const float* k_wpe  = (const float*)d_in[13];
  const float* v_fc1W = (const float*)d_in[14];
  const float* v_fc1b = (const float*)d_in[15];
  const float* v_fc2W = (const float*)d_in[16];
  const float* v_fc2b = (const float*)d_in[17];
  const float* v_rpW  = (const float*)d_in[18];
  const float* v_rpb  = (const float*)d_in[19];
  const float* v_wpe  = (const float*)d_in[20];
  const float* Wg1    = (const float*)d_in[21];
  const float* bg1    = (const float*)d_in[22];
  const float* Wg2    = (const float*)d_in[23];
  const float* bg2    = (const float*)d_in[24];

  // ---- Workspace (peak 51,372,032 B, proven) ----
  char* wsb = (char*)d_ws;
  bf16*  big   = (bf16*)(wsb + 0);
  bf16*  kcomp = (bf16*)(wsb + 33554432);
  bf16*  vcomp = (bf16*)(wsb + 34074624);
  bf16*  gate  = (bf16*)(wsb + 34594816);
  float* ybuf  = (float*)(wsb + 42983424);
  float* out   = (float*)d_out;

  gemm_mfma<1, float, bf16><<<dim3(4096 / 128, 4096 / 128), 256, 0, stream>>>(
      x, Wg1, bg1, big, 4096, 4096, 1024);
  gemm_mfma<3, bf16, bf16><<<dim3(1024 / 128, 4096 / 128), 256, 0, stream>>>(
      big, Wg2, bg2, gate, 4096, 1024, 4096);
  gemm_mfma<0, float, bf16><<<dim3(2048 / 128, 4096 / 128), 256, 0, stream>>>(
      x, Wcomp, bcomp, big, 4096, 2048, 1024);
  comp_mlp<<<kB * kNH * kNB, 64, 0, stream>>>(big, 0, k_fc1W, k_fc1b, k_fc2W, k_fc2b, k_rpW, k_rpb, k_wpe, kcomp);
  comp_mlp<<<kB * kNH * kNB, 64, 0, stream>>>(big, 1, v_fc1W, v_fc1b, v_fc2W, v_fc2b, v_rpW, v_rpb, v_wpe, vcomp);
  gemm_mfma<0, float, bf16><<<dim3(3072 / 128, 4096 / 128), 256, 0, stream>>>(
      x, Wqkv, bqkv, big, 4096, 3072, 1024);
  for (int b = 0; b < kB; ++b) {
    local_attn_mfma<<<dim3(kT / 64, kNH), 256, 0, stream>>>(big, ybuf, b);
    comp_attn_mix<<<kNH * kT, 64, 0, stream>>>(big, kcomp, vcomp, gate, ybuf, b);
    gemm_mfma<0, float, float><<<dim3(1024 / 128, 2048 / 128), 256, 0, stream>>>(
        ybuf, Wproj, bproj, out + (size_t)b * 2048 * kC, 2048, 1024, 1024);
  }
}

// Round 9
// 617.649 us; speedup vs baseline: 5.9339x; 1.1211x over previous
//
#include <hip/hip_runtime.h>
#include <hip/hip_bf16.h>

typedef __hip_bfloat16 bf16;

constexpr int kB = 2, kT = 2048, kC = 1024, kNH = 16, kHS = 64;
constexpr int kL = 32, kST = 16, kWIN = 256;
constexpr int kNB = (kT - kL) / kST + 1;   // 127
constexpr int kM = kB * kT;                // 4096

typedef __attribute__((ext_vector_type(8))) short short8;   // bf16 MFMA A/B frag (4 VGPRs)
typedef __attribute__((ext_vector_type(4))) short short4v;
typedef __attribute__((ext_vector_type(4))) float f32x4;

__device__ __forceinline__ float b2f(bf16 v) { return __bfloat162float(v); }
__device__ __forceinline__ bf16  f2b(float v) { return __float2bfloat16(v); }
__device__ __forceinline__ float gelu_f(float v) { return 0.5f * v * (1.0f + erff(v * 0.70710678118654752f)); }
__device__ __forceinline__ short fbits(float v) {
  return (short)__builtin_bit_cast(unsigned short, f2b(v));
}
// async global->LDS, 16 bytes per lane (dest = wave-uniform base + lane*16)
__device__ __forceinline__ void gl16(const bf16* g, bf16* l) {
  __builtin_amdgcn_global_load_lds(
      (const __attribute__((address_space(1))) void*)g,
      (__attribute__((address_space(3))) void*)l, 16, 0, 0);
}

// ---------------- fp32 -> bf16 conversion (vectorized, grid-stride) ----------------
__global__ __launch_bounds__(256) void f32_to_bf16(const float* __restrict__ src,
                                                   bf16* __restrict__ dst, int n4) {
  int i = blockIdx.x * 256 + threadIdx.x;
  const int stride = gridDim.x * 256;
  for (; i < n4; i += stride) {
    float4 v = ((const float4*)src)[i];
    short4v w; w.x = fbits(v.x); w.y = fbits(v.y); w.z = fbits(v.z); w.w = fbits(v.w);
    ((short4v*)dst)[i] = w;
  }
}

// ---------------- all-bf16 MFMA GEMM, m97 structure ----------------
// Y(M,N) = EPI(X(M,K) @ W(N,K)^T + bias). 128x128 tile, BK=64, 4 waves (2x2),
// global_load_lds width-16 staging into linear LDS [128][64], XCD-swizzled blocks.
template<int EPI, typename TY>
__global__ __launch_bounds__(256) void gemm_bf16(
    const bf16* __restrict__ X, const bf16* __restrict__ W,
    const float* __restrict__ bias, TY* __restrict__ Y,
    int M, int N, int K, int nbx)
{
  __shared__ __align__(16) bf16 As[128 * 64];
  __shared__ __align__(16) bf16 Bs[128 * 64];
  const int nwg = gridDim.x;                       // divisible by 8 for all our shapes
  const int bid = blockIdx.x;
  const int swz = (bid & 7) * (nwg >> 3) + (bid >> 3);   // XCD-contiguous remap
  const int bm = (swz / nbx) * 128;
  const int bn = (swz % nbx) * 128;
  const int tid = threadIdx.x;
  const int lane = tid & 63;
  const int w = tid >> 6;
  const int wr = w >> 1, wc = w & 1;
  const int fr = lane & 15, q = lane >> 4;
  const int srow = lane >> 3;                      // 0..7 within 8-row chunk
  const int scol = (lane & 7) * 8;                 // bf16 col of 16B slice

  f32x4 acc[4][4];
#pragma unroll
  for (int i = 0; i < 4; ++i)
#pragma unroll
    for (int j = 0; j < 4; ++j) acc[i][j] = (f32x4){0.f, 0.f, 0.f, 0.f};

  const bf16* Xb = X + (size_t)bm * K;
  const bf16* Wb = W + (size_t)bn * K;

  for (int k0 = 0; k0 < K; k0 += 64) {
    __syncthreads();
#pragma unroll
    for (int i = 0; i < 4; ++i) {
      const int r = w * 32 + i * 8 + srow;         // wave w stages rows [w*32, w*32+32)
      gl16(Xb + (size_t)r * K + k0 + scol, &As[r * 64 + scol]);
      gl16(Wb + (size_t)r * K + k0 + scol, &Bs[r * 64 + scol]);
    }
    __syncthreads();                               // compiler drains vmcnt here
#pragma unroll
    for (int kk = 0; kk < 2; ++kk) {
      short8 af[4], bfr[4];
#pragma unroll
      for (int i = 0; i < 4; ++i)
        af[i] = *reinterpret_cast<const short8*>(&As[(wr * 64 + i * 16 + fr) * 64 + kk * 32 + q * 8]);
#pragma unroll
      for (int j = 0; j < 4; ++j)
        bfr[j] = *reinterpret_cast<const short8*>(&Bs[(wc * 64 + j * 16 + fr) * 64 + kk * 32 + q * 8]);
#pragma unroll
      for (int i = 0; i < 4; ++i)
#pragma unroll
        for (int j = 0; j < 4; ++j)
          acc[i][j] = __builtin_amdgcn_mfma_f32_16x16x32_bf16(af[i], bfr[j], acc[i][j], 0, 0, 0);
    }
  }

#pragma unroll
  for (int j = 0; j < 4; ++j) {
    const int gcol = bn + wc * 64 + j * 16 + fr;
    const float bv = bias[gcol];
#pragma unroll
    for (int i = 0; i < 4; ++i) {
      const int grow0 = bm + wr * 64 + i * 16 + q * 4;
#pragma unroll
      for (int r = 0; r < 4; ++r) {
        float v = acc[i][j][r] + bv;
        if (EPI == 1) v = gelu_f(v);
        if (EPI == 3) v = 1.f / (1.f + expf(-v));
        if constexpr (sizeof(TY) == 2) Y[(size_t)(grow0 + r) * N + gcol] = f2b(v);
        else                           ((float*)Y)[(size_t)(grow0 + r) * N + gcol] = v;
      }
    }
  }
}

// ---------------- Compression MLP (unchanged) ----------------
__global__ __launch_bounds__(64) void comp_mlp(
    const bf16* __restrict__ kvbuf, int s,
    const float* __restrict__ fc1W, const float* __restrict__ fc1b,
    const float* __restrict__ fc2W, const float* __restrict__ fc2b,
    const float* __restrict__ rpW,  const float* __restrict__ rpb,
    const float* __restrict__ wpe,  bf16* __restrict__ outp)
{
  __shared__ float s_fc1W[128 * 32];
  __shared__ float s_fc1b[128];
  __shared__ float s_fc2W[128];
  const int id = blockIdx.x;
  const int blk = id % kNB;
  const int h = (id / kNB) % kNH;
  const int b = id / (kNB * kNH);
  const int d = threadIdx.x;
  for (int i = d; i < 128 * 32; i += 64) s_fc1W[i] = fc1W[i];
  for (int i = d; i < 128; i += 64) { s_fc1b[i] = fc1b[i]; s_fc2W[i] = fc2W[i]; }
  __syncthreads();

  float xu[kL], xpe[kL];
  const int t0 = blk * kST;
  const bf16* base = kvbuf + ((size_t)(b * kT + t0) * (2 * kC)) + (size_t)s * kC + h * kHS + d;
#pragma unroll
  for (int l = 0; l < kL; ++l) {
    float u = b2f(base[(size_t)l * (2 * kC)]);
    xu[l] = u;
    xpe[l] = u + wpe[l * kHS + d];
  }
  float out = fc2b[0];
  for (int j = 0; j < 128; ++j) {
    float a = s_fc1b[j];
#pragma unroll
    for (int l = 0; l < kL; ++l) a = fmaf(xpe[l], s_fc1W[j * kL + l], a);
    out = fmaf(gelu_f(a), s_fc2W[j], out);
  }
  float res = rpb[0];
#pragma unroll
  for (int l = 0; l < kL; ++l) res = fmaf(xu[l], rpW[l], res);
  float r = out + res;
  r = fminf(3.0f, fmaxf(-3.0f, r));
  outp[((size_t)(b * kNH + h) * kNB + blk) * kHS + d] = f2b(r);
}

// ---------------- Local sliding-window attention: MFMA flash (ybuf now bf16) ----------------
__global__ __launch_bounds__(256) void local_attn_mfma(
    const bf16* __restrict__ qkv, bf16* __restrict__ ybuf, int b)
{
  __shared__ __align__(16) short Qs[64 * 64];
  __shared__ __align__(16) short Ks[64 * 64];
  __shared__ __align__(16) short VTs[64 * 64];
  __shared__ __align__(16) short Ps[64 * 64];
  const int tid = threadIdx.x;
  const int lane = tid & 63;
  const int w = tid >> 6;
  const int fr = lane & 15;
  const int g  = lane >> 4;
  const int h  = blockIdx.y;
  const int t0 = blockIdx.x * 64;
  const size_t rs = 3 * kC;
  const bf16* qbase = qkv + ((size_t)b * kT) * rs + h * kHS;
  const bf16* kbase = qbase + kC;
  const bf16* vbase = qbase + 2 * kC;

  for (int c = tid; c < 512; c += 256) {
    const int r = c >> 3, p = c & 7;
    short8 v = *reinterpret_cast<const short8*>(qbase + (size_t)(t0 + r) * rs + p * 8);
    *reinterpret_cast<short8*>(&Qs[r * 64 + ((p ^ (r & 7)) << 3)]) = v;
  }
  __syncthreads();
  short8 qf[2];
  {
    const int r = w * 16 + fr;
#pragma unroll
    for (int dc = 0; dc < 2; ++dc) {
      const int d0 = dc * 32 + g * 8;
      qf[dc] = *reinterpret_cast<const short8*>(&Qs[r * 64 + (d0 ^ ((r & 7) << 3))]);
    }
  }

  f32x4 acc[4];
  float m[4], l[4];
#pragma unroll
  for (int r = 0; r < 4; ++r) { m[r] = -1e30f; l[r] = 0.f; }
#pragma unroll
  for (int dt = 0; dt < 4; ++dt) acc[dt] = (f32x4){0.f, 0.f, 0.f, 0.f};

  const int jb0 = (t0 >= 256) ? (t0 - 256) : 0;
  for (int jb = jb0; jb <= t0; jb += 64) {
    const bool masked = (jb == t0 - 256) || (jb == t0);
    __syncthreads();
    for (int c = tid; c < 512; c += 256) {
      const int r = c >> 3, p = c & 7;
      short8 v = *reinterpret_cast<const short8*>(kbase + (size_t)(jb + r) * rs + p * 8);
      *reinterpret_cast<short8*>(&Ks[r * 64 + ((p ^ (r & 7)) << 3)]) = v;
    }
    for (int c = tid; c < 512; c += 256) {
      const int r = c >> 3, p = c & 7;
      short8 v = *reinterpret_cast<const short8*>(vbase + (size_t)(jb + r) * rs + p * 8);
#pragma unroll
      for (int e = 0; e < 8; ++e) {
        const int d = p * 8 + e;
        VTs[d * 64 + (r ^ ((d & 7) << 3))] = v[e];
      }
    }
    __syncthreads();

    f32x4 S[4];
#pragma unroll
    for (int ks = 0; ks < 4; ++ks) S[ks] = (f32x4){0.f, 0.f, 0.f, 0.f};
#pragma unroll
    for (int ks = 0; ks < 4; ++ks) {
      const int kr = ks * 16 + fr;
#pragma unroll
      for (int dc = 0; dc < 2; ++dc) {
        const int d0 = dc * 32 + g * 8;
        short8 kf = *reinterpret_cast<const short8*>(&Ks[kr * 64 + (d0 ^ ((kr & 7) << 3))]);
        S[ks] = __builtin_amdgcn_mfma_f32_16x16x32_bf16(qf[dc], kf, S[ks], 0, 0, 0);
      }
    }

    const int qrow0 = t0 + w * 16 + g * 4;
    float rowmax[4];
#pragma unroll
    for (int r = 0; r < 4; ++r) rowmax[r] = -1e30f;
#pragma unroll
    for (int ks = 0; ks < 4; ++ks) {
      const int j = jb + ks * 16 + fr;
#pragma unroll
      for (int r = 0; r < 4; ++r) {
        float s = S[ks][r] * 0.125f;
        if (masked) {
          const int i = qrow0 + r;
          if (!((j <= i) && (j > i - 256))) s = -1e30f;
        }
        S[ks][r] = s;
        rowmax[r] = fmaxf(rowmax[r], s);
      }
    }
#pragma unroll
    for (int off = 1; off <= 8; off <<= 1)
#pragma unroll
      for (int r = 0; r < 4; ++r)
        rowmax[r] = fmaxf(rowmax[r], __shfl_xor(rowmax[r], off));

    float resc[4], psum[4];
#pragma unroll
    for (int r = 0; r < 4; ++r) {
      const float mn = fmaxf(m[r], rowmax[r]);
      resc[r] = __expf(m[r] - mn);
      m[r] = mn;
      psum[r] = 0.f;
    }
#pragma unroll
    for (int ks = 0; ks < 4; ++ks) {
      const int j = jb + ks * 16 + fr;
#pragma unroll
      for (int r = 0; r < 4; ++r) {
        float p = __expf(S[ks][r] - m[r]);
        if (masked) {
          const int i = qrow0 + r;
          if (!((j <= i) && (j > i - 256))) p = 0.f;
        }
        S[ks][r] = p;
        psum[r] += p;
      }
    }
#pragma unroll
    for (int off = 1; off <= 8; off <<= 1)
#pragma unroll
      for (int r = 0; r < 4; ++r) psum[r] += __shfl_xor(psum[r], off);
#pragma unroll
    for (int r = 0; r < 4; ++r) l[r] = l[r] * resc[r] + psum[r];
#pragma unroll
    for (int dt = 0; dt < 4; ++dt)
#pragma unroll
      for (int r = 0; r < 4; ++r) acc[dt][r] *= resc[r];

#pragma unroll
    for (int ks = 0; ks < 4; ++ks)
#pragma unroll
      for (int r = 0; r < 4; ++r) {
        const int prow = w * 16 + g * 4 + r;
        const int pcol = ks * 16 + fr;
        Ps[prow * 64 + (pcol ^ ((prow & 7) << 3))] = fbits(S[ks][r]);
      }

#pragma unroll
    for (int kc = 0; kc < 2; ++kc) {
      const int prow = w * 16 + fr;
      const int k0 = kc * 32 + g * 8;
      short8 pf = *reinterpret_cast<const short8*>(&Ps[prow * 64 + (k0 ^ ((prow & 7) << 3))]);
#pragma unroll
      for (int dt = 0; dt < 4; ++dt) {
        const int dr = dt * 16 + fr;
        short8 vf = *reinterpret_cast<const short8*>(&VTs[dr * 64 + (k0 ^ ((dr & 7) << 3))]);
        acc[dt] = __builtin_amdgcn_mfma_f32_16x16x32_bf16(pf, vf, acc[dt], 0, 0, 0);
      }
    }
  }

#pragma unroll
  for (int dt = 0; dt < 4; ++dt)
#pragma unroll
    for (int r = 0; r < 4; ++r) {
      const int i = t0 + w * 16 + g * 4 + r;
      const int d = dt * 16 + fr;
      ybuf[(size_t)i * kC + h * kHS + d] = f2b(acc[dt][r] / l[r]);
    }
}

// ---------------- Compressed attention + gate mix (ybuf/gate bf16) ----------------
__global__ __launch_bounds__(64) void comp_attn_mix(
    const bf16* __restrict__ qkv, const bf16* __restrict__ kcomp,
    const bf16* __restrict__ vcomp, const bf16* __restrict__ gate,
    bf16* __restrict__ ybuf, int b)
{
  const int id = blockIdx.x;
  const int i = id % kT;
  const int h = id / kT;
  const int lane = threadIdx.x;
  const int c = h * kHS + lane;
  int nallow = (i + 15) >> 4;
  if (nallow > kNB) nallow = kNB;
  float yc = 0.f;
  if (nallow > 0) {
    __shared__ float qs[kHS];
    __shared__ float sc[128];
    const bf16* qrow = qkv + ((size_t)(b * kT + i)) * (3 * kC) + h * kHS;
    qs[lane] = b2f(qrow[lane]);
    __syncthreads();
    const bf16* kb = kcomp + ((size_t)(b * kNH + h)) * kNB * kHS;
    for (int n = lane; n < nallow; n += 64) {
      const bf16* kr = kb + (size_t)n * kHS;
      float dot = 0.f;
      for (int cc = 0; cc < kHS; ++cc) dot = fmaf(b2f(kr[cc]), qs[cc], dot);
      sc[n] = dot * 0.125f;
    }
    __syncthreads();
    float mm = -1e30f;
    for (int n = lane; n < nallow; n += 64) mm = fmaxf(mm, sc[n]);
#pragma unroll
    for (int off = 32; off >= 1; off >>= 1) mm = fmaxf(mm, __shfl_xor(mm, off));
    float ssum = 0.f;
    for (int n = lane; n < nallow; n += 64) { float e = expf(sc[n] - mm); sc[n] = e; ssum += e; }
#pragma unroll
    for (int off = 32; off >= 1; off >>= 1) ssum += __shfl_xor(ssum, off);
    __syncthreads();
    const bf16* vb = vcomp + ((size_t)(b * kNH + h)) * kNB * kHS + lane;
    float accv = 0.f;
    for (int n = 0; n < nallow; ++n)
      accv = fmaf(sc[n], b2f(vb[(size_t)n * kHS]), accv);
    yc = accv / ssum;
  }
  float gg = b2f(gate[((size_t)(b * kT + i)) * kC + c]);
  float yl = b2f(ybuf[(size_t)i * kC + c]);
  ybuf[(size_t)i * kC + c] = f2b(gg * yl + (1.f - gg) * yc);
}

extern "C" void kernel_launch(void* const* d_in, const int* in_sizes, int n_in,
                              void* d_out, int out_size, void* d_ws, size_t ws_size,
                              hipStream_t stream)
{
  (void)in_sizes; (void)n_in; (void)out_size; (void)ws_size; (void)kM; (void)kWIN;
  const float* x      = (const float*)d_in[0];
  const float* Wqkv   = (const float*)d_in[1];
  const float* bqkv   = (const float*)d_in[2];
  const float* Wcomp  = (const float*)d_in[3];
  const float* bcomp  = (const float*)d_in[4];
  const float* Wproj  = (const float*)d_in[5];
  const float* bproj  = (const float*)d_in[6];
  const float* k_fc1W = (const float*)d_in[7];
  const float* k_fc1b = (const float*)d_in[8];
  const float* k_fc2W = (const float*)d_in[9];
  const float* k_fc2b = (const float*)d_in[10];
  const float* k_rpW  = (const float*)d_in[11];
  const float* k_rpb  = (const float*)d_in[12];
  const float* k_wpe  = (const float*)d_in[13];
  const float* v_fc1W = (const float*)d_in[14];
  const float* v_fc1b = (const float*)d_in[15];
  const float* v_fc2W = (const float*)d_in[16];
  const float* v_fc2b = (const float*)d_in[17];
  const float* v_rpW  = (const float*)d_in[18];
  const float* v_rpb  = (const float*)d_in[19];
  const float* v_wpe  = (const float*)d_in[20];
  const float* Wg1    = (const float*)d_in[21];
  const float* bg1    = (const float*)d_in[22];
  const float* Wg2    = (const float*)d_in[23];
  const float* bg2    = (const float*)d_in[24];

  // ---- Workspace (peak 51,372,032 B, identical to proven footprint) ----
  // xbf   [0, 8388608)           bf16 x
  // wscr  [8388608, 16777216)    bf16 current weight
  // big   [16777216, 50331648)   bf16 g1(33.5M) -> kv(16.8M) -> qkv(25.2M), time-disjoint
  //   ybuf [41943040, 46137344)  bf16 (T,C), lives in big tail during attn phase
  // kcomp [50331648, 50851840)
  // vcomp [50851840, 51372032)
  // gate lives in d_out bytes [8388608, 16777216) as bf16 (proj b=1 overwrites last).
  char* wsb = (char*)d_ws;
  bf16* xbf   = (bf16*)(wsb + 0);
  bf16* wscr  = (bf16*)(wsb + 8388608);
  bf16* big   = (bf16*)(wsb + 16777216);
  bf16* ybuf  = (bf16*)(wsb + 41943040);
  bf16* kcomp = (bf16*)(wsb + 50331648);
  bf16* vcomp = (bf16*)(wsb + 50851840);
  bf16* gate  = (bf16*)((char*)d_out + 8388608);
  float* out  = (float*)d_out;

  const int cg = 2048;
  f32_to_bf16<<<cg, 256, 0, stream>>>(x, xbf, 1048576);
  // 1) g1 = gelu(x@Wg1) -> big
  f32_to_bf16<<<cg, 256, 0, stream>>>(Wg1, wscr, 1048576);
  gemm_bf16<1, bf16><<<1024, 256, 0, stream>>>(xbf, wscr, bg1, big, 4096, 4096, 1024, 32);
  // 2) gate = sigmoid(g1@Wg2) -> d_out[8.4M..16.8M)
  f32_to_bf16<<<cg, 256, 0, stream>>>(Wg2, wscr, 1048576);
  gemm_bf16<3, bf16><<<256, 256, 0, stream>>>(big, wscr, bg2, gate, 4096, 1024, 4096, 8);
  // 3) kv -> big (g1 dead); compression MLPs
  f32_to_bf16<<<cg, 256, 0, stream>>>(Wcomp, wscr, 524288);
  gemm_bf16<0, bf16><<<512, 256, 0, stream>>>(xbf, wscr, bcomp, big, 4096, 2048, 1024, 16);
  comp_mlp<<<kB * kNH * kNB, 64, 0, stream>>>(big, 0, k_fc1W, k_fc1b, k_fc2W, k_fc2b, k_rpW, k_rpb, k_wpe, kcomp);
  comp_mlp<<<kB * kNH * kNB, 64, 0, stream>>>(big, 1, v_fc1W, v_fc1b, v_fc2W, v_fc2b, v_rpW, v_rpb, v_wpe, vcomp);
  // 4) qkv -> big (kv dead)
  f32_to_bf16<<<cg, 256, 0, stream>>>(Wqkv, wscr, 786432);
  gemm_bf16<0, bf16><<<768, 256, 0, stream>>>(xbf, wscr, bqkv, big, 4096, 3072, 1024, 24);
  // 5) Wproj -> wscr once; per batch: attn -> ybuf, mix in-place, proj -> d_out
  f32_to_bf16<<<cg, 256, 0, stream>>>(Wproj, wscr, 262144);
  for (int b = 0; b < kB; ++b) {
    local_attn_mfma<<<dim3(kT / 64, kNH), 256, 0, stream>>>(big, ybuf, b);
    comp_attn_mix<<<kNH * kT, 64, 0, stream>>>(big, kcomp, vcomp, gate, ybuf, b);
    gemm_bf16<0, float><<<128, 256, 0, stream>>>(ybuf, wscr, bproj, out + (size_t)b * 2048 * kC, 2048, 1024, 1024, 8);
  }
}

// Round 10
// 523.128 us; speedup vs baseline: 7.0061x; 1.1807x over previous
//
#include <hip/hip_runtime.h>
#include <hip/hip_bf16.h>

typedef __hip_bfloat16 bf16;

constexpr int kB = 2, kT = 2048, kC = 1024, kNH = 16, kHS = 64;
constexpr int kL = 32, kST = 16, kWIN = 256;
constexpr int kNB = (kT - kL) / kST + 1;   // 127
constexpr int kM = kB * kT;                // 4096

typedef __attribute__((ext_vector_type(8))) short short8;   // bf16 MFMA A/B frag (4 VGPRs)
typedef __attribute__((ext_vector_type(4))) short short4v;
typedef __attribute__((ext_vector_type(4))) float f32x4;

__device__ __forceinline__ float b2f(bf16 v) { return __bfloat162float(v); }
__device__ __forceinline__ bf16  f2b(float v) { return __float2bfloat16(v); }
__device__ __forceinline__ float gelu_f(float v) { return 0.5f * v * (1.0f + erff(v * 0.70710678118654752f)); }
__device__ __forceinline__ short fbits(float v) {
  return (short)__builtin_bit_cast(unsigned short, f2b(v));
}
// async global->LDS, 16 bytes per lane (dest = wave-uniform base + lane*16)
__device__ __forceinline__ void gl16(const bf16* g, bf16* l) {
  __builtin_amdgcn_global_load_lds(
      (const __attribute__((address_space(1))) void*)g,
      (__attribute__((address_space(3))) void*)l, 16, 0, 0);
}

// ---------------- fp32 -> bf16 conversion (vectorized, grid-stride) ----------------
__global__ __launch_bounds__(256) void f32_to_bf16(const float* __restrict__ src,
                                                   bf16* __restrict__ dst, int n4) {
  int i = blockIdx.x * 256 + threadIdx.x;
  const int stride = gridDim.x * 256;
  for (; i < n4; i += stride) {
    float4 v = ((const float4*)src)[i];
    short4v w; w.x = fbits(v.x); w.y = fbits(v.y); w.z = fbits(v.z); w.w = fbits(v.w);
    ((short4v*)dst)[i] = w;
  }
}

// ---------------- all-bf16 MFMA GEMM, m97 structure (unchanged from R9) ----------------
template<int EPI, typename TY>
__global__ __launch_bounds__(256) void gemm_bf16(
    const bf16* __restrict__ X, const bf16* __restrict__ W,
    const float* __restrict__ bias, TY* __restrict__ Y,
    int M, int N, int K, int nbx)
{
  __shared__ __align__(16) bf16 As[128 * 64];
  __shared__ __align__(16) bf16 Bs[128 * 64];
  const int nwg = gridDim.x;
  const int bid = blockIdx.x;
  const int swz = (bid & 7) * (nwg >> 3) + (bid >> 3);
  const int bm = (swz / nbx) * 128;
  const int bn = (swz % nbx) * 128;
  const int tid = threadIdx.x;
  const int lane = tid & 63;
  const int w = tid >> 6;
  const int wr = w >> 1, wc = w & 1;
  const int fr = lane & 15, q = lane >> 4;
  const int srow = lane >> 3;
  const int scol = (lane & 7) * 8;

  f32x4 acc[4][4];
#pragma unroll
  for (int i = 0; i < 4; ++i)
#pragma unroll
    for (int j = 0; j < 4; ++j) acc[i][j] = (f32x4){0.f, 0.f, 0.f, 0.f};

  const bf16* Xb = X + (size_t)bm * K;
  const bf16* Wb = W + (size_t)bn * K;

  for (int k0 = 0; k0 < K; k0 += 64) {
    __syncthreads();
#pragma unroll
    for (int i = 0; i < 4; ++i) {
      const int r = w * 32 + i * 8 + srow;
      gl16(Xb + (size_t)r * K + k0 + scol, &As[r * 64 + scol]);
      gl16(Wb + (size_t)r * K + k0 + scol, &Bs[r * 64 + scol]);
    }
    __syncthreads();
#pragma unroll
    for (int kk = 0; kk < 2; ++kk) {
      short8 af[4], bfr[4];
#pragma unroll
      for (int i = 0; i < 4; ++i)
        af[i] = *reinterpret_cast<const short8*>(&As[(wr * 64 + i * 16 + fr) * 64 + kk * 32 + q * 8]);
#pragma unroll
      for (int j = 0; j < 4; ++j)
        bfr[j] = *reinterpret_cast<const short8*>(&Bs[(wc * 64 + j * 16 + fr) * 64 + kk * 32 + q * 8]);
#pragma unroll
      for (int i = 0; i < 4; ++i)
#pragma unroll
        for (int j = 0; j < 4; ++j)
          acc[i][j] = __builtin_amdgcn_mfma_f32_16x16x32_bf16(af[i], bfr[j], acc[i][j], 0, 0, 0);
    }
  }

#pragma unroll
  for (int j = 0; j < 4; ++j) {
    const int gcol = bn + wc * 64 + j * 16 + fr;
    const float bv = bias[gcol];
#pragma unroll
    for (int i = 0; i < 4; ++i) {
      const int grow0 = bm + wr * 64 + i * 16 + q * 4;
#pragma unroll
      for (int r = 0; r < 4; ++r) {
        float v = acc[i][j][r] + bv;
        if (EPI == 1) v = gelu_f(v);
        if (EPI == 3) v = 1.f / (1.f + expf(-v));
        if constexpr (sizeof(TY) == 2) Y[(size_t)(grow0 + r) * N + gcol] = f2b(v);
        else                           ((float*)Y)[(size_t)(grow0 + r) * N + gcol] = v;
      }
    }
  }
}

// ---------------- Compression MLP (unchanged) ----------------
__global__ __launch_bounds__(64) void comp_mlp(
    const bf16* __restrict__ kvbuf, int s,
    const float* __restrict__ fc1W, const float* __restrict__ fc1b,
    const float* __restrict__ fc2W, const float* __restrict__ fc2b,
    const float* __restrict__ rpW,  const float* __restrict__ rpb,
    const float* __restrict__ wpe,  bf16* __restrict__ outp)
{
  __shared__ float s_fc1W[128 * 32];
  __shared__ float s_fc1b[128];
  __shared__ float s_fc2W[128];
  const int id = blockIdx.x;
  const int blk = id % kNB;
  const int h = (id / kNB) % kNH;
  const int b = id / (kNB * kNH);
  const int d = threadIdx.x;
  for (int i = d; i < 128 * 32; i += 64) s_fc1W[i] = fc1W[i];
  for (int i = d; i < 128; i += 64) { s_fc1b[i] = fc1b[i]; s_fc2W[i] = fc2W[i]; }
  __syncthreads();

  float xu[kL], xpe[kL];
  const int t0 = blk * kST;
  const bf16* base = kvbuf + ((size_t)(b * kT + t0) * (2 * kC)) + (size_t)s * kC + h * kHS + d;
#pragma unroll
  for (int l = 0; l < kL; ++l) {
    float u = b2f(base[(size_t)l * (2 * kC)]);
    xu[l] = u;
    xpe[l] = u + wpe[l * kHS + d];
  }
  float out = fc2b[0];
  for (int j = 0; j < 128; ++j) {
    float a = s_fc1b[j];
#pragma unroll
    for (int l = 0; l < kL; ++l) a = fmaf(xpe[l], s_fc1W[j * kL + l], a);
    out = fmaf(gelu_f(a), s_fc2W[j], out);
  }
  float res = rpb[0];
#pragma unroll
  for (int l = 0; l < kL; ++l) res = fmaf(xu[l], rpW[l], res);
  float r = out + res;
  r = fminf(3.0f, fmaxf(-3.0f, r));
  outp[((size_t)(b * kNH + h) * kNB + blk) * kHS + d] = f2b(r);
}

// ---------------- Local sliding-window attention: MFMA flash (unchanged) ----------------
__global__ __launch_bounds__(256) void local_attn_mfma(
    const bf16* __restrict__ qkv, bf16* __restrict__ ybuf, int b)
{
  __shared__ __align__(16) short Qs[64 * 64];
  __shared__ __align__(16) short Ks[64 * 64];
  __shared__ __align__(16) short VTs[64 * 64];
  __shared__ __align__(16) short Ps[64 * 64];
  const int tid = threadIdx.x;
  const int lane = tid & 63;
  const int w = tid >> 6;
  const int fr = lane & 15;
  const int g  = lane >> 4;
  const int h  = blockIdx.y;
  const int t0 = blockIdx.x * 64;
  const size_t rs = 3 * kC;
  const bf16* qbase = qkv + ((size_t)b * kT) * rs + h * kHS;
  const bf16* kbase = qbase + kC;
  const bf16* vbase = qbase + 2 * kC;

  for (int c = tid; c < 512; c += 256) {
    const int r = c >> 3, p = c & 7;
    short8 v = *reinterpret_cast<const short8*>(qbase + (size_t)(t0 + r) * rs + p * 8);
    *reinterpret_cast<short8*>(&Qs[r * 64 + ((p ^ (r & 7)) << 3)]) = v;
  }
  __syncthreads();
  short8 qf[2];
  {
    const int r = w * 16 + fr;
#pragma unroll
    for (int dc = 0; dc < 2; ++dc) {
      const int d0 = dc * 32 + g * 8;
      qf[dc] = *reinterpret_cast<const short8*>(&Qs[r * 64 + (d0 ^ ((r & 7) << 3))]);
    }
  }

  f32x4 acc[4];
  float m[4], l[4];
#pragma unroll
  for (int r = 0; r < 4; ++r) { m[r] = -1e30f; l[r] = 0.f; }
#pragma unroll
  for (int dt = 0; dt < 4; ++dt) acc[dt] = (f32x4){0.f, 0.f, 0.f, 0.f};

  const int jb0 = (t0 >= 256) ? (t0 - 256) : 0;
  for (int jb = jb0; jb <= t0; jb += 64) {
    const bool masked = (jb == t0 - 256) || (jb == t0);
    __syncthreads();
    for (int c = tid; c < 512; c += 256) {
      const int r = c >> 3, p = c & 7;
      short8 v = *reinterpret_cast<const short8*>(kbase + (size_t)(jb + r) * rs + p * 8);
      *reinterpret_cast<short8*>(&Ks[r * 64 + ((p ^ (r & 7)) << 3)]) = v;
    }
    for (int c = tid; c < 512; c += 256) {
      const int r = c >> 3, p = c & 7;
      short8 v = *reinterpret_cast<const short8*>(vbase + (size_t)(jb + r) * rs + p * 8);
#pragma unroll
      for (int e = 0; e < 8; ++e) {
        const int d = p * 8 + e;
        VTs[d * 64 + (r ^ ((d & 7) << 3))] = v[e];
      }
    }
    __syncthreads();

    f32x4 S[4];
#pragma unroll
    for (int ks = 0; ks < 4; ++ks) S[ks] = (f32x4){0.f, 0.f, 0.f, 0.f};
#pragma unroll
    for (int ks = 0; ks < 4; ++ks) {
      const int kr = ks * 16 + fr;
#pragma unroll
      for (int dc = 0; dc < 2; ++dc) {
        const int d0 = dc * 32 + g * 8;
        short8 kf = *reinterpret_cast<const short8*>(&Ks[kr * 64 + (d0 ^ ((kr & 7) << 3))]);
        S[ks] = __builtin_amdgcn_mfma_f32_16x16x32_bf16(qf[dc], kf, S[ks], 0, 0, 0);
      }
    }

    const int qrow0 = t0 + w * 16 + g * 4;
    float rowmax[4];
#pragma unroll
    for (int r = 0; r < 4; ++r) rowmax[r] = -1e30f;
#pragma unroll
    for (int ks = 0; ks < 4; ++ks) {
      const int j = jb + ks * 16 + fr;
#pragma unroll
      for (int r = 0; r < 4; ++r) {
        float s = S[ks][r] * 0.125f;
        if (masked) {
          const int i = qrow0 + r;
          if (!((j <= i) && (j > i - 256))) s = -1e30f;
        }
        S[ks][r] = s;
        rowmax[r] = fmaxf(rowmax[r], s);
      }
    }
#pragma unroll
    for (int off = 1; off <= 8; off <<= 1)
#pragma unroll
      for (int r = 0; r < 4; ++r)
        rowmax[r] = fmaxf(rowmax[r], __shfl_xor(rowmax[r], off));

    float resc[4], psum[4];
#pragma unroll
    for (int r = 0; r < 4; ++r) {
      const float mn = fmaxf(m[r], rowmax[r]);
      resc[r] = __expf(m[r] - mn);
      m[r] = mn;
      psum[r] = 0.f;
    }
#pragma unroll
    for (int ks = 0; ks < 4; ++ks) {
      const int j = jb + ks * 16 + fr;
#pragma unroll
      for (int r = 0; r < 4; ++r) {
        float p = __expf(S[ks][r] - m[r]);
        if (masked) {
          const int i = qrow0 + r;
          if (!((j <= i) && (j > i - 256))) p = 0.f;
        }
        S[ks][r] = p;
        psum[r] += p;
      }
    }
#pragma unroll
    for (int off = 1; off <= 8; off <<= 1)
#pragma unroll
      for (int r = 0; r < 4; ++r) psum[r] += __shfl_xor(psum[r], off);
#pragma unroll
    for (int r = 0; r < 4; ++r) l[r] = l[r] * resc[r] + psum[r];
#pragma unroll
    for (int dt = 0; dt < 4; ++dt)
#pragma unroll
      for (int r = 0; r < 4; ++r) acc[dt][r] *= resc[r];

#pragma unroll
    for (int ks = 0; ks < 4; ++ks)
#pragma unroll
      for (int r = 0; r < 4; ++r) {
        const int prow = w * 16 + g * 4 + r;
        const int pcol = ks * 16 + fr;
        Ps[prow * 64 + (pcol ^ ((prow & 7) << 3))] = fbits(S[ks][r]);
      }

#pragma unroll
    for (int kc = 0; kc < 2; ++kc) {
      const int prow = w * 16 + fr;
      const int k0 = kc * 32 + g * 8;
      short8 pf = *reinterpret_cast<const short8*>(&Ps[prow * 64 + (k0 ^ ((prow & 7) << 3))]);
#pragma unroll
      for (int dt = 0; dt < 4; ++dt) {
        const int dr = dt * 16 + fr;
        short8 vf = *reinterpret_cast<const short8*>(&VTs[dr * 64 + (k0 ^ ((dr & 7) << 3))]);
        acc[dt] = __builtin_amdgcn_mfma_f32_16x16x32_bf16(pf, vf, acc[dt], 0, 0, 0);
      }
    }
  }

#pragma unroll
  for (int dt = 0; dt < 4; ++dt)
#pragma unroll
    for (int r = 0; r < 4; ++r) {
      const int i = t0 + w * 16 + g * 4 + r;
      const int d = dt * 16 + fr;
      ybuf[(size_t)i * kC + h * kHS + d] = f2b(acc[dt][r] / l[r]);
    }
}

// ---------------- Compressed attention: MFMA flash + fused gate mix ----------------
// One block per (h, 64-query tile) for batch b. Keys = compressed blocks n
// (127, staged padded to 128; pad rows clamped+masked). allowed = n<127 && n*16 < i.
__global__ __launch_bounds__(256) void comp_attn_mfma(
    const bf16* __restrict__ qkv, const bf16* __restrict__ kcomp,
    const bf16* __restrict__ vcomp, const bf16* __restrict__ gate,
    bf16* __restrict__ ybuf, int b)
{
  __shared__ __align__(16) short Qs[64 * 64];
  __shared__ __align__(16) short Ks[64 * 64];
  __shared__ __align__(16) short VTs[64 * 64];
  __shared__ __align__(16) short Ps[64 * 64];
  const int tid = threadIdx.x;
  const int lane = tid & 63;
  const int w = tid >> 6;
  const int fr = lane & 15;
  const int g  = lane >> 4;
  const int h  = blockIdx.y;
  const int t0 = blockIdx.x * 64;
  const size_t rs = 3 * kC;
  const bf16* qbase = qkv + ((size_t)b * kT) * rs + h * kHS;
  const bf16* kb = kcomp + ((size_t)(b * kNH + h)) * kNB * kHS;
  const bf16* vb = vcomp + ((size_t)(b * kNH + h)) * kNB * kHS;

  for (int c = tid; c < 512; c += 256) {
    const int r = c >> 3, p = c & 7;
    short8 v = *reinterpret_cast<const short8*>(qbase + (size_t)(t0 + r) * rs + p * 8);
    *reinterpret_cast<short8*>(&Qs[r * 64 + ((p ^ (r & 7)) << 3)]) = v;
  }
  __syncthreads();
  short8 qf[2];
  {
    const int r = w * 16 + fr;
#pragma unroll
    for (int dc = 0; dc < 2; ++dc) {
      const int d0 = dc * 32 + g * 8;
      qf[dc] = *reinterpret_cast<const short8*>(&Qs[r * 64 + (d0 ^ ((r & 7) << 3))]);
    }
  }

  f32x4 acc[4];
  float m[4], l[4];
#pragma unroll
  for (int r = 0; r < 4; ++r) { m[r] = -1e30f; l[r] = 0.f; }
#pragma unroll
  for (int dt = 0; dt < 4; ++dt) acc[dt] = (f32x4){0.f, 0.f, 0.f, 0.f};

  // tiles of 64 keys; needed count: nallow_max = ceil((t0+63)/16) -> 2 tiles iff t0>=1024
  const int ntiles = (t0 >= 1024) ? 2 : 1;
  for (int tb = 0; tb < ntiles; ++tb) {
    const int jb = tb * 64;
    // unmasked iff worst element (n=jb+63, i=t0) allowed
    const bool masked = !(((jb + 63) < kNB) && ((jb + 63) * kST < t0));
    __syncthreads();
    for (int c = tid; c < 512; c += 256) {
      const int r = c >> 3, p = c & 7;
      const int rr = (jb + r < kNB) ? (jb + r) : (kNB - 1);   // clamp pad row
      short8 v = *reinterpret_cast<const short8*>(kb + (size_t)rr * kHS + p * 8);
      *reinterpret_cast<short8*>(&Ks[r * 64 + ((p ^ (r & 7)) << 3)]) = v;
    }
    for (int c = tid; c < 512; c += 256) {
      const int r = c >> 3, p = c & 7;
      const int rr = (jb + r < kNB) ? (jb + r) : (kNB - 1);
      short8 v = *reinterpret_cast<const short8*>(vb + (size_t)rr * kHS + p * 8);
#pragma unroll
      for (int e = 0; e < 8; ++e) {
        const int d = p * 8 + e;
        VTs[d * 64 + (r ^ ((d & 7) << 3))] = v[e];
      }
    }
    __syncthreads();

    f32x4 S[4];
#pragma unroll
    for (int ks = 0; ks < 4; ++ks) S[ks] = (f32x4){0.f, 0.f, 0.f, 0.f};
#pragma unroll
    for (int ks = 0; ks < 4; ++ks) {
      const int kr = ks * 16 + fr;
#pragma unroll
      for (int dc = 0; dc < 2; ++dc) {
        const int d0 = dc * 32 + g * 8;
        short8 kf = *reinterpret_cast<const short8*>(&Ks[kr * 64 + (d0 ^ ((kr & 7) << 3))]);
        S[ks] = __builtin_amdgcn_mfma_f32_16x16x32_bf16(qf[dc], kf, S[ks], 0, 0, 0);
      }
    }

    const int qrow0 = t0 + w * 16 + g * 4;
    float rowmax[4];
#pragma unroll
    for (int r = 0; r < 4; ++r) rowmax[r] = -1e30f;
#pragma unroll
    for (int ks = 0; ks < 4; ++ks) {
      const int n = jb + ks * 16 + fr;
#pragma unroll
      for (int r = 0; r < 4; ++r) {
        float s = S[ks][r] * 0.125f;
        if (masked) {
          const int i = qrow0 + r;
          if (!((n < kNB) && (n * kST < i))) s = -1e30f;
        }
        S[ks][r] = s;
        rowmax[r] = fmaxf(rowmax[r], s);
      }
    }
#pragma unroll
    for (int off = 1; off <= 8; off <<= 1)
#pragma unroll
      for (int r = 0; r < 4; ++r)
        rowmax[r] = fmaxf(rowmax[r], __shfl_xor(rowmax[r], off));

    float resc[4], psum[4];
#pragma unroll
    for (int r = 0; r < 4; ++r) {
      const float mn = fmaxf(m[r], rowmax[r]);
      resc[r] = __expf(m[r] - mn);
      m[r] = mn;
      psum[r] = 0.f;
    }
#pragma unroll
    for (int ks = 0; ks < 4; ++ks) {
      const int n = jb + ks * 16 + fr;
#pragma unroll
      for (int r = 0; r < 4; ++r) {
        float p = __expf(S[ks][r] - m[r]);
        if (masked) {
          const int i = qrow0 + r;
          if (!((n < kNB) && (n * kST < i))) p = 0.f;
        }
        S[ks][r] = p;
        psum[r] += p;
      }
    }
#pragma unroll
    for (int off = 1; off <= 8; off <<= 1)
#pragma unroll
      for (int r = 0; r < 4; ++r) psum[r] += __shfl_xor(psum[r], off);
#pragma unroll
    for (int r = 0; r < 4; ++r) l[r] = l[r] * resc[r] + psum[r];
#pragma unroll
    for (int dt = 0; dt < 4; ++dt)
#pragma unroll
      for (int r = 0; r < 4; ++r) acc[dt][r] *= resc[r];

#pragma unroll
    for (int ks = 0; ks < 4; ++ks)
#pragma unroll
      for (int r = 0; r < 4; ++r) {
        const int prow = w * 16 + g * 4 + r;
        const int pcol = ks * 16 + fr;
        Ps[prow * 64 + (pcol ^ ((prow & 7) << 3))] = fbits(S[ks][r]);
      }

#pragma unroll
    for (int kc = 0; kc < 2; ++kc) {
      const int prow = w * 16 + fr;
      const int k0 = kc * 32 + g * 8;
      short8 pf = *reinterpret_cast<const short8*>(&Ps[prow * 64 + (k0 ^ ((prow & 7) << 3))]);
#pragma unroll
      for (int dt = 0; dt < 4; ++dt) {
        const int dr = dt * 16 + fr;
        short8 vf = *reinterpret_cast<const short8*>(&VTs[dr * 64 + (k0 ^ ((dr & 7) << 3))]);
        acc[dt] = __builtin_amdgcn_mfma_f32_16x16x32_bf16(pf, vf, acc[dt], 0, 0, 0);
      }
    }
  }

  // epilogue: yc = acc/l (0 if no allowed keys), then gate mix in-place into ybuf
#pragma unroll
  for (int r = 0; r < 4; ++r) {
    const int i = t0 + w * 16 + g * 4 + r;
    const float inv = (l[r] > 0.f) ? (1.f / l[r]) : 0.f;
#pragma unroll
    for (int dt = 0; dt < 4; ++dt) {
      const int d = dt * 16 + fr;
      const size_t idx = (size_t)i * kC + h * kHS + d;
      const float yc = acc[dt][r] * inv;
      const float gg = b2f(gate[((size_t)(b * kT + i)) * kC + h * kHS + d]);
      const float yl = b2f(ybuf[idx]);
      ybuf[idx] = f2b(gg * yl + (1.f - gg) * yc);
    }
  }
}

extern "C" void kernel_launch(void* const* d_in, const int* in_sizes, int n_in,
                              void* d_out, int out_size, void* d_ws, size_t ws_size,
                              hipStream_t stream)
{
  (void)in_sizes; (void)n_in; (void)out_size; (void)ws_size; (void)kM; (void)kWIN;
  const float* x      = (const float*)d_in[0];
  const float* Wqkv   = (const float*)d_in[1];
  const float* bqkv   = (const float*)d_in[2];
  const float* Wcomp  = (const float*)d_in[3];
  const float* bcomp  = (const float*)d_in[4];
  const float* Wproj  = (const float*)d_in[5];
  const float* bproj  = (const float*)d_in[6];
  const float* k_fc1W = (const float*)d_in[7];
  const float* k_fc1b = (const float*)d_in[8];
  const float* k_fc2W = (const float*)d_in[9];
  const float* k_fc2b = (const float*)d_in[10];
  const float* k_rpW  = (const float*)d_in[11];
  const float* k_rpb  = (const float*)d_in[12];
  const float* k_wpe  = (const float*)d_in[13];
  const float* v_fc1W = (const float*)d_in[14];
  const float* v_fc1b = (const float*)d_in[15];
  const float* v_fc2W = (const float*)d_in[16];
  const float* v_fc2b = (const float*)d_in[17];
  const float* v_rpW  = (const float*)d_in[18];
  const float* v_rpb  = (const float*)d_in[19];
  const float* v_wpe  = (const float*)d_in[20];
  const float* Wg1    = (const float*)d_in[21];
  const float* bg1    = (const float*)d_in[22];
  const float* Wg2    = (const float*)d_in[23];
  const float* bg2    = (const float*)d_in[24];

  // ---- Workspace (peak 51,372,032 B, identical to proven footprint) ----
  char* wsb = (char*)d_ws;
  bf16* xbf   = (bf16*)(wsb + 0);
  bf16* wscr  = (bf16*)(wsb + 8388608);
  bf16* big   = (bf16*)(wsb + 16777216);
  bf16* ybuf  = (bf16*)(wsb + 41943040);
  bf16* kcomp = (bf16*)(wsb + 50331648);
  bf16* vcomp = (bf16*)(wsb + 50851840);
  bf16* gate  = (bf16*)((char*)d_out + 8388608);
  float* out  = (float*)d_out;

  const int cg = 2048;
  f32_to_bf16<<<cg, 256, 0, stream>>>(x, xbf, 1048576);
  f32_to_bf16<<<cg, 256, 0, stream>>>(Wg1, wscr, 1048576);
  gemm_bf16<1, bf16><<<1024, 256, 0, stream>>>(xbf, wscr, bg1, big, 4096, 4096, 1024, 32);
  f32_to_bf16<<<cg, 256, 0, stream>>>(Wg2, wscr, 1048576);
  gemm_bf16<3, bf16><<<256, 256, 0, stream>>>(big, wscr, bg2, gate, 4096, 1024, 4096, 8);
  f32_to_bf16<<<cg, 256, 0, stream>>>(Wcomp, wscr, 524288);
  gemm_bf16<0, bf16><<<512, 256, 0, stream>>>(xbf, wscr, bcomp, big, 4096, 2048, 1024, 16);
  comp_mlp<<<kB * kNH * kNB, 64, 0, stream>>>(big, 0, k_fc1W, k_fc1b, k_fc2W, k_fc2b, k_rpW, k_rpb, k_wpe, kcomp);
  comp_mlp<<<kB * kNH * kNB, 64, 0, stream>>>(big, 1, v_fc1W, v_fc1b, v_fc2W, v_fc2b, v_rpW, v_rpb, v_wpe, vcomp);
  f32_to_bf16<<<cg, 256, 0, stream>>>(Wqkv, wscr, 786432);
  gemm_bf16<0, bf16><<<768, 256, 0, stream>>>(xbf, wscr, bqkv, big, 4096, 3072, 1024, 24);
  f32_to_bf16<<<cg, 256, 0, stream>>>(Wproj, wscr, 262144);
  for (int b = 0; b < kB; ++b) {
    local_attn_mfma<<<dim3(kT / 64, kNH), 256, 0, stream>>>(big, ybuf, b);
    comp_attn_mfma<<<dim3(kT / 64, kNH), 256, 0, stream>>>(big, kcomp, vcomp, gate, ybuf, b);
    gemm_bf16<0, float><<<128, 256, 0, stream>>>(ybuf, wscr, bproj, out + (size_t)b * 2048 * kC, 2048, 1024, 1024, 8);
  }
}

// Round 11
// 488.379 us; speedup vs baseline: 7.5046x; 1.0712x over previous
//
#include <hip/hip_runtime.h>
#include <hip/hip_bf16.h>

typedef __hip_bfloat16 bf16;

constexpr int kB = 2, kT = 2048, kC = 1024, kNH = 16, kHS = 64;
constexpr int kL = 32, kST = 16, kWIN = 256;
constexpr int kNB = (kT - kL) / kST + 1;   // 127
constexpr int kM = kB * kT;                // 4096

typedef __attribute__((ext_vector_type(8))) short short8;   // bf16 MFMA A/B frag (4 VGPRs)
typedef __attribute__((ext_vector_type(4))) short short4v;
typedef __attribute__((ext_vector_type(4))) float f32x4;

__device__ __forceinline__ float b2f(bf16 v) { return __bfloat162float(v); }
__device__ __forceinline__ bf16  f2b(float v) { return __float2bfloat16(v); }
__device__ __forceinline__ float gelu_f(float v) { return 0.5f * v * (1.0f + erff(v * 0.70710678118654752f)); }
__device__ __forceinline__ short fbits(float v) {
  return (short)__builtin_bit_cast(unsigned short, f2b(v));
}
// async global->LDS, 16 bytes per lane (dest = wave-uniform base + lane*16)
__device__ __forceinline__ void gl16(const bf16* g, bf16* l) {
  __builtin_amdgcn_global_load_lds(
      (const __attribute__((address_space(1))) void*)g,
      (__attribute__((address_space(3))) void*)l, 16, 0, 0);
}

// ---------------- fp32 -> bf16 conversion (vectorized, grid-stride) ----------------
__global__ __launch_bounds__(256) void f32_to_bf16(const float* __restrict__ src,
                                                   bf16* __restrict__ dst, int n4) {
  int i = blockIdx.x * 256 + threadIdx.x;
  const int stride = gridDim.x * 256;
  for (; i < n4; i += stride) {
    float4 v = ((const float4*)src)[i];
    short4v w; w.x = fbits(v.x); w.y = fbits(v.y); w.z = fbits(v.z); w.w = fbits(v.w);
    ((short4v*)dst)[i] = w;
  }
}

// ---------------- all-bf16 MFMA GEMM: 128x128 tile, BK=64, 8 waves (2x4) ----------------
// Wave tile 64x32 (acc[4][2]); global_load_lds width-16 staging; XCD-swizzled blocks.
template<int EPI, typename TY>
__global__ __launch_bounds__(512) void gemm_bf16(
    const bf16* __restrict__ X, const bf16* __restrict__ W,
    const float* __restrict__ bias, TY* __restrict__ Y,
    int M, int N, int K, int nbx)
{
  __shared__ __align__(16) bf16 As[128 * 64];
  __shared__ __align__(16) bf16 Bs[128 * 64];
  const int nwg = gridDim.x;
  const int bid = blockIdx.x;
  const int swz = (bid & 7) * (nwg >> 3) + (bid >> 3);
  const int bm = (swz / nbx) * 128;
  const int bn = (swz % nbx) * 128;
  const int tid = threadIdx.x;
  const int lane = tid & 63;
  const int w = tid >> 6;                 // 0..7
  const int wr = w >> 2, wc = w & 3;      // 2x4 wave grid; wave tile 64 x 32
  const int fr = lane & 15, q = lane >> 4;
  const int srow = lane >> 3;
  const int scol = (lane & 7) * 8;

  f32x4 acc[4][2];
#pragma unroll
  for (int i = 0; i < 4; ++i)
#pragma unroll
    for (int j = 0; j < 2; ++j) acc[i][j] = (f32x4){0.f, 0.f, 0.f, 0.f};

  const bf16* Xb = X + (size_t)bm * K;
  const bf16* Wb = W + (size_t)bn * K;

  for (int k0 = 0; k0 < K; k0 += 64) {
    __syncthreads();
#pragma unroll
    for (int i = 0; i < 2; ++i) {
      const int r = w * 16 + i * 8 + srow;   // wave w stages rows [w*16, w*16+16)
      gl16(Xb + (size_t)r * K + k0 + scol, &As[r * 64 + scol]);
      gl16(Wb + (size_t)r * K + k0 + scol, &Bs[r * 64 + scol]);
    }
    __syncthreads();
#pragma unroll
    for (int kk = 0; kk < 2; ++kk) {
      short8 af[4], bfr[2];
#pragma unroll
      for (int i = 0; i < 4; ++i)
        af[i] = *reinterpret_cast<const short8*>(&As[(wr * 64 + i * 16 + fr) * 64 + kk * 32 + q * 8]);
#pragma unroll
      for (int j = 0; j < 2; ++j)
        bfr[j] = *reinterpret_cast<const short8*>(&Bs[(wc * 32 + j * 16 + fr) * 64 + kk * 32 + q * 8]);
#pragma unroll
      for (int i = 0; i < 4; ++i)
#pragma unroll
        for (int j = 0; j < 2; ++j)
          acc[i][j] = __builtin_amdgcn_mfma_f32_16x16x32_bf16(af[i], bfr[j], acc[i][j], 0, 0, 0);
    }
  }

#pragma unroll
  for (int j = 0; j < 2; ++j) {
    const int gcol = bn + wc * 32 + j * 16 + fr;
    const float bv = bias[gcol];
#pragma unroll
    for (int i = 0; i < 4; ++i) {
      const int grow0 = bm + wr * 64 + i * 16 + q * 4;
#pragma unroll
      for (int r = 0; r < 4; ++r) {
        float v = acc[i][j][r] + bv;
        if (EPI == 1) v = gelu_f(v);
        if (EPI == 3) v = 1.f / (1.f + expf(-v));
        if constexpr (sizeof(TY) == 2) Y[(size_t)(grow0 + r) * N + gcol] = f2b(v);
        else                           ((float*)Y)[(size_t)(grow0 + r) * N + gcol] = v;
      }
    }
  }
}

// ---------------- Compression MLP (unchanged) ----------------
__global__ __launch_bounds__(64) void comp_mlp(
    const bf16* __restrict__ kvbuf, int s,
    const float* __restrict__ fc1W, const float* __restrict__ fc1b,
    const float* __restrict__ fc2W, const float* __restrict__ fc2b,
    const float* __restrict__ rpW,  const float* __restrict__ rpb,
    const float* __restrict__ wpe,  bf16* __restrict__ outp)
{
  __shared__ float s_fc1W[128 * 32];
  __shared__ float s_fc1b[128];
  __shared__ float s_fc2W[128];
  const int id = blockIdx.x;
  const int blk = id % kNB;
  const int h = (id / kNB) % kNH;
  const int b = id / (kNB * kNH);
  const int d = threadIdx.x;
  for (int i = d; i < 128 * 32; i += 64) s_fc1W[i] = fc1W[i];
  for (int i = d; i < 128; i += 64) { s_fc1b[i] = fc1b[i]; s_fc2W[i] = fc2W[i]; }
  __syncthreads();

  float xu[kL], xpe[kL];
  const int t0 = blk * kST;
  const bf16* base = kvbuf + ((size_t)(b * kT + t0) * (2 * kC)) + (size_t)s * kC + h * kHS + d;
#pragma unroll
  for (int l = 0; l < kL; ++l) {
    float u = b2f(base[(size_t)l * (2 * kC)]);
    xu[l] = u;
    xpe[l] = u + wpe[l * kHS + d];
  }
  float out = fc2b[0];
  for (int j = 0; j < 128; ++j) {
    float a = s_fc1b[j];
#pragma unroll
    for (int l = 0; l < kL; ++l) a = fmaf(xpe[l], s_fc1W[j * kL + l], a);
    out = fmaf(gelu_f(a), s_fc2W[j], out);
  }
  float res = rpb[0];
#pragma unroll
  for (int l = 0; l < kL; ++l) res = fmaf(xu[l], rpW[l], res);
  float r = out + res;
  r = fminf(3.0f, fmaxf(-3.0f, r));
  outp[((size_t)(b * kNH + h) * kNB + blk) * kHS + d] = f2b(r);
}

// ---------------- Local sliding-window attention: MFMA flash (unchanged) ----------------
__global__ __launch_bounds__(256) void local_attn_mfma(
    const bf16* __restrict__ qkv, bf16* __restrict__ ybuf, int b)
{
  __shared__ __align__(16) short Qs[64 * 64];
  __shared__ __align__(16) short Ks[64 * 64];
  __shared__ __align__(16) short VTs[64 * 64];
  __shared__ __align__(16) short Ps[64 * 64];
  const int tid = threadIdx.x;
  const int lane = tid & 63;
  const int w = tid >> 6;
  const int fr = lane & 15;
  const int g  = lane >> 4;
  const int h  = blockIdx.y;
  const int t0 = blockIdx.x * 64;
  const size_t rs = 3 * kC;
  const bf16* qbase = qkv + ((size_t)b * kT) * rs + h * kHS;
  const bf16* kbase = qbase + kC;
  const bf16* vbase = qbase + 2 * kC;

  for (int c = tid; c < 512; c += 256) {
    const int r = c >> 3, p = c & 7;
    short8 v = *reinterpret_cast<const short8*>(qbase + (size_t)(t0 + r) * rs + p * 8);
    *reinterpret_cast<short8*>(&Qs[r * 64 + ((p ^ (r & 7)) << 3)]) = v;
  }
  __syncthreads();
  short8 qf[2];
  {
    const int r = w * 16 + fr;
#pragma unroll
    for (int dc = 0; dc < 2; ++dc) {
      const int d0 = dc * 32 + g * 8;
      qf[dc] = *reinterpret_cast<const short8*>(&Qs[r * 64 + (d0 ^ ((r & 7) << 3))]);
    }
  }

  f32x4 acc[4];
  float m[4], l[4];
#pragma unroll
  for (int r = 0; r < 4; ++r) { m[r] = -1e30f; l[r] = 0.f; }
#pragma unroll
  for (int dt = 0; dt < 4; ++dt) acc[dt] = (f32x4){0.f, 0.f, 0.f, 0.f};

  const int jb0 = (t0 >= 256) ? (t0 - 256) : 0;
  for (int jb = jb0; jb <= t0; jb += 64) {
    const bool masked = (jb == t0 - 256) || (jb == t0);
    __syncthreads();
    for (int c = tid; c < 512; c += 256) {
      const int r = c >> 3, p = c & 7;
      short8 v = *reinterpret_cast<const short8*>(kbase + (size_t)(jb + r) * rs + p * 8);
      *reinterpret_cast<short8*>(&Ks[r * 64 + ((p ^ (r & 7)) << 3)]) = v;
    }
    for (int c = tid; c < 512; c += 256) {
      const int r = c >> 3, p = c & 7;
      short8 v = *reinterpret_cast<const short8*>(vbase + (size_t)(jb + r) * rs + p * 8);
#pragma unroll
      for (int e = 0; e < 8; ++e) {
        const int d = p * 8 + e;
        VTs[d * 64 + (r ^ ((d & 7) << 3))] = v[e];
      }
    }
    __syncthreads();

    f32x4 S[4];
#pragma unroll
    for (int ks = 0; ks < 4; ++ks) S[ks] = (f32x4){0.f, 0.f, 0.f, 0.f};
#pragma unroll
    for (int ks = 0; ks < 4; ++ks) {
      const int kr = ks * 16 + fr;
#pragma unroll
      for (int dc = 0; dc < 2; ++dc) {
        const int d0 = dc * 32 + g * 8;
        short8 kf = *reinterpret_cast<const short8*>(&Ks[kr * 64 + (d0 ^ ((kr & 7) << 3))]);
        S[ks] = __builtin_amdgcn_mfma_f32_16x16x32_bf16(qf[dc], kf, S[ks], 0, 0, 0);
      }
    }

    const int qrow0 = t0 + w * 16 + g * 4;
    float rowmax[4];
#pragma unroll
    for (int r = 0; r < 4; ++r) rowmax[r] = -1e30f;
#pragma unroll
    for (int ks = 0; ks < 4; ++ks) {
      const int j = jb + ks * 16 + fr;
#pragma unroll
      for (int r = 0; r < 4; ++r) {
        float s = S[ks][r] * 0.125f;
        if (masked) {
          const int i = qrow0 + r;
          if (!((j <= i) && (j > i - 256))) s = -1e30f;
        }
        S[ks][r] = s;
        rowmax[r] = fmaxf(rowmax[r], s);
      }
    }
#pragma unroll
    for (int off = 1; off <= 8; off <<= 1)
#pragma unroll
      for (int r = 0; r < 4; ++r)
        rowmax[r] = fmaxf(rowmax[r], __shfl_xor(rowmax[r], off));

    float resc[4], psum[4];
#pragma unroll
    for (int r = 0; r < 4; ++r) {
      const float mn = fmaxf(m[r], rowmax[r]);
      resc[r] = __expf(m[r] - mn);
      m[r] = mn;
      psum[r] = 0.f;
    }
#pragma unroll
    for (int ks = 0; ks < 4; ++ks) {
      const int j = jb + ks * 16 + fr;
#pragma unroll
      for (int r = 0; r < 4; ++r) {
        float p = __expf(S[ks][r] - m[r]);
        if (masked) {
          const int i = qrow0 + r;
          if (!((j <= i) && (j > i - 256))) p = 0.f;
        }
        S[ks][r] = p;
        psum[r] += p;
      }
    }
#pragma unroll
    for (int off = 1; off <= 8; off <<= 1)
#pragma unroll
      for (int r = 0; r < 4; ++r) psum[r] += __shfl_xor(psum[r], off);
#pragma unroll
    for (int r = 0; r < 4; ++r) l[r] = l[r] * resc[r] + psum[r];
#pragma unroll
    for (int dt = 0; dt < 4; ++dt)
#pragma unroll
      for (int r = 0; r < 4; ++r) acc[dt][r] *= resc[r];

#pragma unroll
    for (int ks = 0; ks < 4; ++ks)
#pragma unroll
      for (int r = 0; r < 4; ++r) {
        const int prow = w * 16 + g * 4 + r;
        const int pcol = ks * 16 + fr;
        Ps[prow * 64 + (pcol ^ ((prow & 7) << 3))] = fbits(S[ks][r]);
      }

#pragma unroll
    for (int kc = 0; kc < 2; ++kc) {
      const int prow = w * 16 + fr;
      const int k0 = kc * 32 + g * 8;
      short8 pf = *reinterpret_cast<const short8*>(&Ps[prow * 64 + (k0 ^ ((prow & 7) << 3))]);
#pragma unroll
      for (int dt = 0; dt < 4; ++dt) {
        const int dr = dt * 16 + fr;
        short8 vf = *reinterpret_cast<const short8*>(&VTs[dr * 64 + (k0 ^ ((dr & 7) << 3))]);
        acc[dt] = __builtin_amdgcn_mfma_f32_16x16x32_bf16(pf, vf, acc[dt], 0, 0, 0);
      }
    }
  }

#pragma unroll
  for (int dt = 0; dt < 4; ++dt)
#pragma unroll
    for (int r = 0; r < 4; ++r) {
      const int i = t0 + w * 16 + g * 4 + r;
      const int d = dt * 16 + fr;
      ybuf[(size_t)i * kC + h * kHS + d] = f2b(acc[dt][r] / l[r]);
    }
}

// ---------------- Compressed attention: MFMA flash + fused gate mix (unchanged) ----------------
__global__ __launch_bounds__(256) void comp_attn_mfma(
    const bf16* __restrict__ qkv, const bf16* __restrict__ kcomp,
    const bf16* __restrict__ vcomp, const bf16* __restrict__ gate,
    bf16* __restrict__ ybuf, int b)
{
  __shared__ __align__(16) short Qs[64 * 64];
  __shared__ __align__(16) short Ks[64 * 64];
  __shared__ __align__(16) short VTs[64 * 64];
  __shared__ __align__(16) short Ps[64 * 64];
  const int tid = threadIdx.x;
  const int lane = tid & 63;
  const int w = tid >> 6;
  const int fr = lane & 15;
  const int g  = lane >> 4;
  const int h  = blockIdx.y;
  const int t0 = blockIdx.x * 64;
  const size_t rs = 3 * kC;
  const bf16* qbase = qkv + ((size_t)b * kT) * rs + h * kHS;
  const bf16* kb = kcomp + ((size_t)(b * kNH + h)) * kNB * kHS;
  const bf16* vb = vcomp + ((size_t)(b * kNH + h)) * kNB * kHS;

  for (int c = tid; c < 512; c += 256) {
    const int r = c >> 3, p = c & 7;
    short8 v = *reinterpret_cast<const short8*>(qbase + (size_t)(t0 + r) * rs + p * 8);
    *reinterpret_cast<short8*>(&Qs[r * 64 + ((p ^ (r & 7)) << 3)]) = v;
  }
  __syncthreads();
  short8 qf[2];
  {
    const int r = w * 16 + fr;
#pragma unroll
    for (int dc = 0; dc < 2; ++dc) {
      const int d0 = dc * 32 + g * 8;
      qf[dc] = *reinterpret_cast<const short8*>(&Qs[r * 64 + (d0 ^ ((r & 7) << 3))]);
    }
  }

  f32x4 acc[4];
  float m[4], l[4];
#pragma unroll
  for (int r = 0; r < 4; ++r) { m[r] = -1e30f; l[r] = 0.f; }
#pragma unroll
  for (int dt = 0; dt < 4; ++dt) acc[dt] = (f32x4){0.f, 0.f, 0.f, 0.f};

  const int ntiles = (t0 >= 1024) ? 2 : 1;
  for (int tb = 0; tb < ntiles; ++tb) {
    const int jb = tb * 64;
    const bool masked = !(((jb + 63) < kNB) && ((jb + 63) * kST < t0));
    __syncthreads();
    for (int c = tid; c < 512; c += 256) {
      const int r = c >> 3, p = c & 7;
      const int rr = (jb + r < kNB) ? (jb + r) : (kNB - 1);
      short8 v = *reinterpret_cast<const short8*>(kb + (size_t)rr * kHS + p * 8);
      *reinterpret_cast<short8*>(&Ks[r * 64 + ((p ^ (r & 7)) << 3)]) = v;
    }
    for (int c = tid; c < 512; c += 256) {
      const int r = c >> 3, p = c & 7;
      const int rr = (jb + r < kNB) ? (jb + r) : (kNB - 1);
      short8 v = *reinterpret_cast<const short8*>(vb + (size_t)rr * kHS + p * 8);
#pragma unroll
      for (int e = 0; e < 8; ++e) {
        const int d = p * 8 + e;
        VTs[d * 64 + (r ^ ((d & 7) << 3))] = v[e];
      }
    }
    __syncthreads();

    f32x4 S[4];
#pragma unroll
    for (int ks = 0; ks < 4; ++ks) S[ks] = (f32x4){0.f, 0.f, 0.f, 0.f};
#pragma unroll
    for (int ks = 0; ks < 4; ++ks) {
      const int kr = ks * 16 + fr;
#pragma unroll
      for (int dc = 0; dc < 2; ++dc) {
        const int d0 = dc * 32 + g * 8;
        short8 kf = *reinterpret_cast<const short8*>(&Ks[kr * 64 + (d0 ^ ((kr & 7) << 3))]);
        S[ks] = __builtin_amdgcn_mfma_f32_16x16x32_bf16(qf[dc], kf, S[ks], 0, 0, 0);
      }
    }

    const int qrow0 = t0 + w * 16 + g * 4;
    float rowmax[4];
#pragma unroll
    for (int r = 0; r < 4; ++r) rowmax[r] = -1e30f;
#pragma unroll
    for (int ks = 0; ks < 4; ++ks) {
      const int n = jb + ks * 16 + fr;
#pragma unroll
      for (int r = 0; r < 4; ++r) {
        float s = S[ks][r] * 0.125f;
        if (masked) {
          const int i = qrow0 + r;
          if (!((n < kNB) && (n * kST < i))) s = -1e30f;
        }
        S[ks][r] = s;
        rowmax[r] = fmaxf(rowmax[r], s);
      }
    }
#pragma unroll
    for (int off = 1; off <= 8; off <<= 1)
#pragma unroll
      for (int r = 0; r < 4; ++r)
        rowmax[r] = fmaxf(rowmax[r], __shfl_xor(rowmax[r], off));

    float resc[4], psum[4];
#pragma unroll
    for (int r = 0; r < 4; ++r) {
      const float mn = fmaxf(m[r], rowmax[r]);
      resc[r] = __expf(m[r] - mn);
      m[r] = mn;
      psum[r] = 0.f;
    }
#pragma unroll
    for (int ks = 0; ks < 4; ++ks) {
      const int n = jb + ks * 16 + fr;
#pragma unroll
      for (int r = 0; r < 4; ++r) {
        float p = __expf(S[ks][r] - m[r]);
        if (masked) {
          const int i = qrow0 + r;
          if (!((n < kNB) && (n * kST < i))) p = 0.f;
        }
        S[ks][r] = p;
        psum[r] += p;
      }
    }
#pragma unroll
    for (int off = 1; off <= 8; off <<= 1)
#pragma unroll
      for (int r = 0; r < 4; ++r) psum[r] += __shfl_xor(psum[r], off);
#pragma unroll
    for (int r = 0; r < 4; ++r) l[r] = l[r] * resc[r] + psum[r];
#pragma unroll
    for (int dt = 0; dt < 4; ++dt)
#pragma unroll
      for (int r = 0; r < 4; ++r) acc[dt][r] *= resc[r];

#pragma unroll
    for (int ks = 0; ks < 4; ++ks)
#pragma unroll
      for (int r = 0; r < 4; ++r) {
        const int prow = w * 16 + g * 4 + r;
        const int pcol = ks * 16 + fr;
        Ps[prow * 64 + (pcol ^ ((prow & 7) << 3))] = fbits(S[ks][r]);
      }

#pragma unroll
    for (int kc = 0; kc < 2; ++kc) {
      const int prow = w * 16 + fr;
      const int k0 = kc * 32 + g * 8;
      short8 pf = *reinterpret_cast<const short8*>(&Ps[prow * 64 + (k0 ^ ((prow & 7) << 3))]);
#pragma unroll
      for (int dt = 0; dt < 4; ++dt) {
        const int dr = dt * 16 + fr;
        short8 vf = *reinterpret_cast<const short8*>(&VTs[dr * 64 + (k0 ^ ((dr & 7) << 3))]);
        acc[dt] = __builtin_amdgcn_mfma_f32_16x16x32_bf16(pf, vf, acc[dt], 0, 0, 0);
      }
    }
  }

#pragma unroll
  for (int r = 0; r < 4; ++r) {
    const int i = t0 + w * 16 + g * 4 + r;
    const float inv = (l[r] > 0.f) ? (1.f / l[r]) : 0.f;
#pragma unroll
    for (int dt = 0; dt < 4; ++dt) {
      const int d = dt * 16 + fr;
      const size_t idx = (size_t)i * kC + h * kHS + d;
      const float yc = acc[dt][r] * inv;
      const float gg = b2f(gate[((size_t)(b * kT + i)) * kC + h * kHS + d]);
      const float yl = b2f(ybuf[idx]);
      ybuf[idx] = f2b(gg * yl + (1.f - gg) * yc);
    }
  }
}

extern "C" void kernel_launch(void* const* d_in, const int* in_sizes, int n_in,
                              void* d_out, int out_size, void* d_ws, size_t ws_size,
                              hipStream_t stream)
{
  (void)in_sizes; (void)n_in; (void)out_size; (void)ws_size; (void)kM; (void)kWIN;
  const float* x      = (const float*)d_in[0];
  const float* Wqkv   = (const float*)d_in[1];
  const float* bqkv   = (const float*)d_in[2];
  const float* Wcomp  = (const float*)d_in[3];
  const float* bcomp  = (const float*)d_in[4];
  const float* Wproj  = (const float*)d_in[5];
  const float* bproj  = (const float*)d_in[6];
  const float* k_fc1W = (const float*)d_in[7];
  const float* k_fc1b = (const float*)d_in[8];
  const float* k_fc2W = (const float*)d_in[9];
  const float* k_fc2b = (const float*)d_in[10];
  const float* k_rpW  = (const float*)d_in[11];
  const float* k_rpb  = (const float*)d_in[12];
  const float* k_wpe  = (const float*)d_in[13];
  const float* v_fc1W = (const float*)d_in[14];
  const float* v_fc1b = (const float*)d_in[15];
  const float* v_fc2W = (const float*)d_in[16];
  const float* v_fc2b = (const float*)d_in[17];
  const float* v_rpW  = (const float*)d_in[18];
  const float* v_rpb  = (const float*)d_in[19];
  const float* v_wpe  = (const float*)d_in[20];
  const float* Wg1    = (const float*)d_in[21];
  const float* bg1    = (const float*)d_in[22];
  const float* Wg2    = (const float*)d_in[23];
  const float* bg2    = (const float*)d_in[24];

  // ---- Workspace (peak 51,372,032 B, identical to proven footprint) ----
  // xbf   [0, 8388608)           bf16 x
  // wscr  [8388608, 16777216)    bf16 current weight
  // big   [16777216, 50331648)   bf16 g1(33.5M) -> kv(16.8M) -> qkv(25.2M), time-disjoint
  //   ybuf [41943040, 50331648)  bf16 (B,T,C), lives in big tail during attn phase
  // kcomp [50331648, 50851840)
  // vcomp [50851840, 51372032)
  // gate lives in d_out bytes [8388608, 16777216); consumed by both comp_attn before proj.
  char* wsb = (char*)d_ws;
  bf16* xbf   = (bf16*)(wsb + 0);
  bf16* wscr  = (bf16*)(wsb + 8388608);
  bf16* big   = (bf16*)(wsb + 16777216);
  bf16* ybuf  = (bf16*)(wsb + 41943040);
  bf16* kcomp = (bf16*)(wsb + 50331648);
  bf16* vcomp = (bf16*)(wsb + 50851840);
  bf16* gate  = (bf16*)((char*)d_out + 8388608);
  float* out  = (float*)d_out;

  const int cg = 2048;
  f32_to_bf16<<<cg, 256, 0, stream>>>(x, xbf, 1048576);
  f32_to_bf16<<<cg, 256, 0, stream>>>(Wg1, wscr, 1048576);
  gemm_bf16<1, bf16><<<1024, 512, 0, stream>>>(xbf, wscr, bg1, big, 4096, 4096, 1024, 32);
  f32_to_bf16<<<cg, 256, 0, stream>>>(Wg2, wscr, 1048576);
  gemm_bf16<3, bf16><<<256, 512, 0, stream>>>(big, wscr, bg2, gate, 4096, 1024, 4096, 8);
  f32_to_bf16<<<cg, 256, 0, stream>>>(Wcomp, wscr, 524288);
  gemm_bf16<0, bf16><<<512, 512, 0, stream>>>(xbf, wscr, bcomp, big, 4096, 2048, 1024, 16);
  comp_mlp<<<kB * kNH * kNB, 64, 0, stream>>>(big, 0, k_fc1W, k_fc1b, k_fc2W, k_fc2b, k_rpW, k_rpb, k_wpe, kcomp);
  comp_mlp<<<kB * kNH * kNB, 64, 0, stream>>>(big, 1, v_fc1W, v_fc1b, v_fc2W, v_fc2b, v_rpW, v_rpb, v_wpe, vcomp);
  f32_to_bf16<<<cg, 256, 0, stream>>>(Wqkv, wscr, 786432);
  gemm_bf16<0, bf16><<<768, 512, 0, stream>>>(xbf, wscr, bqkv, big, 4096, 3072, 1024, 24);
  f32_to_bf16<<<cg, 256, 0, stream>>>(Wproj, wscr, 262144);
  // attention for both batches into (B,T,C) ybuf; gate consumed here
  for (int b = 0; b < kB; ++b) {
    bf16* yb = ybuf + (size_t)b * kT * kC;
    local_attn_mfma<<<dim3(kT / 64, kNH), 256, 0, stream>>>(big, yb, b);
    comp_attn_mfma<<<dim3(kT / 64, kNH), 256, 0, stream>>>(big, kcomp, vcomp, gate, yb, b);
  }
  // single merged projection over both batches (overwrites gate region after use)
  gemm_bf16<0, float><<<256, 512, 0, stream>>>(ybuf, wscr, bproj, out, 4096, 1024, 1024, 8);
}

// Round 12
// 461.786 us; speedup vs baseline: 7.9367x; 1.0576x over previous
//
#include <hip/hip_runtime.h>
#include <hip/hip_bf16.h>

typedef __hip_bfloat16 bf16;

constexpr int kB = 2, kT = 2048, kC = 1024, kNH = 16, kHS = 64;
constexpr int kL = 32, kST = 16, kWIN = 256;
constexpr int kNB = (kT - kL) / kST + 1;   // 127
constexpr int kM = kB * kT;                // 4096

typedef __attribute__((ext_vector_type(8))) short short8;   // bf16 MFMA A/B frag (4 VGPRs)
typedef __attribute__((ext_vector_type(4))) short short4v;
typedef __attribute__((ext_vector_type(4))) float f32x4;

__device__ __forceinline__ float b2f(bf16 v) { return __bfloat162float(v); }
__device__ __forceinline__ bf16  f2b(float v) { return __float2bfloat16(v); }
__device__ __forceinline__ float gelu_f(float v) { return 0.5f * v * (1.0f + erff(v * 0.70710678118654752f)); }
__device__ __forceinline__ short fbits(float v) {
  return (short)__builtin_bit_cast(unsigned short, f2b(v));
}
// async global->LDS, 16 bytes per lane (dest = wave-uniform base + lane*16)
__device__ __forceinline__ void gl16(const bf16* g, bf16* l) {
  __builtin_amdgcn_global_load_lds(
      (const __attribute__((address_space(1))) void*)g,
      (__attribute__((address_space(3))) void*)l, 16, 0, 0);
}

// ---------------- fp32 -> bf16 conversion (vectorized, grid-stride) ----------------
__global__ __launch_bounds__(256) void f32_to_bf16(const float* __restrict__ src,
                                                   bf16* __restrict__ dst, int n4) {
  int i = blockIdx.x * 256 + threadIdx.x;
  const int stride = gridDim.x * 256;
  for (; i < n4; i += stride) {
    float4 v = ((const float4*)src)[i];
    short4v w; w.x = fbits(v.x); w.y = fbits(v.y); w.z = fbits(v.z); w.w = fbits(v.w);
    ((short4v*)dst)[i] = w;
  }
}

// ---------------- all-bf16 MFMA GEMM: 128x128 tile, BK=64, 8 waves (2x4) ----------------
template<int EPI, typename TY>
__global__ __launch_bounds__(512) void gemm_bf16(
    const bf16* __restrict__ X, const bf16* __restrict__ W,
    const float* __restrict__ bias, TY* __restrict__ Y,
    int M, int N, int K, int nbx)
{
  __shared__ __align__(16) bf16 As[128 * 64];
  __shared__ __align__(16) bf16 Bs[128 * 64];
  const int nwg = gridDim.x;
  const int bid = blockIdx.x;
  const int swz = (bid & 7) * (nwg >> 3) + (bid >> 3);
  const int bm = (swz / nbx) * 128;
  const int bn = (swz % nbx) * 128;
  const int tid = threadIdx.x;
  const int lane = tid & 63;
  const int w = tid >> 6;
  const int wr = w >> 2, wc = w & 3;      // 2x4 wave grid; wave tile 64 x 32
  const int fr = lane & 15, q = lane >> 4;
  const int srow = lane >> 3;
  const int scol = (lane & 7) * 8;

  f32x4 acc[4][2];
#pragma unroll
  for (int i = 0; i < 4; ++i)
#pragma unroll
    for (int j = 0; j < 2; ++j) acc[i][j] = (f32x4){0.f, 0.f, 0.f, 0.f};

  const bf16* Xb = X + (size_t)bm * K;
  const bf16* Wb = W + (size_t)bn * K;

  for (int k0 = 0; k0 < K; k0 += 64) {
    __syncthreads();
#pragma unroll
    for (int i = 0; i < 2; ++i) {
      const int r = w * 16 + i * 8 + srow;
      gl16(Xb + (size_t)r * K + k0 + scol, &As[r * 64 + scol]);
      gl16(Wb + (size_t)r * K + k0 + scol, &Bs[r * 64 + scol]);
    }
    __syncthreads();
#pragma unroll
    for (int kk = 0; kk < 2; ++kk) {
      short8 af[4], bfr[2];
#pragma unroll
      for (int i = 0; i < 4; ++i)
        af[i] = *reinterpret_cast<const short8*>(&As[(wr * 64 + i * 16 + fr) * 64 + kk * 32 + q * 8]);
#pragma unroll
      for (int j = 0; j < 2; ++j)
        bfr[j] = *reinterpret_cast<const short8*>(&Bs[(wc * 32 + j * 16 + fr) * 64 + kk * 32 + q * 8]);
#pragma unroll
      for (int i = 0; i < 4; ++i)
#pragma unroll
        for (int j = 0; j < 2; ++j)
          acc[i][j] = __builtin_amdgcn_mfma_f32_16x16x32_bf16(af[i], bfr[j], acc[i][j], 0, 0, 0);
    }
  }

#pragma unroll
  for (int j = 0; j < 2; ++j) {
    const int gcol = bn + wc * 32 + j * 16 + fr;
    const float bv = bias[gcol];
#pragma unroll
    for (int i = 0; i < 4; ++i) {
      const int grow0 = bm + wr * 64 + i * 16 + q * 4;
#pragma unroll
      for (int r = 0; r < 4; ++r) {
        float v = acc[i][j][r] + bv;
        if (EPI == 1) v = gelu_f(v);
        if (EPI == 3) v = 1.f / (1.f + expf(-v));
        if constexpr (sizeof(TY) == 2) Y[(size_t)(grow0 + r) * N + gcol] = f2b(v);
        else                           ((float*)Y)[(size_t)(grow0 + r) * N + gcol] = v;
      }
    }
  }
}

// ---------------- narrow-N GEMM: 128x64 tile, BK=64, 4 waves (2x2), wave tile 64x32 ----------------
// For deep-K / small-N shapes (gate, proj): doubles blocks/CU for cross-block overlap.
template<int EPI, typename TY>
__global__ __launch_bounds__(256) void gemm_bf16_n64(
    const bf16* __restrict__ X, const bf16* __restrict__ W,
    const float* __restrict__ bias, TY* __restrict__ Y,
    int M, int N, int K, int nbx)
{
  __shared__ __align__(16) bf16 As[128 * 64];
  __shared__ __align__(16) bf16 Bs[64 * 64];
  const int nwg = gridDim.x;
  const int bid = blockIdx.x;
  const int swz = (bid & 7) * (nwg >> 3) + (bid >> 3);
  const int bm = (swz / nbx) * 128;
  const int bn = (swz % nbx) * 64;
  const int tid = threadIdx.x;
  const int lane = tid & 63;
  const int w = tid >> 6;                 // 0..3
  const int wr = w >> 1, wc = w & 1;      // 2x2 wave grid; wave tile 64 x 32
  const int fr = lane & 15, q = lane >> 4;
  const int srow = lane >> 3;
  const int scol = (lane & 7) * 8;

  f32x4 acc[4][2];
#pragma unroll
  for (int i = 0; i < 4; ++i)
#pragma unroll
    for (int j = 0; j < 2; ++j) acc[i][j] = (f32x4){0.f, 0.f, 0.f, 0.f};

  const bf16* Xb = X + (size_t)bm * K;
  const bf16* Wb = W + (size_t)bn * K;

  for (int k0 = 0; k0 < K; k0 += 64) {
    __syncthreads();
#pragma unroll
    for (int i = 0; i < 4; ++i) {        // A: wave w stages rows [w*32, w*32+32)
      const int r = w * 32 + i * 8 + srow;
      gl16(Xb + (size_t)r * K + k0 + scol, &As[r * 64 + scol]);
    }
#pragma unroll
    for (int i = 0; i < 2; ++i) {        // B: wave w stages rows [w*16, w*16+16)
      const int r = w * 16 + i * 8 + srow;
      gl16(Wb + (size_t)r * K + k0 + scol, &Bs[r * 64 + scol]);
    }
    __syncthreads();
#pragma unroll
    for (int kk = 0; kk < 2; ++kk) {
      short8 af[4], bfr[2];
#pragma unroll
      for (int i = 0; i < 4; ++i)
        af[i] = *reinterpret_cast<const short8*>(&As[(wr * 64 + i * 16 + fr) * 64 + kk * 32 + q * 8]);
#pragma unroll
      for (int j = 0; j < 2; ++j)
        bfr[j] = *reinterpret_cast<const short8*>(&Bs[(wc * 32 + j * 16 + fr) * 64 + kk * 32 + q * 8]);
#pragma unroll
      for (int i = 0; i < 4; ++i)
#pragma unroll
        for (int j = 0; j < 2; ++j)
          acc[i][j] = __builtin_amdgcn_mfma_f32_16x16x32_bf16(af[i], bfr[j], acc[i][j], 0, 0, 0);
    }
  }

#pragma unroll
  for (int j = 0; j < 2; ++j) {
    const int gcol = bn + wc * 32 + j * 16 + fr;
    const float bv = bias[gcol];
#pragma unroll
    for (int i = 0; i < 4; ++i) {
      const int grow0 = bm + wr * 64 + i * 16 + q * 4;
#pragma unroll
      for (int r = 0; r < 4; ++r) {
        float v = acc[i][j][r] + bv;
        if (EPI == 1) v = gelu_f(v);
        if (EPI == 3) v = 1.f / (1.f + expf(-v));
        if constexpr (sizeof(TY) == 2) Y[(size_t)(grow0 + r) * N + gcol] = f2b(v);
        else                           ((float*)Y)[(size_t)(grow0 + r) * N + gcol] = v;
      }
    }
  }
}

// ---------------- Compression MLP (unchanged) ----------------
__global__ __launch_bounds__(64) void comp_mlp(
    const bf16* __restrict__ kvbuf, int s,
    const float* __restrict__ fc1W, const float* __restrict__ fc1b,
    const float* __restrict__ fc2W, const float* __restrict__ fc2b,
    const float* __restrict__ rpW,  const float* __restrict__ rpb,
    const float* __restrict__ wpe,  bf16* __restrict__ outp)
{
  __shared__ float s_fc1W[128 * 32];
  __shared__ float s_fc1b[128];
  __shared__ float s_fc2W[128];
  const int id = blockIdx.x;
  const int blk = id % kNB;
  const int h = (id / kNB) % kNH;
  const int b = id / (kNB * kNH);
  const int d = threadIdx.x;
  for (int i = d; i < 128 * 32; i += 64) s_fc1W[i] = fc1W[i];
  for (int i = d; i < 128; i += 64) { s_fc1b[i] = fc1b[i]; s_fc2W[i] = fc2W[i]; }
  __syncthreads();

  float xu[kL], xpe[kL];
  const int t0 = blk * kST;
  const bf16* base = kvbuf + ((size_t)(b * kT + t0) * (2 * kC)) + (size_t)s * kC + h * kHS + d;
#pragma unroll
  for (int l = 0; l < kL; ++l) {
    float u = b2f(base[(size_t)l * (2 * kC)]);
    xu[l] = u;
    xpe[l] = u + wpe[l * kHS + d];
  }
  float out = fc2b[0];
  for (int j = 0; j < 128; ++j) {
    float a = s_fc1b[j];
#pragma unroll
    for (int l = 0; l < kL; ++l) a = fmaf(xpe[l], s_fc1W[j * kL + l], a);
    out = fmaf(gelu_f(a), s_fc2W[j], out);
  }
  float res = rpb[0];
#pragma unroll
  for (int l = 0; l < kL; ++l) res = fmaf(xu[l], rpW[l], res);
  float r = out + res;
  r = fminf(3.0f, fmaxf(-3.0f, r));
  outp[((size_t)(b * kNH + h) * kNB + blk) * kHS + d] = f2b(r);
}

// ---------------- Local sliding-window attention: MFMA flash (batch in grid.z) ----------------
__global__ __launch_bounds__(256) void local_attn_mfma(
    const bf16* __restrict__ qkv, bf16* __restrict__ ybuf0)
{
  __shared__ __align__(16) short Qs[64 * 64];
  __shared__ __align__(16) short Ks[64 * 64];
  __shared__ __align__(16) short VTs[64 * 64];
  __shared__ __align__(16) short Ps[64 * 64];
  const int tid = threadIdx.x;
  const int lane = tid & 63;
  const int w = tid >> 6;
  const int fr = lane & 15;
  const int g  = lane >> 4;
  const int h  = blockIdx.y;
  const int b  = blockIdx.z;
  const int t0 = blockIdx.x * 64;
  bf16* ybuf = ybuf0 + (size_t)b * kT * kC;
  const size_t rs = 3 * kC;
  const bf16* qbase = qkv + ((size_t)b * kT) * rs + h * kHS;
  const bf16* kbase = qbase + kC;
  const bf16* vbase = qbase + 2 * kC;

  for (int c = tid; c < 512; c += 256) {
    const int r = c >> 3, p = c & 7;
    short8 v = *reinterpret_cast<const short8*>(qbase + (size_t)(t0 + r) * rs + p * 8);
    *reinterpret_cast<short8*>(&Qs[r * 64 + ((p ^ (r & 7)) << 3)]) = v;
  }
  __syncthreads();
  short8 qf[2];
  {
    const int r = w * 16 + fr;
#pragma unroll
    for (int dc = 0; dc < 2; ++dc) {
      const int d0 = dc * 32 + g * 8;
      qf[dc] = *reinterpret_cast<const short8*>(&Qs[r * 64 + (d0 ^ ((r & 7) << 3))]);
    }
  }

  f32x4 acc[4];
  float m[4], l[4];
#pragma unroll
  for (int r = 0; r < 4; ++r) { m[r] = -1e30f; l[r] = 0.f; }
#pragma unroll
  for (int dt = 0; dt < 4; ++dt) acc[dt] = (f32x4){0.f, 0.f, 0.f, 0.f};

  const int jb0 = (t0 >= 256) ? (t0 - 256) : 0;
  for (int jb = jb0; jb <= t0; jb += 64) {
    const bool masked = (jb == t0 - 256) || (jb == t0);
    __syncthreads();
    for (int c = tid; c < 512; c += 256) {
      const int r = c >> 3, p = c & 7;
      short8 v = *reinterpret_cast<const short8*>(kbase + (size_t)(jb + r) * rs + p * 8);
      *reinterpret_cast<short8*>(&Ks[r * 64 + ((p ^ (r & 7)) << 3)]) = v;
    }
    for (int c = tid; c < 512; c += 256) {
      const int r = c >> 3, p = c & 7;
      short8 v = *reinterpret_cast<const short8*>(vbase + (size_t)(jb + r) * rs + p * 8);
#pragma unroll
      for (int e = 0; e < 8; ++e) {
        const int d = p * 8 + e;
        VTs[d * 64 + (r ^ ((d & 7) << 3))] = v[e];
      }
    }
    __syncthreads();

    f32x4 S[4];
#pragma unroll
    for (int ks = 0; ks < 4; ++ks) S[ks] = (f32x4){0.f, 0.f, 0.f, 0.f};
#pragma unroll
    for (int ks = 0; ks < 4; ++ks) {
      const int kr = ks * 16 + fr;
#pragma unroll
      for (int dc = 0; dc < 2; ++dc) {
        const int d0 = dc * 32 + g * 8;
        short8 kf = *reinterpret_cast<const short8*>(&Ks[kr * 64 + (d0 ^ ((kr & 7) << 3))]);
        S[ks] = __builtin_amdgcn_mfma_f32_16x16x32_bf16(qf[dc], kf, S[ks], 0, 0, 0);
      }
    }

    const int qrow0 = t0 + w * 16 + g * 4;
    float rowmax[4];
#pragma unroll
    for (int r = 0; r < 4; ++r) rowmax[r] = -1e30f;
#pragma unroll
    for (int ks = 0; ks < 4; ++ks) {
      const int j = jb + ks * 16 + fr;
#pragma unroll
      for (int r = 0; r < 4; ++r) {
        float s = S[ks][r] * 0.125f;
        if (masked) {
          const int i = qrow0 + r;
          if (!((j <= i) && (j > i - 256))) s = -1e30f;
        }
        S[ks][r] = s;
        rowmax[r] = fmaxf(rowmax[r], s);
      }
    }
#pragma unroll
    for (int off = 1; off <= 8; off <<= 1)
#pragma unroll
      for (int r = 0; r < 4; ++r)
        rowmax[r] = fmaxf(rowmax[r], __shfl_xor(rowmax[r], off));

    float resc[4], psum[4];
#pragma unroll
    for (int r = 0; r < 4; ++r) {
      const float mn = fmaxf(m[r], rowmax[r]);
      resc[r] = __expf(m[r] - mn);
      m[r] = mn;
      psum[r] = 0.f;
    }
#pragma unroll
    for (int ks = 0; ks < 4; ++ks) {
      const int j = jb + ks * 16 + fr;
#pragma unroll
      for (int r = 0; r < 4; ++r) {
        float p = __expf(S[ks][r] - m[r]);
        if (masked) {
          const int i = qrow0 + r;
          if (!((j <= i) && (j > i - 256))) p = 0.f;
        }
        S[ks][r] = p;
        psum[r] += p;
      }
    }
#pragma unroll
    for (int off = 1; off <= 8; off <<= 1)
#pragma unroll
      for (int r = 0; r < 4; ++r) psum[r] += __shfl_xor(psum[r], off);
#pragma unroll
    for (int r = 0; r < 4; ++r) l[r] = l[r] * resc[r] + psum[r];
#pragma unroll
    for (int dt = 0; dt < 4; ++dt)
#pragma unroll
      for (int r = 0; r < 4; ++r) acc[dt][r] *= resc[r];

#pragma unroll
    for (int ks = 0; ks < 4; ++ks)
#pragma unroll
      for (int r = 0; r < 4; ++r) {
        const int prow = w * 16 + g * 4 + r;
        const int pcol = ks * 16 + fr;
        Ps[prow * 64 + (pcol ^ ((prow & 7) << 3))] = fbits(S[ks][r]);
      }

#pragma unroll
    for (int kc = 0; kc < 2; ++kc) {
      const int prow = w * 16 + fr;
      const int k0 = kc * 32 + g * 8;
      short8 pf = *reinterpret_cast<const short8*>(&Ps[prow * 64 + (k0 ^ ((prow & 7) << 3))]);
#pragma unroll
      for (int dt = 0; dt < 4; ++dt) {
        const int dr = dt * 16 + fr;
        short8 vf = *reinterpret_cast<const short8*>(&VTs[dr * 64 + (k0 ^ ((dr & 7) << 3))]);
        acc[dt] = __builtin_amdgcn_mfma_f32_16x16x32_bf16(pf, vf, acc[dt], 0, 0, 0);
      }
    }
  }

#pragma unroll
  for (int dt = 0; dt < 4; ++dt)
#pragma unroll
    for (int r = 0; r < 4; ++r) {
      const int i = t0 + w * 16 + g * 4 + r;
      const int d = dt * 16 + fr;
      ybuf[(size_t)i * kC + h * kHS + d] = f2b(acc[dt][r] / l[r]);
    }
}

// ---------------- Compressed attention: MFMA flash + fused gate mix (batch in grid.z) ----------------
__global__ __launch_bounds__(256) void comp_attn_mfma(
    const bf16* __restrict__ qkv, const bf16* __restrict__ kcomp,
    const bf16* __restrict__ vcomp, const bf16* __restrict__ gate,
    bf16* __restrict__ ybuf0)
{
  __shared__ __align__(16) short Qs[64 * 64];
  __shared__ __align__(16) short Ks[64 * 64];
  __shared__ __align__(16) short VTs[64 * 64];
  __shared__ __align__(16) short Ps[64 * 64];
  const int tid = threadIdx.x;
  const int lane = tid & 63;
  const int w = tid >> 6;
  const int fr = lane & 15;
  const int g  = lane >> 4;
  const int h  = blockIdx.y;
  const int b  = blockIdx.z;
  const int t0 = blockIdx.x * 64;
  bf16* ybuf = ybuf0 + (size_t)b * kT * kC;
  const size_t rs = 3 * kC;
  const bf16* qbase = qkv + ((size_t)b * kT) * rs + h * kHS;
  const bf16* kb = kcomp + ((size_t)(b * kNH + h)) * kNB * kHS;
  const bf16* vb = vcomp + ((size_t)(b * kNH + h)) * kNB * kHS;

  for (int c = tid; c < 512; c += 256) {
    const int r = c >> 3, p = c & 7;
    short8 v = *reinterpret_cast<const short8*>(qbase + (size_t)(t0 + r) * rs + p * 8);
    *reinterpret_cast<short8*>(&Qs[r * 64 + ((p ^ (r & 7)) << 3)]) = v;
  }
  __syncthreads();
  short8 qf[2];
  {
    const int r = w * 16 + fr;
#pragma unroll
    for (int dc = 0; dc < 2; ++dc) {
      const int d0 = dc * 32 + g * 8;
      qf[dc] = *reinterpret_cast<const short8*>(&Qs[r * 64 + (d0 ^ ((r & 7) << 3))]);
    }
  }

  f32x4 acc[4];
  float m[4], l[4];
#pragma unroll
  for (int r = 0; r < 4; ++r) { m[r] = -1e30f; l[r] = 0.f; }
#pragma unroll
  for (int dt = 0; dt < 4; ++dt) acc[dt] = (f32x4){0.f, 0.f, 0.f, 0.f};

  const int ntiles = (t0 >= 1024) ? 2 : 1;
  for (int tb = 0; tb < ntiles; ++tb) {
    const int jb = tb * 64;
    const bool masked = !(((jb + 63) < kNB) && ((jb + 63) * kST < t0));
    __syncthreads();
    for (int c = tid; c < 512; c += 256) {
      const int r = c >> 3, p = c & 7;
      const int rr = (jb + r < kNB) ? (jb + r) : (kNB - 1);
      short8 v = *reinterpret_cast<const short8*>(kb + (size_t)rr * kHS + p * 8);
      *reinterpret_cast<short8*>(&Ks[r * 64 + ((p ^ (r & 7)) << 3)]) = v;
    }
    for (int c = tid; c < 512; c += 256) {
      const int r = c >> 3, p = c & 7;
      const int rr = (jb + r < kNB) ? (jb + r) : (kNB - 1);
      short8 v = *reinterpret_cast<const short8*>(vb + (size_t)rr * kHS + p * 8);
#pragma unroll
      for (int e = 0; e < 8; ++e) {
        const int d = p * 8 + e;
        VTs[d * 64 + (r ^ ((d & 7) << 3))] = v[e];
      }
    }
    __syncthreads();

    f32x4 S[4];
#pragma unroll
    for (int ks = 0; ks < 4; ++ks) S[ks] = (f32x4){0.f, 0.f, 0.f, 0.f};
#pragma unroll
    for (int ks = 0; ks < 4; ++ks) {
      const int kr = ks * 16 + fr;
#pragma unroll
      for (int dc = 0; dc < 2; ++dc) {
        const int d0 = dc * 32 + g * 8;
        short8 kf = *reinterpret_cast<const short8*>(&Ks[kr * 64 + (d0 ^ ((kr & 7) << 3))]);
        S[ks] = __builtin_amdgcn_mfma_f32_16x16x32_bf16(qf[dc], kf, S[ks], 0, 0, 0);
      }
    }

    const int qrow0 = t0 + w * 16 + g * 4;
    float rowmax[4];
#pragma unroll
    for (int r = 0; r < 4; ++r) rowmax[r] = -1e30f;
#pragma unroll
    for (int ks = 0; ks < 4; ++ks) {
      const int n = jb + ks * 16 + fr;
#pragma unroll
      for (int r = 0; r < 4; ++r) {
        float s = S[ks][r] * 0.125f;
        if (masked) {
          const int i = qrow0 + r;
          if (!((n < kNB) && (n * kST < i))) s = -1e30f;
        }
        S[ks][r] = s;
        rowmax[r] = fmaxf(rowmax[r], s);
      }
    }
#pragma unroll
    for (int off = 1; off <= 8; off <<= 1)
#pragma unroll
      for (int r = 0; r < 4; ++r)
        rowmax[r] = fmaxf(rowmax[r], __shfl_xor(rowmax[r], off));

    float resc[4], psum[4];
#pragma unroll
    for (int r = 0; r < 4; ++r) {
      const float mn = fmaxf(m[r], rowmax[r]);
      resc[r] = __expf(m[r] - mn);
      m[r] = mn;
      psum[r] = 0.f;
    }
#pragma unroll
    for (int ks = 0; ks < 4; ++ks) {
      const int n = jb + ks * 16 + fr;
#pragma unroll
      for (int r = 0; r < 4; ++r) {
        float p = __expf(S[ks][r] - m[r]);
        if (masked) {
          const int i = qrow0 + r;
          if (!((n < kNB) && (n * kST < i))) p = 0.f;
        }
        S[ks][r] = p;
        psum[r] += p;
      }
    }
#pragma unroll
    for (int off = 1; off <= 8; off <<= 1)
#pragma unroll
      for (int r = 0; r < 4; ++r) psum[r] += __shfl_xor(psum[r], off);
#pragma unroll
    for (int r = 0; r < 4; ++r) l[r] = l[r] * resc[r] + psum[r];
#pragma unroll
    for (int dt = 0; dt < 4; ++dt)
#pragma unroll
      for (int r = 0; r < 4; ++r) acc[dt][r] *= resc[r];

#pragma unroll
    for (int ks = 0; ks < 4; ++ks)
#pragma unroll
      for (int r = 0; r < 4; ++r) {
        const int prow = w * 16 + g * 4 + r;
        const int pcol = ks * 16 + fr;
        Ps[prow * 64 + (pcol ^ ((prow & 7) << 3))] = fbits(S[ks][r]);
      }

#pragma unroll
    for (int kc = 0; kc < 2; ++kc) {
      const int prow = w * 16 + fr;
      const int k0 = kc * 32 + g * 8;
      short8 pf = *reinterpret_cast<const short8*>(&Ps[prow * 64 + (k0 ^ ((prow & 7) << 3))]);
#pragma unroll
      for (int dt = 0; dt < 4; ++dt) {
        const int dr = dt * 16 + fr;
        short8 vf = *reinterpret_cast<const short8*>(&VTs[dr * 64 + (k0 ^ ((dr & 7) << 3))]);
        acc[dt] = __builtin_amdgcn_mfma_f32_16x16x32_bf16(pf, vf, acc[dt], 0, 0, 0);
      }
    }
  }

#pragma unroll
  for (int r = 0; r < 4; ++r) {
    const int i = t0 + w * 16 + g * 4 + r;
    const float inv = (l[r] > 0.f) ? (1.f / l[r]) : 0.f;
#pragma unroll
    for (int dt = 0; dt < 4; ++dt) {
      const int d = dt * 16 + fr;
      const size_t idx = (size_t)i * kC + h * kHS + d;
      const float yc = acc[dt][r] * inv;
      const float gg = b2f(gate[((size_t)(b * kT + i)) * kC + h * kHS + d]);
      const float yl = b2f(ybuf[idx]);
      ybuf[idx] = f2b(gg * yl + (1.f - gg) * yc);
    }
  }
}

extern "C" void kernel_launch(void* const* d_in, const int* in_sizes, int n_in,
                              void* d_out, int out_size, void* d_ws, size_t ws_size,
                              hipStream_t stream)
{
  (void)in_sizes; (void)n_in; (void)out_size; (void)ws_size; (void)kM; (void)kWIN;
  const float* x      = (const float*)d_in[0];
  const float* Wqkv   = (const float*)d_in[1];
  const float* bqkv   = (const float*)d_in[2];
  const float* Wcomp  = (const float*)d_in[3];
  const float* bcomp  = (const float*)d_in[4];
  const float* Wproj  = (const float*)d_in[5];
  const float* bproj  = (const float*)d_in[6];
  const float* k_fc1W = (const float*)d_in[7];
  const float* k_fc1b = (const float*)d_in[8];
  const float* k_fc2W = (const float*)d_in[9];
  const float* k_fc2b = (const float*)d_in[10];
  const float* k_rpW  = (const float*)d_in[11];
  const float* k_rpb  = (const float*)d_in[12];
  const float* k_wpe  = (const float*)d_in[13];
  const float* v_fc1W = (const float*)d_in[14];
  const float* v_fc1b = (const float*)d_in[15];
  const float* v_fc2W = (const float*)d_in[16];
  const float* v_fc2b = (const float*)d_in[17];
  const float* v_rpW  = (const float*)d_in[18];
  const float* v_rpb  = (const float*)d_in[19];
  const float* v_wpe  = (const float*)d_in[20];
  const float* Wg1    = (const float*)d_in[21];
  const float* bg1    = (const float*)d_in[22];
  const float* Wg2    = (const float*)d_in[23];
  const float* bg2    = (const float*)d_in[24];

  // ---- Workspace (peak 51,372,032 B, identical to proven footprint) ----
  char* wsb = (char*)d_ws;
  bf16* xbf   = (bf16*)(wsb + 0);
  bf16* wscr  = (bf16*)(wsb + 8388608);
  bf16* big   = (bf16*)(wsb + 16777216);
  bf16* ybuf  = (bf16*)(wsb + 41943040);
  bf16* kcomp = (bf16*)(wsb + 50331648);
  bf16* vcomp = (bf16*)(wsb + 50851840);
  bf16* gate  = (bf16*)((char*)d_out + 8388608);
  float* out  = (float*)d_out;

  const int cg = 2048;
  f32_to_bf16<<<cg, 256, 0, stream>>>(x, xbf, 1048576);
  f32_to_bf16<<<cg, 256, 0, stream>>>(Wg1, wscr, 1048576);
  gemm_bf16<1, bf16><<<1024, 512, 0, stream>>>(xbf, wscr, bg1, big, 4096, 4096, 1024, 32);
  f32_to_bf16<<<cg, 256, 0, stream>>>(Wg2, wscr, 1048576);
  gemm_bf16_n64<3, bf16><<<512, 256, 0, stream>>>(big, wscr, bg2, gate, 4096, 1024, 4096, 16);
  f32_to_bf16<<<cg, 256, 0, stream>>>(Wcomp, wscr, 524288);
  gemm_bf16<0, bf16><<<512, 512, 0, stream>>>(xbf, wscr, bcomp, big, 4096, 2048, 1024, 16);
  comp_mlp<<<kB * kNH * kNB, 64, 0, stream>>>(big, 0, k_fc1W, k_fc1b, k_fc2W, k_fc2b, k_rpW, k_rpb, k_wpe, kcomp);
  comp_mlp<<<kB * kNH * kNB, 64, 0, stream>>>(big, 1, v_fc1W, v_fc1b, v_fc2W, v_fc2b, v_rpW, v_rpb, v_wpe, vcomp);
  f32_to_bf16<<<cg, 256, 0, stream>>>(Wqkv, wscr, 786432);
  gemm_bf16<0, bf16><<<768, 512, 0, stream>>>(xbf, wscr, bqkv, big, 4096, 3072, 1024, 24);
  f32_to_bf16<<<cg, 256, 0, stream>>>(Wproj, wscr, 262144);
  // attention for both batches (batch = blockIdx.z); gate consumed here
  local_attn_mfma<<<dim3(kT / 64, kNH, kB), 256, 0, stream>>>(big, ybuf);
  comp_attn_mfma<<<dim3(kT / 64, kNH, kB), 256, 0, stream>>>(big, kcomp, vcomp, gate, ybuf);
  // single merged projection over both batches (overwrites gate region after use)
  gemm_bf16_n64<0, float><<<512, 256, 0, stream>>>(ybuf, wscr, bproj, out, 4096, 1024, 1024, 16);
}

// Round 13
// 373.972 us; speedup vs baseline: 9.8004x; 1.2348x over previous
//
#include <hip/hip_runtime.h>
#include <hip/hip_bf16.h>

typedef __hip_bfloat16 bf16;

constexpr int kB = 2, kT = 2048, kC = 1024, kNH = 16, kHS = 64;
constexpr int kL = 32, kST = 16, kWIN = 256;
constexpr int kNB = (kT - kL) / kST + 1;   // 127
constexpr int kM = kB * kT;                // 4096

typedef __attribute__((ext_vector_type(8))) short short8;   // bf16 MFMA A/B frag (4 VGPRs)
typedef __attribute__((ext_vector_type(4))) short short4v;
typedef __attribute__((ext_vector_type(4))) float f32x4;

__device__ __forceinline__ float b2f(bf16 v) { return __bfloat162float(v); }
__device__ __forceinline__ bf16  f2b(float v) { return __float2bfloat16(v); }
__device__ __forceinline__ float bu2f(unsigned int u) { return __uint_as_float(u << 16); }
__device__ __forceinline__ float gelu_f(float v) { return 0.5f * v * (1.0f + erff(v * 0.70710678118654752f)); }
__device__ __forceinline__ short fbits(float v) {
  return (short)__builtin_bit_cast(unsigned short, f2b(v));
}
// async global->LDS, 16 bytes per lane (dest = wave-uniform base + lane*16)
__device__ __forceinline__ void gl16(const bf16* g, bf16* l) {
  __builtin_amdgcn_global_load_lds(
      (const __attribute__((address_space(1))) void*)g,
      (__attribute__((address_space(3))) void*)l, 16, 0, 0);
}

// ---------------- fp32 -> bf16 conversion (vectorized, grid-stride) ----------------
__global__ __launch_bounds__(256) void f32_to_bf16(const float* __restrict__ src,
                                                   bf16* __restrict__ dst, int n4) {
  int i = blockIdx.x * 256 + threadIdx.x;
  const int stride = gridDim.x * 256;
  for (; i < n4; i += stride) {
    float4 v = ((const float4*)src)[i];
    short4v w; w.x = fbits(v.x); w.y = fbits(v.y); w.z = fbits(v.z); w.w = fbits(v.w);
    ((short4v*)dst)[i] = w;
  }
}

// ---------------- all-bf16 MFMA GEMM: 128x128 tile, BK=64, 8 waves (2x4) ----------------
template<int EPI, typename TY>
__global__ __launch_bounds__(512) void gemm_bf16(
    const bf16* __restrict__ X, const bf16* __restrict__ W,
    const float* __restrict__ bias, TY* __restrict__ Y,
    int M, int N, int K, int nbx)
{
  __shared__ __align__(16) bf16 As[128 * 64];
  __shared__ __align__(16) bf16 Bs[128 * 64];
  const int nwg = gridDim.x;
  const int bid = blockIdx.x;
  const int swz = (bid & 7) * (nwg >> 3) + (bid >> 3);
  const int bm = (swz / nbx) * 128;
  const int bn = (swz % nbx) * 128;
  const int tid = threadIdx.x;
  const int lane = tid & 63;
  const int w = tid >> 6;
  const int wr = w >> 2, wc = w & 3;      // 2x4 wave grid; wave tile 64 x 32
  const int fr = lane & 15, q = lane >> 4;
  const int srow = lane >> 3;
  const int scol = (lane & 7) * 8;

  f32x4 acc[4][2];
#pragma unroll
  for (int i = 0; i < 4; ++i)
#pragma unroll
    for (int j = 0; j < 2; ++j) acc[i][j] = (f32x4){0.f, 0.f, 0.f, 0.f};

  const bf16* Xb = X + (size_t)bm * K;
  const bf16* Wb = W + (size_t)bn * K;

  for (int k0 = 0; k0 < K; k0 += 64) {
    __syncthreads();
#pragma unroll
    for (int i = 0; i < 2; ++i) {
      const int r = w * 16 + i * 8 + srow;
      gl16(Xb + (size_t)r * K + k0 + scol, &As[r * 64 + scol]);
      gl16(Wb + (size_t)r * K + k0 + scol, &Bs[r * 64 + scol]);
    }
    __syncthreads();
#pragma unroll
    for (int kk = 0; kk < 2; ++kk) {
      short8 af[4], bfr[2];
#pragma unroll
      for (int i = 0; i < 4; ++i)
        af[i] = *reinterpret_cast<const short8*>(&As[(wr * 64 + i * 16 + fr) * 64 + kk * 32 + q * 8]);
#pragma unroll
      for (int j = 0; j < 2; ++j)
        bfr[j] = *reinterpret_cast<const short8*>(&Bs[(wc * 32 + j * 16 + fr) * 64 + kk * 32 + q * 8]);
#pragma unroll
      for (int i = 0; i < 4; ++i)
#pragma unroll
        for (int j = 0; j < 2; ++j)
          acc[i][j] = __builtin_amdgcn_mfma_f32_16x16x32_bf16(af[i], bfr[j], acc[i][j], 0, 0, 0);
    }
  }

#pragma unroll
  for (int j = 0; j < 2; ++j) {
    const int gcol = bn + wc * 32 + j * 16 + fr;
    const float bv = bias[gcol];
#pragma unroll
    for (int i = 0; i < 4; ++i) {
      const int grow0 = bm + wr * 64 + i * 16 + q * 4;
#pragma unroll
      for (int r = 0; r < 4; ++r) {
        float v = acc[i][j][r] + bv;
        if (EPI == 1) v = gelu_f(v);
        if (EPI == 3) v = 1.f / (1.f + expf(-v));
        if constexpr (sizeof(TY) == 2) Y[(size_t)(grow0 + r) * N + gcol] = f2b(v);
        else                           ((float*)Y)[(size_t)(grow0 + r) * N + gcol] = v;
      }
    }
  }
}

// ---------------- narrow-N GEMM: 128x64 tile, BK=64, 4 waves (2x2), wave tile 64x32 ----------------
template<int EPI, typename TY>
__global__ __launch_bounds__(256) void gemm_bf16_n64(
    const bf16* __restrict__ X, const bf16* __restrict__ W,
    const float* __restrict__ bias, TY* __restrict__ Y,
    int M, int N, int K, int nbx)
{
  __shared__ __align__(16) bf16 As[128 * 64];
  __shared__ __align__(16) bf16 Bs[64 * 64];
  const int nwg = gridDim.x;
  const int bid = blockIdx.x;
  const int swz = (bid & 7) * (nwg >> 3) + (bid >> 3);
  const int bm = (swz / nbx) * 128;
  const int bn = (swz % nbx) * 64;
  const int tid = threadIdx.x;
  const int lane = tid & 63;
  const int w = tid >> 6;                 // 0..3
  const int wr = w >> 1, wc = w & 1;      // 2x2 wave grid; wave tile 64 x 32
  const int fr = lane & 15, q = lane >> 4;
  const int srow = lane >> 3;
  const int scol = (lane & 7) * 8;

  f32x4 acc[4][2];
#pragma unroll
  for (int i = 0; i < 4; ++i)
#pragma unroll
    for (int j = 0; j < 2; ++j) acc[i][j] = (f32x4){0.f, 0.f, 0.f, 0.f};

  const bf16* Xb = X + (size_t)bm * K;
  const bf16* Wb = W + (size_t)bn * K;

  for (int k0 = 0; k0 < K; k0 += 64) {
    __syncthreads();
#pragma unroll
    for (int i = 0; i < 4; ++i) {
      const int r = w * 32 + i * 8 + srow;
      gl16(Xb + (size_t)r * K + k0 + scol, &As[r * 64 + scol]);
    }
#pragma unroll
    for (int i = 0; i < 2; ++i) {
      const int r = w * 16 + i * 8 + srow;
      gl16(Wb + (size_t)r * K + k0 + scol, &Bs[r * 64 + scol]);
    }
    __syncthreads();
#pragma unroll
    for (int kk = 0; kk < 2; ++kk) {
      short8 af[4], bfr[2];
#pragma unroll
      for (int i = 0; i < 4; ++i)
        af[i] = *reinterpret_cast<const short8*>(&As[(wr * 64 + i * 16 + fr) * 64 + kk * 32 + q * 8]);
#pragma unroll
      for (int j = 0; j < 2; ++j)
        bfr[j] = *reinterpret_cast<const short8*>(&Bs[(wc * 32 + j * 16 + fr) * 64 + kk * 32 + q * 8]);
#pragma unroll
      for (int i = 0; i < 4; ++i)
#pragma unroll
        for (int j = 0; j < 2; ++j)
          acc[i][j] = __builtin_amdgcn_mfma_f32_16x16x32_bf16(af[i], bfr[j], acc[i][j], 0, 0, 0);
    }
  }

#pragma unroll
  for (int j = 0; j < 2; ++j) {
    const int gcol = bn + wc * 32 + j * 16 + fr;
    const float bv = bias[gcol];
#pragma unroll
    for (int i = 0; i < 4; ++i) {
      const int grow0 = bm + wr * 64 + i * 16 + q * 4;
#pragma unroll
      for (int r = 0; r < 4; ++r) {
        float v = acc[i][j][r] + bv;
        if (EPI == 1) v = gelu_f(v);
        if (EPI == 3) v = 1.f / (1.f + expf(-v));
        if constexpr (sizeof(TY) == 2) Y[(size_t)(grow0 + r) * N + gcol] = f2b(v);
        else                           ((float*)Y)[(size_t)(grow0 + r) * N + gcol] = v;
      }
    }
  }
}

// ---------------- Compression MLP via MFMA ----------------
// One 256-thread block per (blk, h, b). h = gelu(XPE @ fc1W^T + fc1b); out = h@fc2W + xu@rpW + consts.
// XPE: 64(d) x 32(L) bf16 in LDS (pad 40); FC1: 128(j) x 32 bf16 (pad 40).
// Wave w: rows d in [w*16, w*16+16); 8 MFMAs (16x16x32, K=32 in one shot).
__global__ __launch_bounds__(256) void comp_mlp_mfma(
    const bf16* __restrict__ kvbuf, int s,
    const float* __restrict__ fc1W, const float* __restrict__ fc1b,
    const float* __restrict__ fc2W, const float* __restrict__ fc2b,
    const float* __restrict__ rpW,  const float* __restrict__ rpb,
    const float* __restrict__ wpe,  bf16* __restrict__ outp)
{
  __shared__ __align__(16) short XPE[64 * 40];
  __shared__ __align__(16) short XU [64 * 40];
  __shared__ __align__(16) short FC1[128 * 40];
  __shared__ float s_fc1b[128];
  __shared__ float s_fc2W[128];
  __shared__ float s_rpW[32];
  const int tid = threadIdx.x;
  const int lane = tid & 63;
  const int w = tid >> 6;
  const int fr = lane & 15, q = lane >> 4;
  const int blk = blockIdx.x;
  const int h = blockIdx.y;
  const int b = blockIdx.z;
  const int t0 = blk * kST;

  // stage fc1W (4096 fp32 -> bf16), 16 elems/thread
  {
    const int base = tid * 16;
#pragma unroll
    for (int c = 0; c < 4; ++c) {
      float4 v = *reinterpret_cast<const float4*>(fc1W + base + c * 4);
      const int idx = base + c * 4;
      short* dst = &FC1[(idx >> 5) * 40 + (idx & 31)];
      dst[0] = fbits(v.x); dst[1] = fbits(v.y); dst[2] = fbits(v.z); dst[3] = fbits(v.w);
    }
  }
  if (tid < 128) { s_fc1b[tid] = fc1b[tid]; s_fc2W[tid] = fc2W[tid]; }
  else if (tid < 160) s_rpW[tid - 128] = rpW[tid - 128];
  // stage xu / xpe: thread handles (l = tid>>3, d0 = (tid&7)*8)
  {
    const int l = tid >> 3, d0 = (tid & 7) * 8;
    const bf16* src = kvbuf + ((size_t)(b * kT + t0 + l) * (2 * kC)) + (size_t)s * kC + h * kHS + d0;
    short8 u = *reinterpret_cast<const short8*>(src);
    const float* wp = wpe + l * kHS + d0;
#pragma unroll
    for (int e = 0; e < 8; ++e) {
      const int d = d0 + e;
      XU[d * 40 + l] = u[e];
      const float xv = bu2f((unsigned short)u[e]) + wp[e];
      XPE[d * 40 + l] = fbits(xv);
    }
  }
  __syncthreads();

  // MFMA: A row = w*16+fr (d), k = q*8; B row = nt*16+fr (j), k = q*8
  const short8 af = *reinterpret_cast<const short8*>(&XPE[(w * 16 + fr) * 40 + q * 8]);
  f32x4 acc[8];
#pragma unroll
  for (int nt = 0; nt < 8; ++nt) {
    const short8 bf_ = *reinterpret_cast<const short8*>(&FC1[(nt * 16 + fr) * 40 + q * 8]);
    acc[nt] = __builtin_amdgcn_mfma_f32_16x16x32_bf16(af, bf_, (f32x4){0.f, 0.f, 0.f, 0.f}, 0, 0, 0);
  }

  // epilogue: lane holds H[d = w*16 + q*4 + r][j = nt*16 + fr], r=0..3
  float sum[4] = {0.f, 0.f, 0.f, 0.f};
#pragma unroll
  for (int nt = 0; nt < 8; ++nt) {
    const int j = nt * 16 + fr;
    const float bb = s_fc1b[j];
    const float w2 = s_fc2W[j];
#pragma unroll
    for (int r = 0; r < 4; ++r)
      sum[r] += gelu_f(acc[nt][r] + bb) * w2;
  }
  // residual: lane fr covers l in {fr*2, fr*2+1} for its 4 rows
#pragma unroll
  for (int r = 0; r < 4; ++r) {
    const int d = w * 16 + q * 4 + r;
#pragma unroll
    for (int e = 0; e < 2; ++e) {
      const int l = fr * 2 + e;
      sum[r] += bu2f((unsigned short)XU[d * 40 + l]) * s_rpW[l];
    }
  }
#pragma unroll
  for (int off = 1; off <= 8; off <<= 1)
#pragma unroll
    for (int r = 0; r < 4; ++r) sum[r] += __shfl_xor(sum[r], off);

  if (fr == 0) {
    const float c0 = fc2b[0] + rpb[0];
    bf16* op = outp + ((size_t)(b * kNH + h) * kNB + blk) * kHS;
#pragma unroll
    for (int r = 0; r < 4; ++r) {
      float v = sum[r] + c0;
      v = fminf(3.0f, fmaxf(-3.0f, v));
      op[w * 16 + q * 4 + r] = f2b(v);
    }
  }
}

// ---------------- Local sliding-window attention: MFMA flash (batch in grid.z) ----------------
__global__ __launch_bounds__(256) void local_attn_mfma(
    const bf16* __restrict__ qkv, bf16* __restrict__ ybuf0)
{
  __shared__ __align__(16) short Qs[64 * 64];
  __shared__ __align__(16) short Ks[64 * 64];
  __shared__ __align__(16) short VTs[64 * 64];
  __shared__ __align__(16) short Ps[64 * 64];
  const int tid = threadIdx.x;
  const int lane = tid & 63;
  const int w = tid >> 6;
  const int fr = lane & 15;
  const int g  = lane >> 4;
  const int h  = blockIdx.y;
  const int b  = blockIdx.z;
  const int t0 = blockIdx.x * 64;
  bf16* ybuf = ybuf0 + (size_t)b * kT * kC;
  const size_t rs = 3 * kC;
  const bf16* qbase = qkv + ((size_t)b * kT) * rs + h * kHS;
  const bf16* kbase = qbase + kC;
  const bf16* vbase = qbase + 2 * kC;

  for (int c = tid; c < 512; c += 256) {
    const int r = c >> 3, p = c & 7;
    short8 v = *reinterpret_cast<const short8*>(qbase + (size_t)(t0 + r) * rs + p * 8);
    *reinterpret_cast<short8*>(&Qs[r * 64 + ((p ^ (r & 7)) << 3)]) = v;
  }
  __syncthreads();
  short8 qf[2];
  {
    const int r = w * 16 + fr;
#pragma unroll
    for (int dc = 0; dc < 2; ++dc) {
      const int d0 = dc * 32 + g * 8;
      qf[dc] = *reinterpret_cast<const short8*>(&Qs[r * 64 + (d0 ^ ((r & 7) << 3))]);
    }
  }

  f32x4 acc[4];
  float m[4], l[4];
#pragma unroll
  for (int r = 0; r < 4; ++r) { m[r] = -1e30f; l[r] = 0.f; }
#pragma unroll
  for (int dt = 0; dt < 4; ++dt) acc[dt] = (f32x4){0.f, 0.f, 0.f, 0.f};

  const int jb0 = (t0 >= 256) ? (t0 - 256) : 0;
  for (int jb = jb0; jb <= t0; jb += 64) {
    const bool masked = (jb == t0 - 256) || (jb == t0);
    __syncthreads();
    for (int c = tid; c < 512; c += 256) {
      const int r = c >> 3, p = c & 7;
      short8 v = *reinterpret_cast<const short8*>(kbase + (size_t)(jb + r) * rs + p * 8);
      *reinterpret_cast<short8*>(&Ks[r * 64 + ((p ^ (r & 7)) << 3)]) = v;
    }
    for (int c = tid; c < 512; c += 256) {
      const int r = c >> 3, p = c & 7;
      short8 v = *reinterpret_cast<const short8*>(vbase + (size_t)(jb + r) * rs + p * 8);
#pragma unroll
      for (int e = 0; e < 8; ++e) {
        const int d = p * 8 + e;
        VTs[d * 64 + (r ^ ((d & 7) << 3))] = v[e];
      }
    }
    __syncthreads();

    f32x4 S[4];
#pragma unroll
    for (int ks = 0; ks < 4; ++ks) S[ks] = (f32x4){0.f, 0.f, 0.f, 0.f};
#pragma unroll
    for (int ks = 0; ks < 4; ++ks) {
      const int kr = ks * 16 + fr;
#pragma unroll
      for (int dc = 0; dc < 2; ++dc) {
        const int d0 = dc * 32 + g * 8;
        short8 kf = *reinterpret_cast<const short8*>(&Ks[kr * 64 + (d0 ^ ((kr & 7) << 3))]);
        S[ks] = __builtin_amdgcn_mfma_f32_16x16x32_bf16(qf[dc], kf, S[ks], 0, 0, 0);
      }
    }

    const int qrow0 = t0 + w * 16 + g * 4;
    float rowmax[4];
#pragma unroll
    for (int r = 0; r < 4; ++r) rowmax[r] = -1e30f;
#pragma unroll
    for (int ks = 0; ks < 4; ++ks) {
      const int j = jb + ks * 16 + fr;
#pragma unroll
      for (int r = 0; r < 4; ++r) {
        float s = S[ks][r] * 0.125f;
        if (masked) {
          const int i = qrow0 + r;
          if (!((j <= i) && (j > i - 256))) s = -1e30f;
        }
        S[ks][r] = s;
        rowmax[r] = fmaxf(rowmax[r], s);
      }
    }
#pragma unroll
    for (int off = 1; off <= 8; off <<= 1)
#pragma unroll
      for (int r = 0; r < 4; ++r)
        rowmax[r] = fmaxf(rowmax[r], __shfl_xor(rowmax[r], off));

    float resc[4], psum[4];
#pragma unroll
    for (int r = 0; r < 4; ++r) {
      const float mn = fmaxf(m[r], rowmax[r]);
      resc[r] = __expf(m[r] - mn);
      m[r] = mn;
      psum[r] = 0.f;
    }
#pragma unroll
    for (int ks = 0; ks < 4; ++ks) {
      const int j = jb + ks * 16 + fr;
#pragma unroll
      for (int r = 0; r < 4; ++r) {
        float p = __expf(S[ks][r] - m[r]);
        if (masked) {
          const int i = qrow0 + r;
          if (!((j <= i) && (j > i - 256))) p = 0.f;
        }
        S[ks][r] = p;
        psum[r] += p;
      }
    }
#pragma unroll
    for (int off = 1; off <= 8; off <<= 1)
#pragma unroll
      for (int r = 0; r < 4; ++r) psum[r] += __shfl_xor(psum[r], off);
#pragma unroll
    for (int r = 0; r < 4; ++r) l[r] = l[r] * resc[r] + psum[r];
#pragma unroll
    for (int dt = 0; dt < 4; ++dt)
#pragma unroll
      for (int r = 0; r < 4; ++r) acc[dt][r] *= resc[r];

#pragma unroll
    for (int ks = 0; ks < 4; ++ks)
#pragma unroll
      for (int r = 0; r < 4; ++r) {
        const int prow = w * 16 + g * 4 + r;
        const int pcol = ks * 16 + fr;
        Ps[prow * 64 + (pcol ^ ((prow & 7) << 3))] = fbits(S[ks][r]);
      }

#pragma unroll
    for (int kc = 0; kc < 2; ++kc) {
      const int prow = w * 16 + fr;
      const int k0 = kc * 32 + g * 8;
      short8 pf = *reinterpret_cast<const short8*>(&Ps[prow * 64 + (k0 ^ ((prow & 7) << 3))]);
#pragma unroll
      for (int dt = 0; dt < 4; ++dt) {
        const int dr = dt * 16 + fr;
        short8 vf = *reinterpret_cast<const short8*>(&VTs[dr * 64 + (k0 ^ ((dr & 7) << 3))]);
        acc[dt] = __builtin_amdgcn_mfma_f32_16x16x32_bf16(pf, vf, acc[dt], 0, 0, 0);
      }
    }
  }

#pragma unroll
  for (int dt = 0; dt < 4; ++dt)
#pragma unroll
    for (int r = 0; r < 4; ++r) {
      const int i = t0 + w * 16 + g * 4 + r;
      const int d = dt * 16 + fr;
      ybuf[(size_t)i * kC + h * kHS + d] = f2b(acc[dt][r] / l[r]);
    }
}

// ---------------- Compressed attention: MFMA flash + fused gate mix (batch in grid.z) ----------------
__global__ __launch_bounds__(256) void comp_attn_mfma(
    const bf16* __restrict__ qkv, const bf16* __restrict__ kcomp,
    const bf16* __restrict__ vcomp, const bf16* __restrict__ gate,
    bf16* __restrict__ ybuf0)
{
  __shared__ __align__(16) short Qs[64 * 64];
  __shared__ __align__(16) short Ks[64 * 64];
  __shared__ __align__(16) short VTs[64 * 64];
  __shared__ __align__(16) short Ps[64 * 64];
  const int tid = threadIdx.x;
  const int lane = tid & 63;
  const int w = tid >> 6;
  const int fr = lane & 15;
  const int g  = lane >> 4;
  const int h  = blockIdx.y;
  const int b  = blockIdx.z;
  const int t0 = blockIdx.x * 64;
  bf16* ybuf = ybuf0 + (size_t)b * kT * kC;
  const size_t rs = 3 * kC;
  const bf16* qbase = qkv + ((size_t)b * kT) * rs + h * kHS;
  const bf16* kb = kcomp + ((size_t)(b * kNH + h)) * kNB * kHS;
  const bf16* vb = vcomp + ((size_t)(b * kNH + h)) * kNB * kHS;

  for (int c = tid; c < 512; c += 256) {
    const int r = c >> 3, p = c & 7;
    short8 v = *reinterpret_cast<const short8*>(qbase + (size_t)(t0 + r) * rs + p * 8);
    *reinterpret_cast<short8*>(&Qs[r * 64 + ((p ^ (r & 7)) << 3)]) = v;
  }
  __syncthreads();
  short8 qf[2];
  {
    const int r = w * 16 + fr;
#pragma unroll
    for (int dc = 0; dc < 2; ++dc) {
      const int d0 = dc * 32 + g * 8;
      qf[dc] = *reinterpret_cast<const short8*>(&Qs[r * 64 + (d0 ^ ((r & 7) << 3))]);
    }
  }

  f32x4 acc[4];
  float m[4], l[4];
#pragma unroll
  for (int r = 0; r < 4; ++r) { m[r] = -1e30f; l[r] = 0.f; }
#pragma unroll
  for (int dt = 0; dt < 4; ++dt) acc[dt] = (f32x4){0.f, 0.f, 0.f, 0.f};

  const int ntiles = (t0 >= 1024) ? 2 : 1;
  for (int tb = 0; tb < ntiles; ++tb) {
    const int jb = tb * 64;
    const bool masked = !(((jb + 63) < kNB) && ((jb + 63) * kST < t0));
    __syncthreads();
    for (int c = tid; c < 512; c += 256) {
      const int r = c >> 3, p = c & 7;
      const int rr = (jb + r < kNB) ? (jb + r) : (kNB - 1);
      short8 v = *reinterpret_cast<const short8*>(kb + (size_t)rr * kHS + p * 8);
      *reinterpret_cast<short8*>(&Ks[r * 64 + ((p ^ (r & 7)) << 3)]) = v;
    }
    for (int c = tid; c < 512; c += 256) {
      const int r = c >> 3, p = c & 7;
      const int rr = (jb + r < kNB) ? (jb + r) : (kNB - 1);
      short8 v = *reinterpret_cast<const short8*>(vb + (size_t)rr * kHS + p * 8);
#pragma unroll
      for (int e = 0; e < 8; ++e) {
        const int d = p * 8 + e;
        VTs[d * 64 + (r ^ ((d & 7) << 3))] = v[e];
      }
    }
    __syncthreads();

    f32x4 S[4];
#pragma unroll
    for (int ks = 0; ks < 4; ++ks) S[ks] = (f32x4){0.f, 0.f, 0.f, 0.f};
#pragma unroll
    for (int ks = 0; ks < 4; ++ks) {
      const int kr = ks * 16 + fr;
#pragma unroll
      for (int dc = 0; dc < 2; ++dc) {
        const int d0 = dc * 32 + g * 8;
        short8 kf = *reinterpret_cast<const short8*>(&Ks[kr * 64 + (d0 ^ ((kr & 7) << 3))]);
        S[ks] = __builtin_amdgcn_mfma_f32_16x16x32_bf16(qf[dc], kf, S[ks], 0, 0, 0);
      }
    }

    const int qrow0 = t0 + w * 16 + g * 4;
    float rowmax[4];
#pragma unroll
    for (int r = 0; r < 4; ++r) rowmax[r] = -1e30f;
#pragma unroll
    for (int ks = 0; ks < 4; ++ks) {
      const int n = jb + ks * 16 + fr;
#pragma unroll
      for (int r = 0; r < 4; ++r) {
        float s = S[ks][r] * 0.125f;
        if (masked) {
          const int i = qrow0 + r;
          if (!((n < kNB) && (n * kST < i))) s = -1e30f;
        }
        S[ks][r] = s;
        rowmax[r] = fmaxf(rowmax[r], s);
      }
    }
#pragma unroll
    for (int off = 1; off <= 8; off <<= 1)
#pragma unroll
      for (int r = 0; r < 4; ++r)
        rowmax[r] = fmaxf(rowmax[r], __shfl_xor(rowmax[r], off));

    float resc[4], psum[4];
#pragma unroll
    for (int r = 0; r < 4; ++r) {
      const float mn = fmaxf(m[r], rowmax[r]);
      resc[r] = __expf(m[r] - mn);
      m[r] = mn;
      psum[r] = 0.f;
    }
#pragma unroll
    for (int ks = 0; ks < 4; ++ks) {
      const int n = jb + ks * 16 + fr;
#pragma unroll
      for (int r = 0; r < 4; ++r) {
        float p = __expf(S[ks][r] - m[r]);
        if (masked) {
          const int i = qrow0 + r;
          if (!((n < kNB) && (n * kST < i))) p = 0.f;
        }
        S[ks][r] = p;
        psum[r] += p;
      }
    }
#pragma unroll
    for (int off = 1; off <= 8; off <<= 1)
#pragma unroll
      for (int r = 0; r < 4; ++r) psum[r] += __shfl_xor(psum[r], off);
#pragma unroll
    for (int r = 0; r < 4; ++r) l[r] = l[r] * resc[r] + psum[r];
#pragma unroll
    for (int dt = 0; dt < 4; ++dt)
#pragma unroll
      for (int r = 0; r < 4; ++r) acc[dt][r] *= resc[r];

#pragma unroll
    for (int ks = 0; ks < 4; ++ks)
#pragma unroll
      for (int r = 0; r < 4; ++r) {
        const int prow = w * 16 + g * 4 + r;
        const int pcol = ks * 16 + fr;
        Ps[prow * 64 + (pcol ^ ((prow & 7) << 3))] = fbits(S[ks][r]);
      }

#pragma unroll
    for (int kc = 0; kc < 2; ++kc) {
      const int prow = w * 16 + fr;
      const int k0 = kc * 32 + g * 8;
      short8 pf = *reinterpret_cast<const short8*>(&Ps[prow * 64 + (k0 ^ ((prow & 7) << 3))]);
#pragma unroll
      for (int dt = 0; dt < 4; ++dt) {
        const int dr = dt * 16 + fr;
        short8 vf = *reinterpret_cast<const short8*>(&VTs[dr * 64 + (k0 ^ ((dr & 7) << 3))]);
        acc[dt] = __builtin_amdgcn_mfma_f32_16x16x32_bf16(pf, vf, acc[dt], 0, 0, 0);
      }
    }
  }

#pragma unroll
  for (int r = 0; r < 4; ++r) {
    const int i = t0 + w * 16 + g * 4 + r;
    const float inv = (l[r] > 0.f) ? (1.f / l[r]) : 0.f;
#pragma unroll
    for (int dt = 0; dt < 4; ++dt) {
      const int d = dt * 16 + fr;
      const size_t idx = (size_t)i * kC + h * kHS + d;
      const float yc = acc[dt][r] * inv;
      const float gg = b2f(gate[((size_t)(b * kT + i)) * kC + h * kHS + d]);
      const float yl = b2f(ybuf[idx]);
      ybuf[idx] = f2b(gg * yl + (1.f - gg) * yc);
    }
  }
}

extern "C" void kernel_launch(void* const* d_in, const int* in_sizes, int n_in,
                              void* d_out, int out_size, void* d_ws, size_t ws_size,
                              hipStream_t stream)
{
  (void)in_sizes; (void)n_in; (void)out_size; (void)ws_size; (void)kM; (void)kWIN;
  const float* x      = (const float*)d_in[0];
  const float* Wqkv   = (const float*)d_in[1];
  const float* bqkv   = (const float*)d_in[2];
  const float* Wcomp  = (const float*)d_in[3];
  const float* bcomp  = (const float*)d_in[4];
  const float* Wproj  = (const float*)d_in[5];
  const float* bproj  = (const float*)d_in[6];
  const float* k_fc1W = (const float*)d_in[7];
  const float* k_fc1b = (const float*)d_in[8];
  const float* k_fc2W = (const float*)d_in[9];
  const float* k_fc2b = (const float*)d_in[10];
  const float* k_rpW  = (const float*)d_in[11];
  const float* k_rpb  = (const float*)d_in[12];
  const float* k_wpe  = (const float*)d_in[13];
  const float* v_fc1W = (const float*)d_in[14];
  const float* v_fc1b = (const float*)d_in[15];
  const float* v_fc2W = (const float*)d_in[16];
  const float* v_fc2b = (const float*)d_in[17];
  const float* v_rpW  = (const float*)d_in[18];
  const float* v_rpb  = (const float*)d_in[19];
  const float* v_wpe  = (const float*)d_in[20];
  const float* Wg1    = (const float*)d_in[21];
  const float* bg1    = (const float*)d_in[22];
  const float* Wg2    = (const float*)d_in[23];
  const float* bg2    = (const float*)d_in[24];

  // ---- Workspace (peak 51,372,032 B, identical to proven footprint) ----
  char* wsb = (char*)d_ws;
  bf16* xbf   = (bf16*)(wsb + 0);
  bf16* wscr  = (bf16*)(wsb + 8388608);
  bf16* big   = (bf16*)(wsb + 16777216);
  bf16* ybuf  = (bf16*)(wsb + 41943040);
  bf16* kcomp = (bf16*)(wsb + 50331648);
  bf16* vcomp = (bf16*)(wsb + 50851840);
  bf16* gate  = (bf16*)((char*)d_out + 8388608);
  float* out  = (float*)d_out;

  const int cg = 2048;
  f32_to_bf16<<<cg, 256, 0, stream>>>(x, xbf, 1048576);
  f32_to_bf16<<<cg, 256, 0, stream>>>(Wg1, wscr, 1048576);
  gemm_bf16<1, bf16><<<1024, 512, 0, stream>>>(xbf, wscr, bg1, big, 4096, 4096, 1024, 32);
  f32_to_bf16<<<cg, 256, 0, stream>>>(Wg2, wscr, 1048576);
  gemm_bf16_n64<3, bf16><<<512, 256, 0, stream>>>(big, wscr, bg2, gate, 4096, 1024, 4096, 16);
  f32_to_bf16<<<cg, 256, 0, stream>>>(Wcomp, wscr, 524288);
  gemm_bf16<0, bf16><<<512, 512, 0, stream>>>(xbf, wscr, bcomp, big, 4096, 2048, 1024, 16);
  comp_mlp_mfma<<<dim3(kNB, kNH, kB), 256, 0, stream>>>(big, 0, k_fc1W, k_fc1b, k_fc2W, k_fc2b, k_rpW, k_rpb, k_wpe, kcomp);
  comp_mlp_mfma<<<dim3(kNB, kNH, kB), 256, 0, stream>>>(big, 1, v_fc1W, v_fc1b, v_fc2W, v_fc2b, v_rpW, v_rpb, v_wpe, vcomp);
  f32_to_bf16<<<cg, 256, 0, stream>>>(Wqkv, wscr, 786432);
  gemm_bf16<0, bf16><<<768, 512, 0, stream>>>(xbf, wscr, bqkv, big, 4096, 3072, 1024, 24);
  f32_to_bf16<<<cg, 256, 0, stream>>>(Wproj, wscr, 262144);
  // attention for both batches (batch = blockIdx.z); gate consumed here
  local_attn_mfma<<<dim3(kT / 64, kNH, kB), 256, 0, stream>>>(big, ybuf);
  comp_attn_mfma<<<dim3(kT / 64, kNH, kB), 256, 0, stream>>>(big, kcomp, vcomp, gate, ybuf);
  // single merged projection over both batches (overwrites gate region after use)
  gemm_bf16_n64<0, float><<<512, 256, 0, stream>>>(ybuf, wscr, bproj, out, 4096, 1024, 1024, 16);
}

// Round 14
// 365.442 us; speedup vs baseline: 10.0292x; 1.0233x over previous
//
#include <hip/hip_runtime.h>
#include <hip/hip_bf16.h>

typedef __hip_bfloat16 bf16;

constexpr int kB = 2, kT = 2048, kC = 1024, kNH = 16, kHS = 64;
constexpr int kL = 32, kST = 16, kWIN = 256;
constexpr int kNB = (kT - kL) / kST + 1;   // 127
constexpr int kM = kB * kT;                // 4096

typedef __attribute__((ext_vector_type(8))) short short8;   // bf16 MFMA A/B frag (4 VGPRs)
typedef __attribute__((ext_vector_type(4))) short short4v;
typedef __attribute__((ext_vector_type(4))) float f32x4;

__device__ __forceinline__ float b2f(bf16 v) { return __bfloat162float(v); }
__device__ __forceinline__ bf16  f2b(float v) { return __float2bfloat16(v); }
__device__ __forceinline__ float bu2f(unsigned int u) { return __uint_as_float(u << 16); }
__device__ __forceinline__ float gelu_f(float v) { return 0.5f * v * (1.0f + erff(v * 0.70710678118654752f)); }
__device__ __forceinline__ short fbits(float v) {
  return (short)__builtin_bit_cast(unsigned short, f2b(v));
}
// async global->LDS, 16 bytes per lane (dest = wave-uniform base + lane*16)
__device__ __forceinline__ void gl16(const bf16* g, bf16* l) {
  __builtin_amdgcn_global_load_lds(
      (const __attribute__((address_space(1))) void*)g,
      (__attribute__((address_space(3))) void*)l, 16, 0, 0);
}

// ---------------- fp32 -> bf16 conversion (vectorized, grid-stride) ----------------
__global__ __launch_bounds__(256) void f32_to_bf16(const float* __restrict__ src,
                                                   bf16* __restrict__ dst, int n4) {
  int i = blockIdx.x * 256 + threadIdx.x;
  const int stride = gridDim.x * 256;
  for (; i < n4; i += stride) {
    float4 v = ((const float4*)src)[i];
    short4v w; w.x = fbits(v.x); w.y = fbits(v.y); w.z = fbits(v.z); w.w = fbits(v.w);
    ((short4v*)dst)[i] = w;
  }
}

// ---------------- all-bf16 MFMA GEMM: 128x128 tile, BK=64, 8 waves (2x4) ----------------
template<int EPI, typename TY>
__global__ __launch_bounds__(512) void gemm_bf16(
    const bf16* __restrict__ X, const bf16* __restrict__ W,
    const float* __restrict__ bias, TY* __restrict__ Y,
    int M, int N, int K, int nbx)
{
  __shared__ __align__(16) bf16 As[128 * 64];
  __shared__ __align__(16) bf16 Bs[128 * 64];
  const int nwg = gridDim.x;
  const int bid = blockIdx.x;
  const int swz = (bid & 7) * (nwg >> 3) + (bid >> 3);
  const int bm = (swz / nbx) * 128;
  const int bn = (swz % nbx) * 128;
  const int tid = threadIdx.x;
  const int lane = tid & 63;
  const int w = tid >> 6;
  const int wr = w >> 2, wc = w & 3;      // 2x4 wave grid; wave tile 64 x 32
  const int fr = lane & 15, q = lane >> 4;
  const int srow = lane >> 3;
  const int scol = (lane & 7) * 8;

  f32x4 acc[4][2];
#pragma unroll
  for (int i = 0; i < 4; ++i)
#pragma unroll
    for (int j = 0; j < 2; ++j) acc[i][j] = (f32x4){0.f, 0.f, 0.f, 0.f};

  const bf16* Xb = X + (size_t)bm * K;
  const bf16* Wb = W + (size_t)bn * K;

  for (int k0 = 0; k0 < K; k0 += 64) {
    __syncthreads();
#pragma unroll
    for (int i = 0; i < 2; ++i) {
      const int r = w * 16 + i * 8 + srow;
      gl16(Xb + (size_t)r * K + k0 + scol, &As[r * 64 + scol]);
      gl16(Wb + (size_t)r * K + k0 + scol, &Bs[r * 64 + scol]);
    }
    __syncthreads();
#pragma unroll
    for (int kk = 0; kk < 2; ++kk) {
      short8 af[4], bfr[2];
#pragma unroll
      for (int i = 0; i < 4; ++i)
        af[i] = *reinterpret_cast<const short8*>(&As[(wr * 64 + i * 16 + fr) * 64 + kk * 32 + q * 8]);
#pragma unroll
      for (int j = 0; j < 2; ++j)
        bfr[j] = *reinterpret_cast<const short8*>(&Bs[(wc * 32 + j * 16 + fr) * 64 + kk * 32 + q * 8]);
#pragma unroll
      for (int i = 0; i < 4; ++i)
#pragma unroll
        for (int j = 0; j < 2; ++j)
          acc[i][j] = __builtin_amdgcn_mfma_f32_16x16x32_bf16(af[i], bfr[j], acc[i][j], 0, 0, 0);
    }
  }

#pragma unroll
  for (int j = 0; j < 2; ++j) {
    const int gcol = bn + wc * 32 + j * 16 + fr;
    const float bv = bias[gcol];
#pragma unroll
    for (int i = 0; i < 4; ++i) {
      const int grow0 = bm + wr * 64 + i * 16 + q * 4;
#pragma unroll
      for (int r = 0; r < 4; ++r) {
        float v = acc[i][j][r] + bv;
        if (EPI == 1) v = gelu_f(v);
        if (EPI == 3) v = 1.f / (1.f + expf(-v));
        if constexpr (sizeof(TY) == 2) Y[(size_t)(grow0 + r) * N + gcol] = f2b(v);
        else                           ((float*)Y)[(size_t)(grow0 + r) * N + gcol] = v;
      }
    }
  }
}

// ---------------- small-tile GEMM: 64x64 tile, BK=64, 4 waves (2x2), wave tile 32x32 ----------------
// For deep-K narrow-N shapes (gate, proj): 4+ blocks/CU so staging drains interleave
// across independent blocks and hide HBM latency.
template<int EPI, typename TY>
__global__ __launch_bounds__(256) void gemm_bf16_t64(
    const bf16* __restrict__ X, const bf16* __restrict__ W,
    const float* __restrict__ bias, TY* __restrict__ Y,
    int M, int N, int K, int nbx)
{
  __shared__ __align__(16) bf16 As[64 * 64];
  __shared__ __align__(16) bf16 Bs[64 * 64];
  const int nwg = gridDim.x;
  const int bid = blockIdx.x;
  const int swz = (bid & 7) * (nwg >> 3) + (bid >> 3);
  const int bm = (swz / nbx) * 64;
  const int bn = (swz % nbx) * 64;
  const int tid = threadIdx.x;
  const int lane = tid & 63;
  const int w = tid >> 6;                 // 0..3
  const int wr = w >> 1, wc = w & 1;      // 2x2 wave grid; wave tile 32 x 32
  const int fr = lane & 15, q = lane >> 4;
  const int srow = lane >> 3;
  const int scol = (lane & 7) * 8;

  f32x4 acc[2][2];
#pragma unroll
  for (int i = 0; i < 2; ++i)
#pragma unroll
    for (int j = 0; j < 2; ++j) acc[i][j] = (f32x4){0.f, 0.f, 0.f, 0.f};

  const bf16* Xb = X + (size_t)bm * K;
  const bf16* Wb = W + (size_t)bn * K;

  for (int k0 = 0; k0 < K; k0 += 64) {
    __syncthreads();
#pragma unroll
    for (int i = 0; i < 2; ++i) {        // wave w stages rows [w*16, w*16+16) of A and B
      const int r = w * 16 + i * 8 + srow;
      gl16(Xb + (size_t)r * K + k0 + scol, &As[r * 64 + scol]);
      gl16(Wb + (size_t)r * K + k0 + scol, &Bs[r * 64 + scol]);
    }
    __syncthreads();
#pragma unroll
    for (int kk = 0; kk < 2; ++kk) {
      short8 af[2], bfr[2];
#pragma unroll
      for (int i = 0; i < 2; ++i)
        af[i] = *reinterpret_cast<const short8*>(&As[(wr * 32 + i * 16 + fr) * 64 + kk * 32 + q * 8]);
#pragma unroll
      for (int j = 0; j < 2; ++j)
        bfr[j] = *reinterpret_cast<const short8*>(&Bs[(wc * 32 + j * 16 + fr) * 64 + kk * 32 + q * 8]);
#pragma unroll
      for (int i = 0; i < 2; ++i)
#pragma unroll
        for (int j = 0; j < 2; ++j)
          acc[i][j] = __builtin_amdgcn_mfma_f32_16x16x32_bf16(af[i], bfr[j], acc[i][j], 0, 0, 0);
    }
  }

#pragma unroll
  for (int j = 0; j < 2; ++j) {
    const int gcol = bn + wc * 32 + j * 16 + fr;
    const float bv = bias[gcol];
#pragma unroll
    for (int i = 0; i < 2; ++i) {
      const int grow0 = bm + wr * 32 + i * 16 + q * 4;
#pragma unroll
      for (int r = 0; r < 4; ++r) {
        float v = acc[i][j][r] + bv;
        if (EPI == 1) v = gelu_f(v);
        if (EPI == 3) v = 1.f / (1.f + expf(-v));
        if constexpr (sizeof(TY) == 2) Y[(size_t)(grow0 + r) * N + gcol] = f2b(v);
        else                           ((float*)Y)[(size_t)(grow0 + r) * N + gcol] = v;
      }
    }
  }
}

// ---------------- Compression MLP via MFMA (unchanged) ----------------
__global__ __launch_bounds__(256) void comp_mlp_mfma(
    const bf16* __restrict__ kvbuf, int s,
    const float* __restrict__ fc1W, const float* __restrict__ fc1b,
    const float* __restrict__ fc2W, const float* __restrict__ fc2b,
    const float* __restrict__ rpW,  const float* __restrict__ rpb,
    const float* __restrict__ wpe,  bf16* __restrict__ outp)
{
  __shared__ __align__(16) short XPE[64 * 40];
  __shared__ __align__(16) short XU [64 * 40];
  __shared__ __align__(16) short FC1[128 * 40];
  __shared__ float s_fc1b[128];
  __shared__ float s_fc2W[128];
  __shared__ float s_rpW[32];
  const int tid = threadIdx.x;
  const int lane = tid & 63;
  const int w = tid >> 6;
  const int fr = lane & 15, q = lane >> 4;
  const int blk = blockIdx.x;
  const int h = blockIdx.y;
  const int b = blockIdx.z;
  const int t0 = blk * kST;

  {
    const int base = tid * 16;
#pragma unroll
    for (int c = 0; c < 4; ++c) {
      float4 v = *reinterpret_cast<const float4*>(fc1W + base + c * 4);
      const int idx = base + c * 4;
      short* dst = &FC1[(idx >> 5) * 40 + (idx & 31)];
      dst[0] = fbits(v.x); dst[1] = fbits(v.y); dst[2] = fbits(v.z); dst[3] = fbits(v.w);
    }
  }
  if (tid < 128) { s_fc1b[tid] = fc1b[tid]; s_fc2W[tid] = fc2W[tid]; }
  else if (tid < 160) s_rpW[tid - 128] = rpW[tid - 128];
  {
    const int l = tid >> 3, d0 = (tid & 7) * 8;
    const bf16* src = kvbuf + ((size_t)(b * kT + t0 + l) * (2 * kC)) + (size_t)s * kC + h * kHS + d0;
    short8 u = *reinterpret_cast<const short8*>(src);
    const float* wp = wpe + l * kHS + d0;
#pragma unroll
    for (int e = 0; e < 8; ++e) {
      const int d = d0 + e;
      XU[d * 40 + l] = u[e];
      const float xv = bu2f((unsigned short)u[e]) + wp[e];
      XPE[d * 40 + l] = fbits(xv);
    }
  }
  __syncthreads();

  const short8 af = *reinterpret_cast<const short8*>(&XPE[(w * 16 + fr) * 40 + q * 8]);
  f32x4 acc[8];
#pragma unroll
  for (int nt = 0; nt < 8; ++nt) {
    const short8 bf_ = *reinterpret_cast<const short8*>(&FC1[(nt * 16 + fr) * 40 + q * 8]);
    acc[nt] = __builtin_amdgcn_mfma_f32_16x16x32_bf16(af, bf_, (f32x4){0.f, 0.f, 0.f, 0.f}, 0, 0, 0);
  }

  float sum[4] = {0.f, 0.f, 0.f, 0.f};
#pragma unroll
  for (int nt = 0; nt < 8; ++nt) {
    const int j = nt * 16 + fr;
    const float bb = s_fc1b[j];
    const float w2 = s_fc2W[j];
#pragma unroll
    for (int r = 0; r < 4; ++r)
      sum[r] += gelu_f(acc[nt][r] + bb) * w2;
  }
#pragma unroll
  for (int r = 0; r < 4; ++r) {
    const int d = w * 16 + q * 4 + r;
#pragma unroll
    for (int e = 0; e < 2; ++e) {
      const int l = fr * 2 + e;
      sum[r] += bu2f((unsigned short)XU[d * 40 + l]) * s_rpW[l];
    }
  }
#pragma unroll
  for (int off = 1; off <= 8; off <<= 1)
#pragma unroll
    for (int r = 0; r < 4; ++r) sum[r] += __shfl_xor(sum[r], off);

  if (fr == 0) {
    const float c0 = fc2b[0] + rpb[0];
    bf16* op = outp + ((size_t)(b * kNH + h) * kNB + blk) * kHS;
#pragma unroll
    for (int r = 0; r < 4; ++r) {
      float v = sum[r] + c0;
      v = fminf(3.0f, fmaxf(-3.0f, v));
      op[w * 16 + q * 4 + r] = f2b(v);
    }
  }
}

// ---------------- Local sliding-window attention: MFMA flash (batch in grid.z) ----------------
__global__ __launch_bounds__(256) void local_attn_mfma(
    const bf16* __restrict__ qkv, bf16* __restrict__ ybuf0)
{
  __shared__ __align__(16) short Qs[64 * 64];
  __shared__ __align__(16) short Ks[64 * 64];
  __shared__ __align__(16) short VTs[64 * 64];
  __shared__ __align__(16) short Ps[64 * 64];
  const int tid = threadIdx.x;
  const int lane = tid & 63;
  const int w = tid >> 6;
  const int fr = lane & 15;
  const int g  = lane >> 4;
  const int h  = blockIdx.y;
  const int b  = blockIdx.z;
  const int t0 = blockIdx.x * 64;
  bf16* ybuf = ybuf0 + (size_t)b * kT * kC;
  const size_t rs = 3 * kC;
  const bf16* qbase = qkv + ((size_t)b * kT) * rs + h * kHS;
  const bf16* kbase = qbase + kC;
  const bf16* vbase = qbase + 2 * kC;

  for (int c = tid; c < 512; c += 256) {
    const int r = c >> 3, p = c & 7;
    short8 v = *reinterpret_cast<const short8*>(qbase + (size_t)(t0 + r) * rs + p * 8);
    *reinterpret_cast<short8*>(&Qs[r * 64 + ((p ^ (r & 7)) << 3)]) = v;
  }
  __syncthreads();
  short8 qf[2];
  {
    const int r = w * 16 + fr;
#pragma unroll
    for (int dc = 0; dc < 2; ++dc) {
      const int d0 = dc * 32 + g * 8;
      qf[dc] = *reinterpret_cast<const short8*>(&Qs[r * 64 + (d0 ^ ((r & 7) << 3))]);
    }
  }

  f32x4 acc[4];
  float m[4], l[4];
#pragma unroll
  for (int r = 0; r < 4; ++r) { m[r] = -1e30f; l[r] = 0.f; }
#pragma unroll
  for (int dt = 0; dt < 4; ++dt) acc[dt] = (f32x4){0.f, 0.f, 0.f, 0.f};

  const int jb0 = (t0 >= 256) ? (t0 - 256) : 0;
  for (int jb = jb0; jb <= t0; jb += 64) {
    const bool masked = (jb == t0 - 256) || (jb == t0);
    __syncthreads();
    for (int c = tid; c < 512; c += 256) {
      const int r = c >> 3, p = c & 7;
      short8 v = *reinterpret_cast<const short8*>(kbase + (size_t)(jb + r) * rs + p * 8);
      *reinterpret_cast<short8*>(&Ks[r * 64 + ((p ^ (r & 7)) << 3)]) = v;
    }
    for (int c = tid; c < 512; c += 256) {
      const int r = c >> 3, p = c & 7;
      short8 v = *reinterpret_cast<const short8*>(vbase + (size_t)(jb + r) * rs + p * 8);
#pragma unroll
      for (int e = 0; e < 8; ++e) {
        const int d = p * 8 + e;
        VTs[d * 64 + (r ^ ((d & 7) << 3))] = v[e];
      }
    }
    __syncthreads();

    f32x4 S[4];
#pragma unroll
    for (int ks = 0; ks < 4; ++ks) S[ks] = (f32x4){0.f, 0.f, 0.f, 0.f};
#pragma unroll
    for (int ks = 0; ks < 4; ++ks) {
      const int kr = ks * 16 + fr;
#pragma unroll
      for (int dc = 0; dc < 2; ++dc) {
        const int d0 = dc * 32 + g * 8;
        short8 kf = *reinterpret_cast<const short8*>(&Ks[kr * 64 + (d0 ^ ((kr & 7) << 3))]);
        S[ks] = __builtin_amdgcn_mfma_f32_16x16x32_bf16(qf[dc], kf, S[ks], 0, 0, 0);
      }
    }

    const int qrow0 = t0 + w * 16 + g * 4;
    float rowmax[4];
#pragma unroll
    for (int r = 0; r < 4; ++r) rowmax[r] = -1e30f;
#pragma unroll
    for (int ks = 0; ks < 4; ++ks) {
      const int j = jb + ks * 16 + fr;
#pragma unroll
      for (int r = 0; r < 4; ++r) {
        float s = S[ks][r] * 0.125f;
        if (masked) {
          const int i = qrow0 + r;
          if (!((j <= i) && (j > i - 256))) s = -1e30f;
        }
        S[ks][r] = s;
        rowmax[r] = fmaxf(rowmax[r], s);
      }
    }
#pragma unroll
    for (int off = 1; off <= 8; off <<= 1)
#pragma unroll
      for (int r = 0; r < 4; ++r)
        rowmax[r] = fmaxf(rowmax[r], __shfl_xor(rowmax[r], off));

    float resc[4], psum[4];
#pragma unroll
    for (int r = 0; r < 4; ++r) {
      const float mn = fmaxf(m[r], rowmax[r]);
      resc[r] = __expf(m[r] - mn);
      m[r] = mn;
      psum[r] = 0.f;
    }
#pragma unroll
    for (int ks = 0; ks < 4; ++ks) {
      const int j = jb + ks * 16 + fr;
#pragma unroll
      for (int r = 0; r < 4; ++r) {
        float p = __expf(S[ks][r] - m[r]);
        if (masked) {
          const int i = qrow0 + r;
          if (!((j <= i) && (j > i - 256))) p = 0.f;
        }
        S[ks][r] = p;
        psum[r] += p;
      }
    }
#pragma unroll
    for (int off = 1; off <= 8; off <<= 1)
#pragma unroll
      for (int r = 0; r < 4; ++r) psum[r] += __shfl_xor(psum[r], off);
#pragma unroll
    for (int r = 0; r < 4; ++r) l[r] = l[r] * resc[r] + psum[r];
#pragma unroll
    for (int dt = 0; dt < 4; ++dt)
#pragma unroll
      for (int r = 0; r < 4; ++r) acc[dt][r] *= resc[r];

#pragma unroll
    for (int ks = 0; ks < 4; ++ks)
#pragma unroll
      for (int r = 0; r < 4; ++r) {
        const int prow = w * 16 + g * 4 + r;
        const int pcol = ks * 16 + fr;
        Ps[prow * 64 + (pcol ^ ((prow & 7) << 3))] = fbits(S[ks][r]);
      }

#pragma unroll
    for (int kc = 0; kc < 2; ++kc) {
      const int prow = w * 16 + fr;
      const int k0 = kc * 32 + g * 8;
      short8 pf = *reinterpret_cast<const short8*>(&Ps[prow * 64 + (k0 ^ ((prow & 7) << 3))]);
#pragma unroll
      for (int dt = 0; dt < 4; ++dt) {
        const int dr = dt * 16 + fr;
        short8 vf = *reinterpret_cast<const short8*>(&VTs[dr * 64 + (k0 ^ ((dr & 7) << 3))]);
        acc[dt] = __builtin_amdgcn_mfma_f32_16x16x32_bf16(pf, vf, acc[dt], 0, 0, 0);
      }
    }
  }

#pragma unroll
  for (int dt = 0; dt < 4; ++dt)
#pragma unroll
    for (int r = 0; r < 4; ++r) {
      const int i = t0 + w * 16 + g * 4 + r;
      const int d = dt * 16 + fr;
      ybuf[(size_t)i * kC + h * kHS + d] = f2b(acc[dt][r] / l[r]);
    }
}

// ---------------- Compressed attention: MFMA flash + fused gate mix (batch in grid.z) ----------------
__global__ __launch_bounds__(256) void comp_attn_mfma(
    const bf16* __restrict__ qkv, const bf16* __restrict__ kcomp,
    const bf16* __restrict__ vcomp, const bf16* __restrict__ gate,
    bf16* __restrict__ ybuf0)
{
  __shared__ __align__(16) short Qs[64 * 64];
  __shared__ __align__(16) short Ks[64 * 64];
  __shared__ __align__(16) short VTs[64 * 64];
  __shared__ __align__(16) short Ps[64 * 64];
  const int tid = threadIdx.x;
  const int lane = tid & 63;
  const int w = tid >> 6;
  const int fr = lane & 15;
  const int g  = lane >> 4;
  const int h  = blockIdx.y;
  const int b  = blockIdx.z;
  const int t0 = blockIdx.x * 64;
  bf16* ybuf = ybuf0 + (size_t)b * kT * kC;
  const size_t rs = 3 * kC;
  const bf16* qbase = qkv + ((size_t)b * kT) * rs + h * kHS;
  const bf16* kb = kcomp + ((size_t)(b * kNH + h)) * kNB * kHS;
  const bf16* vb = vcomp + ((size_t)(b * kNH + h)) * kNB * kHS;

  for (int c = tid; c < 512; c += 256) {
    const int r = c >> 3, p = c & 7;
    short8 v = *reinterpret_cast<const short8*>(qbase + (size_t)(t0 + r) * rs + p * 8);
    *reinterpret_cast<short8*>(&Qs[r * 64 + ((p ^ (r & 7)) << 3)]) = v;
  }
  __syncthreads();
  short8 qf[2];
  {
    const int r = w * 16 + fr;
#pragma unroll
    for (int dc = 0; dc < 2; ++dc) {
      const int d0 = dc * 32 + g * 8;
      qf[dc] = *reinterpret_cast<const short8*>(&Qs[r * 64 + (d0 ^ ((r & 7) << 3))]);
    }
  }

  f32x4 acc[4];
  float m[4], l[4];
#pragma unroll
  for (int r = 0; r < 4; ++r) { m[r] = -1e30f; l[r] = 0.f; }
#pragma unroll
  for (int dt = 0; dt < 4; ++dt) acc[dt] = (f32x4){0.f, 0.f, 0.f, 0.f};

  const int ntiles = (t0 >= 1024) ? 2 : 1;
  for (int tb = 0; tb < ntiles; ++tb) {
    const int jb = tb * 64;
    const bool masked = !(((jb + 63) < kNB) && ((jb + 63) * kST < t0));
    __syncthreads();
    for (int c = tid; c < 512; c += 256) {
      const int r = c >> 3, p = c & 7;
      const int rr = (jb + r < kNB) ? (jb + r) : (kNB - 1);
      short8 v = *reinterpret_cast<const short8*>(kb + (size_t)rr * kHS + p * 8);
      *reinterpret_cast<short8*>(&Ks[r * 64 + ((p ^ (r & 7)) << 3)]) = v;
    }
    for (int c = tid; c < 512; c += 256) {
      const int r = c >> 3, p = c & 7;
      const int rr = (jb + r < kNB) ? (jb + r) : (kNB - 1);
      short8 v = *reinterpret_cast<const short8*>(vb + (size_t)rr * kHS + p * 8);
#pragma unroll
      for (int e = 0; e < 8; ++e) {
        const int d = p * 8 + e;
        VTs[d * 64 + (r ^ ((d & 7) << 3))] = v[e];
      }
    }
    __syncthreads();

    f32x4 S[4];
#pragma unroll
    for (int ks = 0; ks < 4; ++ks) S[ks] = (f32x4){0.f, 0.f, 0.f, 0.f};
#pragma unroll
    for (int ks = 0; ks < 4; ++ks) {
      const int kr = ks * 16 + fr;
#pragma unroll
      for (int dc = 0; dc < 2; ++dc) {
        const int d0 = dc * 32 + g * 8;
        short8 kf = *reinterpret_cast<const short8*>(&Ks[kr * 64 + (d0 ^ ((kr & 7) << 3))]);
        S[ks] = __builtin_amdgcn_mfma_f32_16x16x32_bf16(qf[dc], kf, S[ks], 0, 0, 0);
      }
    }

    const int qrow0 = t0 + w * 16 + g * 4;
    float rowmax[4];
#pragma unroll
    for (int r = 0; r < 4; ++r) rowmax[r] = -1e30f;
#pragma unroll
    for (int ks = 0; ks < 4; ++ks) {
      const int n = jb + ks * 16 + fr;
#pragma unroll
      for (int r = 0; r < 4; ++r) {
        float s = S[ks][r] * 0.125f;
        if (masked) {
          const int i = qrow0 + r;
          if (!((n < kNB) && (n * kST < i))) s = -1e30f;
        }
        S[ks][r] = s;
        rowmax[r] = fmaxf(rowmax[r], s);
      }
    }
#pragma unroll
    for (int off = 1; off <= 8; off <<= 1)
#pragma unroll
      for (int r = 0; r < 4; ++r)
        rowmax[r] = fmaxf(rowmax[r], __shfl_xor(rowmax[r], off));

    float resc[4], psum[4];
#pragma unroll
    for (int r = 0; r < 4; ++r) {
      const float mn = fmaxf(m[r], rowmax[r]);
      resc[r] = __expf(m[r] - mn);
      m[r] = mn;
      psum[r] = 0.f;
    }
#pragma unroll
    for (int ks = 0; ks < 4; ++ks) {
      const int n = jb + ks * 16 + fr;
#pragma unroll
      for (int r = 0; r < 4; ++r) {
        float p = __expf(S[ks][r] - m[r]);
        if (masked) {
          const int i = qrow0 + r;
          if (!((n < kNB) && (n * kST < i))) p = 0.f;
        }
        S[ks][r] = p;
        psum[r] += p;
      }
    }
#pragma unroll
    for (int off = 1; off <= 8; off <<= 1)
#pragma unroll
      for (int r = 0; r < 4; ++r) psum[r] += __shfl_xor(psum[r], off);
#pragma unroll
    for (int r = 0; r < 4; ++r) l[r] = l[r] * resc[r] + psum[r];
#pragma unroll
    for (int dt = 0; dt < 4; ++dt)
#pragma unroll
      for (int r = 0; r < 4; ++r) acc[dt][r] *= resc[r];

#pragma unroll
    for (int ks = 0; ks < 4; ++ks)
#pragma unroll
      for (int r = 0; r < 4; ++r) {
        const int prow = w * 16 + g * 4 + r;
        const int pcol = ks * 16 + fr;
        Ps[prow * 64 + (pcol ^ ((prow & 7) << 3))] = fbits(S[ks][r]);
      }

#pragma unroll
    for (int kc = 0; kc < 2; ++kc) {
      const int prow = w * 16 + fr;
      const int k0 = kc * 32 + g * 8;
      short8 pf = *reinterpret_cast<const short8*>(&Ps[prow * 64 + (k0 ^ ((prow & 7) << 3))]);
#pragma unroll
      for (int dt = 0; dt < 4; ++dt) {
        const int dr = dt * 16 + fr;
        short8 vf = *reinterpret_cast<const short8*>(&VTs[dr * 64 + (k0 ^ ((dr & 7) << 3))]);
        acc[dt] = __builtin_amdgcn_mfma_f32_16x16x32_bf16(pf, vf, acc[dt], 0, 0, 0);
      }
    }
  }

#pragma unroll
  for (int r = 0; r < 4; ++r) {
    const int i = t0 + w * 16 + g * 4 + r;
    const float inv = (l[r] > 0.f) ? (1.f / l[r]) : 0.f;
#pragma unroll
    for (int dt = 0; dt < 4; ++dt) {
      const int d = dt * 16 + fr;
      const size_t idx = (size_t)i * kC + h * kHS + d;
      const float yc = acc[dt][r] * inv;
      const float gg = b2f(gate[((size_t)(b * kT + i)) * kC + h * kHS + d]);
      const float yl = b2f(ybuf[idx]);
      ybuf[idx] = f2b(gg * yl + (1.f - gg) * yc);
    }
  }
}

extern "C" void kernel_launch(void* const* d_in, const int* in_sizes, int n_in,
                              void* d_out, int out_size, void* d_ws, size_t ws_size,
                              hipStream_t stream)
{
  (void)in_sizes; (void)n_in; (void)out_size; (void)ws_size; (void)kM; (void)kWIN;
  const float* x      = (const float*)d_in[0];
  const float* Wqkv   = (const float*)d_in[1];
  const float* bqkv   = (const float*)d_in[2];
  const float* Wcomp  = (const float*)d_in[3];
  const float* bcomp  = (const float*)d_in[4];
  const float* Wproj  = (const float*)d_in[5];
  const float* bproj  = (const float*)d_in[6];
  const float* k_fc1W = (const float*)d_in[7];
  const float* k_fc1b = (const float*)d_in[8];
  const float* k_fc2W = (const float*)d_in[9];
  const float* k_fc2b = (const float*)d_in[10];
  const float* k_rpW  = (const float*)d_in[11];
  const float* k_rpb  = (const float*)d_in[12];
  const float* k_wpe  = (const float*)d_in[13];
  const float* v_fc1W = (const float*)d_in[14];
  const float* v_fc1b = (const float*)d_in[15];
  const float* v_fc2W = (const float*)d_in[16];
  const float* v_fc2b = (const float*)d_in[17];
  const float* v_rpW  = (const float*)d_in[18];
  const float* v_rpb  = (const float*)d_in[19];
  const float* v_wpe  = (const float*)d_in[20];
  const float* Wg1    = (const float*)d_in[21];
  const float* bg1    = (const float*)d_in[22];
  const float* Wg2    = (const float*)d_in[23];
  const float* bg2    = (const float*)d_in[24];

  // ---- Workspace (peak 51,372,032 B, identical to proven footprint) ----
  char* wsb = (char*)d_ws;
  bf16* xbf   = (bf16*)(wsb + 0);
  bf16* wscr  = (bf16*)(wsb + 8388608);
  bf16* big   = (bf16*)(wsb + 16777216);
  bf16* ybuf  = (bf16*)(wsb + 41943040);
  bf16* kcomp = (bf16*)(wsb + 50331648);
  bf16* vcomp = (bf16*)(wsb + 50851840);
  bf16* gate  = (bf16*)((char*)d_out + 8388608);
  float* out  = (float*)d_out;

  const int cg = 2048;
  f32_to_bf16<<<cg, 256, 0, stream>>>(x, xbf, 1048576);
  f32_to_bf16<<<cg, 256, 0, stream>>>(Wg1, wscr, 1048576);
  gemm_bf16<1, bf16><<<1024, 512, 0, stream>>>(xbf, wscr, bg1, big, 4096, 4096, 1024, 32);
  f32_to_bf16<<<cg, 256, 0, stream>>>(Wg2, wscr, 1048576);
  gemm_bf16_t64<3, bf16><<<1024, 256, 0, stream>>>(big, wscr, bg2, gate, 4096, 1024, 4096, 16);
  f32_to_bf16<<<cg, 256, 0, stream>>>(Wcomp, wscr, 524288);
  gemm_bf16<0, bf16><<<512, 512, 0, stream>>>(xbf, wscr, bcomp, big, 4096, 2048, 1024, 16);
  comp_mlp_mfma<<<dim3(kNB, kNH, kB), 256, 0, stream>>>(big, 0, k_fc1W, k_fc1b, k_fc2W, k_fc2b, k_rpW, k_rpb, k_wpe, kcomp);
  comp_mlp_mfma<<<dim3(kNB, kNH, kB), 256, 0, stream>>>(big, 1, v_fc1W, v_fc1b, v_fc2W, v_fc2b, v_rpW, v_rpb, v_wpe, vcomp);
  f32_to_bf16<<<cg, 256, 0, stream>>>(Wqkv, wscr, 786432);
  gemm_bf16<0, bf16><<<768, 512, 0, stream>>>(xbf, wscr, bqkv, big, 4096, 3072, 1024, 24);
  f32_to_bf16<<<cg, 256, 0, stream>>>(Wproj, wscr, 262144);
  // attention for both batches (batch = blockIdx.z); gate consumed here
  local_attn_mfma<<<dim3(kT / 64, kNH, kB), 256, 0, stream>>>(big, ybuf);
  comp_attn_mfma<<<dim3(kT / 64, kNH, kB), 256, 0, stream>>>(big, kcomp, vcomp, gate, ybuf);
  // single merged projection over both batches (overwrites gate region after use)
  gemm_bf16_t64<0, float><<<1024, 256, 0, stream>>>(ybuf, wscr, bproj, out, 4096, 1024, 1024, 16);
}